// Round 1
// baseline (4863.983 us; speedup 1.0000x reference)
//
#include <hip/hip_runtime.h>
#include <math.h>

// Problem constants: B=16384 samples, DIM=64, WIDTH=256, DD=64, C2=16
#define SB 16      // samples per workgroup
#define PAD 17     // LDS row pad for transposed [neuron][sample] tiles

// ws layout (float offsets)
#define OFF_W0T  0            // 5 x (64x256)
#define OFF_W1T  81920        // 5 x (256x256)
#define OFF_W2PT 409600       // 256x2016
#define OFF_W2CT 925696       // 256x1024
#define OFF_W2BT 1187840      // 256x4096
#define OFF_DE   2236416      // 16384x64
#define OFF_DS   3284992      // 16384x64
#define OFF_IT   4333568      // 2016 int
#define OFF_JT   4335584      // 2016 int
#define WS_FLOATS 4337600     // ~17.35 MB

__device__ __forceinline__ void fma16(float* acc0, float* acc1, float a0, float a1,
                                      float4 wA, float4 wB) {
    float w[8] = {wA.x, wA.y, wA.z, wA.w, wB.x, wB.y, wB.z, wB.w};
    #pragma unroll
    for (int q = 0; q < 8; ++q) {
        acc0[q] = fmaf(a0, w[q], acc0[q]);
        acc1[q] = fmaf(a1, w[q], acc1[q]);
    }
}

__device__ __forceinline__ void fma8v(float* acc0, float* acc1, float a0, float a1, float4 w) {
    acc0[0] = fmaf(a0, w.x, acc0[0]); acc0[1] = fmaf(a0, w.y, acc0[1]);
    acc0[2] = fmaf(a0, w.z, acc0[2]); acc0[3] = fmaf(a0, w.w, acc0[3]);
    acc1[0] = fmaf(a1, w.x, acc1[0]); acc1[1] = fmaf(a1, w.y, acc1[1]);
    acc1[2] = fmaf(a1, w.z, acc1[2]); acc1[3] = fmaf(a1, w.w, acc1[3]);
}

// out[c*R + r] = in[r*C + c]   (in: R rows x C cols, row-major)
__global__ void k_transpose(const float* __restrict__ in, float* __restrict__ out, int R, int C) {
    int tid = blockIdx.x * blockDim.x + threadIdx.x;
    if (tid >= R * C) return;
    int c = tid / R, r = tid - c * R;
    out[tid] = in[r * C + c];
}

// tril_indices(64,-1) row-major: t = i*(i-1)/2 + j
__global__ void k_trilidx(int* __restrict__ it, int* __restrict__ jt) {
    int t = blockIdx.x * blockDim.x + threadIdx.x;
    if (t >= 2016) return;
    int i = (int)((1.0f + sqrtf(1.0f + 8.0f * (float)t)) * 0.5f);
    while (i * (i - 1) / 2 > t) --i;
    while ((i + 1) * i / 2 <= t) ++i;
    it[t] = i;
    jt[t] = t - i * (i - 1) / 2;
}

// ---------------- K1: dE, dS (energy/entropy forward + analytic backward) ----------------
__global__ __launch_bounds__(256) void k1_grads(
    const float* __restrict__ y, const float* __restrict__ ws,
    const float* __restrict__ W0E, const float* __restrict__ b0E,
    const float* __restrict__ W1E, const float* __restrict__ b1E,
    const float* __restrict__ w2E,
    const float* __restrict__ W0S, const float* __restrict__ b0S,
    const float* __restrict__ W1S, const float* __restrict__ b1S,
    const float* __restrict__ w2S,
    float* __restrict__ odE, float* __restrict__ odS)
{
    __shared__ float sYT[64][PAD];
    __shared__ float sH1T[256][PAD];
    __shared__ float sH2T[256][PAD];
    __shared__ float sUT[256][PAD];

    const int tid = threadIdx.x;
    const int sbase = blockIdx.x * SB;
    for (int idx = tid; idx < SB * 64; idx += 256) {
        int s = idx >> 6, i = idx & 63;
        sYT[i][s] = y[(sbase + s) * 64 + i];
    }
    __syncthreads();

    const int ts = tid >> 5, tn = tid & 31;
    const int s0 = 2 * ts, s1 = s0 + 1;

    for (int m = 0; m < 2; ++m) {
        const float* w0t = ws + OFF_W0T + m * 16384;
        const float* w1t = ws + OFF_W1T + m * 65536;
        const float* W0 = m ? W0S : W0E;
        const float* W1 = m ? W1S : W1E;
        const float* b0 = m ? b0S : b0E;
        const float* b1 = m ? b1S : b1E;
        const float* w2 = m ? w2S : w2E;
        float* outg = m ? odS : odE;

        // H1 = tanh(Y @ W0^T + b0), K=64
        {
            float acc0[8] = {0}, acc1[8] = {0};
            #pragma unroll 4
            for (int k = 0; k < 64; ++k) {
                float a0 = sYT[k][s0], a1 = sYT[k][s1];
                float4 wA = *(const float4*)(w0t + k * 256 + tn * 8);
                float4 wB = *(const float4*)(w0t + k * 256 + tn * 8 + 4);
                fma16(acc0, acc1, a0, a1, wA, wB);
            }
            #pragma unroll
            for (int q = 0; q < 8; ++q) {
                int j = tn * 8 + q;
                float b = b0[j];
                sH1T[j][s0] = tanhf(acc0[q] + b);
                sH1T[j][s1] = tanhf(acc1[q] + b);
            }
        }
        __syncthreads();
        // H2 = tanh(H1 @ W1^T + b1), K=256
        {
            float acc0[8] = {0}, acc1[8] = {0};
            #pragma unroll 4
            for (int k = 0; k < 256; ++k) {
                float a0 = sH1T[k][s0], a1 = sH1T[k][s1];
                float4 wA = *(const float4*)(w1t + k * 256 + tn * 8);
                float4 wB = *(const float4*)(w1t + k * 256 + tn * 8 + 4);
                fma16(acc0, acc1, a0, a1, wA, wB);
            }
            #pragma unroll
            for (int q = 0; q < 8; ++q) {
                int j = tn * 8 + q;
                float b = b1[j];
                sH2T[j][s0] = tanhf(acc0[q] + b);
                sH2T[j][s1] = tanhf(acc1[q] + b);
            }
        }
        __syncthreads();
        // G2 = (1 - H2^2) * w2  (in place)
        for (int idx = tid; idx < 256 * SB; idx += 256) {
            int j = idx >> 4, s = idx & 15;
            float h = sH2T[j][s];
            sH2T[j][s] = (1.f - h * h) * w2[j];
        }
        __syncthreads();
        // U = G2 @ W1 (natural layout), fused G1 = (1-H1^2)*U
        {
            float acc0[8] = {0}, acc1[8] = {0};
            #pragma unroll 4
            for (int k = 0; k < 256; ++k) {
                float a0 = sH2T[k][s0], a1 = sH2T[k][s1];
                float4 wA = *(const float4*)(W1 + k * 256 + tn * 8);
                float4 wB = *(const float4*)(W1 + k * 256 + tn * 8 + 4);
                fma16(acc0, acc1, a0, a1, wA, wB);
            }
            #pragma unroll
            for (int q = 0; q < 8; ++q) {
                int ko = tn * 8 + q;
                float h0 = sH1T[ko][s0], h1v = sH1T[ko][s1];
                sUT[ko][s0] = (1.f - h0 * h0) * acc0[q];
                sUT[ko][s1] = (1.f - h1v * h1v) * acc1[q];
            }
        }
        __syncthreads();
        // dE = G1 @ W0 (natural layout)
        {
            float a00 = 0, a01 = 0, a10 = 0, a11 = 0;
            #pragma unroll 4
            for (int k = 0; k < 256; ++k) {
                float g0 = sUT[k][s0], g1 = sUT[k][s1];
                float2 w = *(const float2*)(W0 + k * 64 + tn * 2);
                a00 = fmaf(g0, w.x, a00); a01 = fmaf(g0, w.y, a01);
                a10 = fmaf(g1, w.x, a10); a11 = fmaf(g1, w.y, a11);
            }
            outg[(sbase + s0) * 64 + tn * 2]     = a00;
            outg[(sbase + s0) * 64 + tn * 2 + 1] = a01;
            outg[(sbase + s1) * 64 + tn * 2]     = a10;
            outg[(sbase + s1) * 64 + tn * 2 + 1] = a11;
        }
        __syncthreads();
    }
}

// ---------------- K2: pA head + poisson, writes d_out ----------------
__global__ __launch_bounds__(256) void k2_poisson(
    const float* __restrict__ y, const float* __restrict__ ws,
    const float* __restrict__ b0P, const float* __restrict__ b1P,
    float* __restrict__ dout)
{
    __shared__ float sYT[64][PAD];
    __shared__ float sH1T[256][PAD];
    __shared__ float sH2T[256][PAD];
    __shared__ float sdE[SB][64], sdS[SB][64];
    __shared__ float sAdE[SB][64], sAdS[SB][64];
    __shared__ int sIT[256], sJT[256];
    __shared__ float sScal[SB][4];

    const int tid = threadIdx.x;
    const int sbase = blockIdx.x * SB;
    const float* gdE = ws + OFF_DE;
    const float* gdS = ws + OFF_DS;

    for (int idx = tid; idx < SB * 64; idx += 256) {
        int s = idx >> 6, i = idx & 63;
        sYT[i][s] = y[(sbase + s) * 64 + i];
        sdE[s][i] = gdE[sbase * 64 + idx];
        sdS[s][i] = gdS[sbase * 64 + idx];
        sAdE[s][i] = 0.f; sAdS[s][i] = 0.f;
    }
    if (tid < SB * 4) ((float*)sScal)[tid] = 0.f;
    __syncthreads();

    const int ts = tid >> 5, tn = tid & 31;
    const int s0 = 2 * ts, s1 = s0 + 1;
    const float* w0t = ws + OFF_W0T + 2 * 16384;
    const float* w1t = ws + OFF_W1T + 2 * 65536;

    // pA forward H1
    {
        float acc0[8] = {0}, acc1[8] = {0};
        #pragma unroll 4
        for (int k = 0; k < 64; ++k) {
            float a0 = sYT[k][s0], a1 = sYT[k][s1];
            float4 wA = *(const float4*)(w0t + k * 256 + tn * 8);
            float4 wB = *(const float4*)(w0t + k * 256 + tn * 8 + 4);
            fma16(acc0, acc1, a0, a1, wA, wB);
        }
        #pragma unroll
        for (int q = 0; q < 8; ++q) {
            int j = tn * 8 + q;
            float b = b0P[j];
            sH1T[j][s0] = tanhf(acc0[q] + b);
            sH1T[j][s1] = tanhf(acc1[q] + b);
        }
    }
    __syncthreads();
    // pA forward H2
    {
        float acc0[8] = {0}, acc1[8] = {0};
        #pragma unroll 4
        for (int k = 0; k < 256; ++k) {
            float a0 = sH1T[k][s0], a1 = sH1T[k][s1];
            float4 wA = *(const float4*)(w1t + k * 256 + tn * 8);
            float4 wB = *(const float4*)(w1t + k * 256 + tn * 8 + 4);
            fma16(acc0, acc1, a0, a1, wA, wB);
        }
        #pragma unroll
        for (int q = 0; q < 8; ++q) {
            int j = tn * 8 + q;
            float b = b1P[j];
            sH2T[j][s0] = tanhf(acc0[q] + b);
            sH2T[j][s1] = tanhf(acc1[q] + b);
        }
    }
    __syncthreads();

    const float* w2pt = ws + OFF_W2PT;
    const int* itab = (const int*)(ws + OFF_IT);
    const int* jtab = (const int*)(ws + OFF_JT);

    for (int ch = 0; ch < 8; ++ch) {
        int cb = ch * 256;
        int nlim = 2016 - cb; if (nlim > 256) nlim = 256;
        for (int idx = tid; idx < nlim; idx += 256) {
            sIT[idx] = itab[cb + idx];
            sJT[idx] = jtab[cb + idx];
        }
        __syncthreads();
        if (tn * 8 < nlim) {
            float acc0[8] = {0}, acc1[8] = {0};
            #pragma unroll 4
            for (int k = 0; k < 256; ++k) {
                float a0 = sH2T[k][s0], a1 = sH2T[k][s1];
                float4 wA = *(const float4*)(w2pt + k * 2016 + cb + tn * 8);
                float4 wB = *(const float4*)(w2pt + k * 2016 + cb + tn * 8 + 4);
                fma16(acc0, acc1, a0, a1, wA, wB);
            }
            // scatter: AdE_i += a*dE_j ; AdE_j -= a*dE_i (antisymmetric A)
            #pragma unroll
            for (int q = 0; q < 8; ++q) {
                int tt = tn * 8 + q;
                int i = sIT[tt], j = sJT[tt];
                float a0v = acc0[q], a1v = acc1[q];
                unsafeAtomicAdd(&sAdE[s0][i],  a0v * sdE[s0][j]);
                unsafeAtomicAdd(&sAdE[s0][j], -a0v * sdE[s0][i]);
                unsafeAtomicAdd(&sAdS[s0][i],  a0v * sdS[s0][j]);
                unsafeAtomicAdd(&sAdS[s0][j], -a0v * sdS[s0][i]);
                unsafeAtomicAdd(&sAdE[s1][i],  a1v * sdE[s1][j]);
                unsafeAtomicAdd(&sAdE[s1][j], -a1v * sdE[s1][i]);
                unsafeAtomicAdd(&sAdS[s1][i],  a1v * sdS[s1][j]);
                unsafeAtomicAdd(&sAdS[s1][j], -a1v * sdS[s1][i]);
            }
        }
        __syncthreads();
    }

    // scalars: [0]=dE.AdS  [1]=dE.dS  [2]=dS.dS
    for (int idx = tid; idx < SB * 64; idx += 256) {
        int s = idx >> 6, i = idx & 63;
        float de = sdE[s][i], dsv = sdS[s][i];
        unsafeAtomicAdd(&sScal[s][0], de * sAdS[s][i]);
        unsafeAtomicAdd(&sScal[s][1], de * dsv);
        unsafeAtomicAdd(&sScal[s][2], dsv * dsv);
    }
    __syncthreads();
    for (int idx = tid; idx < SB * 64; idx += 256) {
        int s = idx >> 6, i = idx & 63;
        float res = sAdE[s][i] + (sScal[s][0] * sdS[s][i] - sScal[s][1] * sAdS[s][i]) / sScal[s][2];
        dout[(sbase + s) * 64 + i] = res;
    }
}

// ---------------- K3: fC/fB heads + friction, accumulates into d_out ----------------
__global__ __launch_bounds__(512) void k3_friction(
    const float* __restrict__ y, const float* __restrict__ ws,
    const float* __restrict__ b0C, const float* __restrict__ b1C,
    const float* __restrict__ b0B, const float* __restrict__ b1B,
    float* __restrict__ dout)
{
    extern __shared__ float smem[];
    float* sYT  = smem;                   // 64*PAD
    float* sH1T = sYT + 64 * PAD;         // 256*PAD
    float* sH2cT = sH1T + 256 * PAD;      // 256*PAD
    float* sH2bT = sH2cT + 256 * PAD;     // 256*PAD
    float* sC   = sH2bT + 256 * PAD;      // 16*1028
    float* sdE  = sC + 16 * 1028;         // 16*64
    float* sdS  = sdE + 1024;
    float* sBdE = sdS + 1024;
    float* sBdS = sBdE + 1024;
    float* sv   = sBdS + 1024;
    float* sq   = sv + 1024;
    float* sScal = sq + 1024;             // 16*4: [0]=dE.dE [1]=dE.dS [2]=dE.v
    float* sr   = sScal + 64;             // 16*16

    const int tid = threadIdx.x;
    const int sbase = blockIdx.x * SB;
    const float* gdE = ws + OFF_DE;
    const float* gdS = ws + OFF_DS;

    for (int idx = tid; idx < SB * 64; idx += 512) {
        int s = idx >> 6, i = idx & 63;
        sYT[i * PAD + s] = y[(sbase + s) * 64 + i];
        sdE[idx] = gdE[sbase * 64 + idx];
        sdS[idx] = gdS[sbase * 64 + idx];
        sBdE[idx] = 0.f; sBdS[idx] = 0.f; sq[idx] = 0.f;
    }
    if (tid < 64) sScal[tid] = 0.f;
    __syncthreads();

    for (int idx = tid; idx < SB * 64; idx += 512) {
        int s = idx >> 6;
        float de = sdE[idx];
        unsafeAtomicAdd(&sScal[s * 4 + 0], de * de);
        unsafeAtomicAdd(&sScal[s * 4 + 1], de * sdS[idx]);
    }

    const int ts = tid >> 6, tn = tid & 63;
    const int s0 = 2 * ts, s1 = s0 + 1;
    const int n4 = tn * 4;

    // forwards: mm=0 -> fC (index 3), mm=1 -> fB (index 4)
    for (int mm = 0; mm < 2; ++mm) {
        const float* w0t = ws + OFF_W0T + (3 + mm) * 16384;
        const float* w1t = ws + OFF_W1T + (3 + mm) * 65536;
        const float* b0 = mm ? b0B : b0C;
        const float* b1 = mm ? b1B : b1C;
        float* dst = mm ? sH2bT : sH2cT;
        {
            float acc0[4] = {0}, acc1[4] = {0};
            #pragma unroll 4
            for (int k = 0; k < 64; ++k) {
                float a0 = sYT[k * PAD + s0], a1 = sYT[k * PAD + s1];
                float4 w = *(const float4*)(w0t + k * 256 + n4);
                fma8v(acc0, acc1, a0, a1, w);
            }
            #pragma unroll
            for (int q = 0; q < 4; ++q) {
                float b = b0[n4 + q];
                sH1T[(n4 + q) * PAD + s0] = tanhf(acc0[q] + b);
                sH1T[(n4 + q) * PAD + s1] = tanhf(acc1[q] + b);
            }
        }
        __syncthreads();
        {
            float acc0[4] = {0}, acc1[4] = {0};
            #pragma unroll 4
            for (int k = 0; k < 256; ++k) {
                float a0 = sH1T[k * PAD + s0], a1 = sH1T[k * PAD + s1];
                float4 w = *(const float4*)(w1t + k * 256 + n4);
                fma8v(acc0, acc1, a0, a1, w);
            }
            #pragma unroll
            for (int q = 0; q < 4; ++q) {
                float b = b1[n4 + q];
                dst[(n4 + q) * PAD + s0] = tanhf(acc0[q] + b);
                dst[(n4 + q) * PAD + s1] = tanhf(acc1[q] + b);
            }
        }
        __syncthreads();
    }

    // C = h2c @ W2c^T  -> sC[s][n], n in [0,1024)
    const float* w2ct = ws + OFF_W2CT;
    for (int cc = 0; cc < 4; ++cc) {
        float acc0[4] = {0}, acc1[4] = {0};
        #pragma unroll 4
        for (int k = 0; k < 256; ++k) {
            float a0 = sH2cT[k * PAD + s0], a1 = sH2cT[k * PAD + s1];
            float4 w = *(const float4*)(w2ct + k * 1024 + cc * 256 + n4);
            fma8v(acc0, acc1, a0, a1, w);
        }
        #pragma unroll
        for (int q = 0; q < 4; ++q) {
            sC[s0 * 1028 + cc * 256 + n4 + q] = acc0[q];
            sC[s1 * 1028 + cc * 256 + n4 + q] = acc1[q];
        }
    }
    __syncthreads();

    const float* w2bt = ws + OFF_W2BT;
    const int kloc = tn >> 4;          // 0..3
    const int i0 = (tn & 15) * 4;      // 0..60

    // Pass 1: BdotdE, BdotdS  (Bm chunk per rb: k in {4rb..4rb+3}, all i)
    for (int rb = 0; rb < 16; ++rb) {
        float acc0[4] = {0}, acc1[4] = {0};
        #pragma unroll 4
        for (int k = 0; k < 256; ++k) {
            float a0 = sH2bT[k * PAD + s0], a1 = sH2bT[k * PAD + s1];
            float4 w = *(const float4*)(w2bt + k * 4096 + rb * 256 + n4);
            fma8v(acc0, acc1, a0, a1, w);
        }
        int kk = rb * 4 + kloc;
        {
            float pd = fmaf(acc0[3], sdE[s0 * 64 + i0 + 3], fmaf(acc0[2], sdE[s0 * 64 + i0 + 2],
                       fmaf(acc0[1], sdE[s0 * 64 + i0 + 1], acc0[0] * sdE[s0 * 64 + i0])));
            float ps = fmaf(acc0[3], sdS[s0 * 64 + i0 + 3], fmaf(acc0[2], sdS[s0 * 64 + i0 + 2],
                       fmaf(acc0[1], sdS[s0 * 64 + i0 + 1], acc0[0] * sdS[s0 * 64 + i0])));
            unsafeAtomicAdd(&sBdE[s0 * 64 + kk], pd);
            unsafeAtomicAdd(&sBdS[s0 * 64 + kk], ps);
        }
        {
            float pd = fmaf(acc1[3], sdE[s1 * 64 + i0 + 3], fmaf(acc1[2], sdE[s1 * 64 + i0 + 2],
                       fmaf(acc1[1], sdE[s1 * 64 + i0 + 1], acc1[0] * sdE[s1 * 64 + i0])));
            float ps = fmaf(acc1[3], sdS[s1 * 64 + i0 + 3], fmaf(acc1[2], sdS[s1 * 64 + i0 + 2],
                       fmaf(acc1[1], sdS[s1 * 64 + i0 + 1], acc1[0] * sdS[s1 * 64 + i0])));
            unsafeAtomicAdd(&sBdE[s1 * 64 + kk], pd);
            unsafeAtomicAdd(&sBdS[s1 * 64 + kk], ps);
        }
    }
    __syncthreads();

    // v = BdotdS - beta*BdotdE ; dEv
    for (int idx = tid; idx < SB * 64; idx += 512) {
        int s = idx >> 6;
        float beta = sScal[s * 4 + 1] / sScal[s * 4 + 0];
        sv[idx] = sBdS[idx] - beta * sBdE[idx];
    }
    __syncthreads();
    for (int idx = tid; idx < SB * 64; idx += 512) {
        int s = idx >> 6;
        unsafeAtomicAdd(&sScal[s * 4 + 2], sdE[idx] * sv[idx]);
    }
    __syncthreads();

    // Pass 2: q = Bm @ v
    for (int rb = 0; rb < 16; ++rb) {
        float acc0[4] = {0}, acc1[4] = {0};
        #pragma unroll 4
        for (int k = 0; k < 256; ++k) {
            float a0 = sH2bT[k * PAD + s0], a1 = sH2bT[k * PAD + s1];
            float4 w = *(const float4*)(w2bt + k * 4096 + rb * 256 + n4);
            fma8v(acc0, acc1, a0, a1, w);
        }
        int kk = rb * 4 + kloc;
        {
            float pq = fmaf(acc0[3], sv[s0 * 64 + i0 + 3], fmaf(acc0[2], sv[s0 * 64 + i0 + 2],
                       fmaf(acc0[1], sv[s0 * 64 + i0 + 1], acc0[0] * sv[s0 * 64 + i0])));
            unsafeAtomicAdd(&sq[s0 * 64 + kk], pq);
        }
        {
            float pq = fmaf(acc1[3], sv[s1 * 64 + i0 + 3], fmaf(acc1[2], sv[s1 * 64 + i0 + 2],
                       fmaf(acc1[1], sv[s1 * 64 + i0 + 1], acc1[0] * sv[s1 * 64 + i0])));
            unsafeAtomicAdd(&sq[s1 * 64 + kk], pq);
        }
    }
    __syncthreads();

    // r[m] = sum_k C[k,m] * (q[k] - gamma*BdotdE[k])
    if (tid < 256) {
        int s = tid >> 4, m = tid & 15;
        float gamma = sScal[s * 4 + 2] / sScal[s * 4 + 0];
        float r = 0.f;
        #pragma unroll 4
        for (int k = 0; k < 64; ++k) {
            float wv = sq[s * 64 + k] - gamma * sBdE[s * 64 + k];
            r = fmaf(sC[s * 1028 + k * 16 + m], wv, r);
        }
        sr[s * 16 + m] = r;
    }
    __syncthreads();
    // out_l += sum_m C[l,m] * r[m]
    for (int idx = tid; idx < SB * 64; idx += 512) {
        int s = idx >> 6, l = idx & 63;
        float o = 0.f;
        #pragma unroll
        for (int m2 = 0; m2 < 16; ++m2)
            o = fmaf(sC[s * 1028 + l * 16 + m2], sr[s * 16 + m2], o);
        int gi = (sbase + s) * 64 + l;
        dout[gi] = dout[gi] + o;
    }
}

extern "C" void kernel_launch(void* const* d_in, const int* in_sizes, int n_in,
                              void* d_out, int out_size, void* d_ws, size_t ws_size,
                              hipStream_t stream)
{
    (void)in_sizes; (void)n_in; (void)out_size;
    const float* y = (const float*)d_in[1];
    const float* W0[5]; const float* b0[5]; const float* W1[5]; const float* b1[5]; const float* W2[5];
    for (int m = 0; m < 5; ++m) {
        int base = 2 + m * 5;
        W0[m] = (const float*)d_in[base + 0];
        b0[m] = (const float*)d_in[base + 1];
        W1[m] = (const float*)d_in[base + 2];
        b1[m] = (const float*)d_in[base + 3];
        W2[m] = (const float*)d_in[base + 4];
    }
    float* ws = (float*)d_ws;
    float* dout = (float*)d_out;
    if (ws_size < (size_t)WS_FLOATS * sizeof(float)) return;

    for (int m = 0; m < 5; ++m) {
        hipLaunchKernelGGL(k_transpose, dim3((256 * 64 + 255) / 256), dim3(256), 0, stream,
                           W0[m], ws + OFF_W0T + m * 16384, 256, 64);
        hipLaunchKernelGGL(k_transpose, dim3((256 * 256 + 255) / 256), dim3(256), 0, stream,
                           W1[m], ws + OFF_W1T + m * 65536, 256, 256);
    }
    hipLaunchKernelGGL(k_transpose, dim3((2016 * 256 + 255) / 256), dim3(256), 0, stream,
                       W2[2], ws + OFF_W2PT, 2016, 256);
    hipLaunchKernelGGL(k_transpose, dim3((1024 * 256 + 255) / 256), dim3(256), 0, stream,
                       W2[3], ws + OFF_W2CT, 1024, 256);
    hipLaunchKernelGGL(k_transpose, dim3((4096 * 256 + 255) / 256), dim3(256), 0, stream,
                       W2[4], ws + OFF_W2BT, 4096, 256);
    hipLaunchKernelGGL(k_trilidx, dim3(8), dim3(256), 0, stream,
                       (int*)(ws + OFF_IT), (int*)(ws + OFF_JT));

    hipLaunchKernelGGL(k1_grads, dim3(1024), dim3(256), 0, stream,
                       y, ws,
                       W0[0], b0[0], W1[0], b1[0], W2[0],
                       W0[1], b0[1], W1[1], b1[1], W2[1],
                       ws + OFF_DE, ws + OFF_DS);
    hipLaunchKernelGGL(k2_poisson, dim3(1024), dim3(256), 0, stream, y, ws, b0[2], b1[2], dout);

    const int k3_smem = 148224;
    hipFuncSetAttribute((const void*)k3_friction, hipFuncAttributeMaxDynamicSharedMemorySize, k3_smem);
    hipLaunchKernelGGL(k3_friction, dim3(1024), dim3(512), k3_smem, stream,
                       y, ws, b0[3], b1[3], b0[4], b1[4], dout);
}

// Round 2
// 2737.556 us; speedup vs baseline: 1.7768x; 1.7768x over previous
//
#include <hip/hip_runtime.h>
#include <math.h>

// Problem constants: B=16384 samples, DIM=64, WIDTH=256, DD=64, C2=16
#define SB 16      // samples per workgroup
#define PAD 17     // LDS row pad for transposed [neuron][sample] tiles (k1/k2)

// ws layout (float offsets)
#define OFF_W0T  0            // 5 x (64x256)
#define OFF_W1T  81920        // 5 x (256x256)
#define OFF_W2PT 409600       // 256x2016
#define OFF_W2CT 925696       // 256x1024
#define OFF_W2BT 1187840      // 256x4096
#define OFF_DE   2236416      // 16384x64
#define OFF_DS   3284992      // 16384x64
#define OFF_IT   4333568      // 2016 int
#define OFF_JT   4335584      // 2016 int
#define WS_FLOATS 4337600     // ~17.35 MB

__device__ __forceinline__ void fma16(float* acc0, float* acc1, float a0, float a1,
                                      float4 wA, float4 wB) {
    float w[8] = {wA.x, wA.y, wA.z, wA.w, wB.x, wB.y, wB.z, wB.w};
    #pragma unroll
    for (int q = 0; q < 8; ++q) {
        acc0[q] = fmaf(a0, w[q], acc0[q]);
        acc1[q] = fmaf(a1, w[q], acc1[q]);
    }
}

__device__ __forceinline__ void fma8v(float* acc0, float* acc1, float a0, float a1, float4 w) {
    acc0[0] = fmaf(a0, w.x, acc0[0]); acc0[1] = fmaf(a0, w.y, acc0[1]);
    acc0[2] = fmaf(a0, w.z, acc0[2]); acc0[3] = fmaf(a0, w.w, acc0[3]);
    acc1[0] = fmaf(a1, w.x, acc1[0]); acc1[1] = fmaf(a1, w.y, acc1[1]);
    acc1[2] = fmaf(a1, w.z, acc1[2]); acc1[3] = fmaf(a1, w.w, acc1[3]);
}

__device__ __forceinline__ void fma4acc(float* a, float h, float4 w) {
    a[0] = fmaf(h, w.x, a[0]); a[1] = fmaf(h, w.y, a[1]);
    a[2] = fmaf(h, w.z, a[2]); a[3] = fmaf(h, w.w, a[3]);
}

__device__ __forceinline__ float dot4(const float* a, const float* b) {
    return fmaf(a[3], b[3], fmaf(a[2], b[2], fmaf(a[1], b[1], a[0] * b[0])));
}

// out[c*R + r] = in[r*C + c]   (in: R rows x C cols, row-major)
__global__ void k_transpose(const float* __restrict__ in, float* __restrict__ out, int R, int C) {
    int tid = blockIdx.x * blockDim.x + threadIdx.x;
    if (tid >= R * C) return;
    int c = tid / R, r = tid - c * R;
    out[tid] = in[r * C + c];
}

// tril_indices(64,-1) row-major: t = i*(i-1)/2 + j
__global__ void k_trilidx(int* __restrict__ it, int* __restrict__ jt) {
    int t = blockIdx.x * blockDim.x + threadIdx.x;
    if (t >= 2016) return;
    int i = (int)((1.0f + sqrtf(1.0f + 8.0f * (float)t)) * 0.5f);
    while (i * (i - 1) / 2 > t) --i;
    while ((i + 1) * i / 2 <= t) ++i;
    it[t] = i;
    jt[t] = t - i * (i - 1) / 2;
}

// ---------------- K1: dE, dS (energy/entropy forward + analytic backward) ----------------
__global__ __launch_bounds__(256) void k1_grads(
    const float* __restrict__ y, const float* __restrict__ ws,
    const float* __restrict__ W0E, const float* __restrict__ b0E,
    const float* __restrict__ W1E, const float* __restrict__ b1E,
    const float* __restrict__ w2E,
    const float* __restrict__ W0S, const float* __restrict__ b0S,
    const float* __restrict__ W1S, const float* __restrict__ b1S,
    const float* __restrict__ w2S,
    float* __restrict__ odE, float* __restrict__ odS)
{
    __shared__ float sYT[64][PAD];
    __shared__ float sH1T[256][PAD];
    __shared__ float sH2T[256][PAD];
    __shared__ float sUT[256][PAD];

    const int tid = threadIdx.x;
    const int sbase = blockIdx.x * SB;
    for (int idx = tid; idx < SB * 64; idx += 256) {
        int s = idx >> 6, i = idx & 63;
        sYT[i][s] = y[(sbase + s) * 64 + i];
    }
    __syncthreads();

    const int ts = tid >> 5, tn = tid & 31;
    const int s0 = 2 * ts, s1 = s0 + 1;

    for (int m = 0; m < 2; ++m) {
        const float* w0t = ws + OFF_W0T + m * 16384;
        const float* w1t = ws + OFF_W1T + m * 65536;
        const float* W0 = m ? W0S : W0E;
        const float* W1 = m ? W1S : W1E;
        const float* b0 = m ? b0S : b0E;
        const float* b1 = m ? b1S : b1E;
        const float* w2 = m ? w2S : w2E;
        float* outg = m ? odS : odE;

        // H1 = tanh(Y @ W0^T + b0), K=64
        {
            float acc0[8] = {0}, acc1[8] = {0};
            #pragma unroll 4
            for (int k = 0; k < 64; ++k) {
                float a0 = sYT[k][s0], a1 = sYT[k][s1];
                float4 wA = *(const float4*)(w0t + k * 256 + tn * 8);
                float4 wB = *(const float4*)(w0t + k * 256 + tn * 8 + 4);
                fma16(acc0, acc1, a0, a1, wA, wB);
            }
            #pragma unroll
            for (int q = 0; q < 8; ++q) {
                int j = tn * 8 + q;
                float b = b0[j];
                sH1T[j][s0] = tanhf(acc0[q] + b);
                sH1T[j][s1] = tanhf(acc1[q] + b);
            }
        }
        __syncthreads();
        // H2 = tanh(H1 @ W1^T + b1), K=256
        {
            float acc0[8] = {0}, acc1[8] = {0};
            #pragma unroll 4
            for (int k = 0; k < 256; ++k) {
                float a0 = sH1T[k][s0], a1 = sH1T[k][s1];
                float4 wA = *(const float4*)(w1t + k * 256 + tn * 8);
                float4 wB = *(const float4*)(w1t + k * 256 + tn * 8 + 4);
                fma16(acc0, acc1, a0, a1, wA, wB);
            }
            #pragma unroll
            for (int q = 0; q < 8; ++q) {
                int j = tn * 8 + q;
                float b = b1[j];
                sH2T[j][s0] = tanhf(acc0[q] + b);
                sH2T[j][s1] = tanhf(acc1[q] + b);
            }
        }
        __syncthreads();
        // G2 = (1 - H2^2) * w2  (in place)
        for (int idx = tid; idx < 256 * SB; idx += 256) {
            int j = idx >> 4, s = idx & 15;
            float h = sH2T[j][s];
            sH2T[j][s] = (1.f - h * h) * w2[j];
        }
        __syncthreads();
        // U = G2 @ W1 (natural layout), fused G1 = (1-H1^2)*U
        {
            float acc0[8] = {0}, acc1[8] = {0};
            #pragma unroll 4
            for (int k = 0; k < 256; ++k) {
                float a0 = sH2T[k][s0], a1 = sH2T[k][s1];
                float4 wA = *(const float4*)(W1 + k * 256 + tn * 8);
                float4 wB = *(const float4*)(W1 + k * 256 + tn * 8 + 4);
                fma16(acc0, acc1, a0, a1, wA, wB);
            }
            #pragma unroll
            for (int q = 0; q < 8; ++q) {
                int ko = tn * 8 + q;
                float h0 = sH1T[ko][s0], h1v = sH1T[ko][s1];
                sUT[ko][s0] = (1.f - h0 * h0) * acc0[q];
                sUT[ko][s1] = (1.f - h1v * h1v) * acc1[q];
            }
        }
        __syncthreads();
        // dE = G1 @ W0 (natural layout)
        {
            float a00 = 0, a01 = 0, a10 = 0, a11 = 0;
            #pragma unroll 4
            for (int k = 0; k < 256; ++k) {
                float g0 = sUT[k][s0], g1 = sUT[k][s1];
                float2 w = *(const float2*)(W0 + k * 64 + tn * 2);
                a00 = fmaf(g0, w.x, a00); a01 = fmaf(g0, w.y, a01);
                a10 = fmaf(g1, w.x, a10); a11 = fmaf(g1, w.y, a11);
            }
            outg[(sbase + s0) * 64 + tn * 2]     = a00;
            outg[(sbase + s0) * 64 + tn * 2 + 1] = a01;
            outg[(sbase + s1) * 64 + tn * 2]     = a10;
            outg[(sbase + s1) * 64 + tn * 2 + 1] = a11;
        }
        __syncthreads();
    }
}

// ---------------- K2: pA head + poisson, writes d_out ----------------
__global__ __launch_bounds__(256) void k2_poisson(
    const float* __restrict__ y, const float* __restrict__ ws,
    const float* __restrict__ b0P, const float* __restrict__ b1P,
    float* __restrict__ dout)
{
    __shared__ float sYT[64][PAD];
    __shared__ float sH1T[256][PAD];
    __shared__ float sH2T[256][PAD];
    __shared__ float sdE[SB][64], sdS[SB][64];
    __shared__ float sAdE[SB][64], sAdS[SB][64];
    __shared__ int sIT[256], sJT[256];
    __shared__ float sScal[SB][4];

    const int tid = threadIdx.x;
    const int sbase = blockIdx.x * SB;
    const float* gdE = ws + OFF_DE;
    const float* gdS = ws + OFF_DS;

    for (int idx = tid; idx < SB * 64; idx += 256) {
        int s = idx >> 6, i = idx & 63;
        sYT[i][s] = y[(sbase + s) * 64 + i];
        sdE[s][i] = gdE[sbase * 64 + idx];
        sdS[s][i] = gdS[sbase * 64 + idx];
        sAdE[s][i] = 0.f; sAdS[s][i] = 0.f;
    }
    if (tid < SB * 4) ((float*)sScal)[tid] = 0.f;
    __syncthreads();

    const int ts = tid >> 5, tn = tid & 31;
    const int s0 = 2 * ts, s1 = s0 + 1;
    const float* w0t = ws + OFF_W0T + 2 * 16384;
    const float* w1t = ws + OFF_W1T + 2 * 65536;

    // pA forward H1
    {
        float acc0[8] = {0}, acc1[8] = {0};
        #pragma unroll 4
        for (int k = 0; k < 64; ++k) {
            float a0 = sYT[k][s0], a1 = sYT[k][s1];
            float4 wA = *(const float4*)(w0t + k * 256 + tn * 8);
            float4 wB = *(const float4*)(w0t + k * 256 + tn * 8 + 4);
            fma16(acc0, acc1, a0, a1, wA, wB);
        }
        #pragma unroll
        for (int q = 0; q < 8; ++q) {
            int j = tn * 8 + q;
            float b = b0P[j];
            sH1T[j][s0] = tanhf(acc0[q] + b);
            sH1T[j][s1] = tanhf(acc1[q] + b);
        }
    }
    __syncthreads();
    // pA forward H2
    {
        float acc0[8] = {0}, acc1[8] = {0};
        #pragma unroll 4
        for (int k = 0; k < 256; ++k) {
            float a0 = sH1T[k][s0], a1 = sH1T[k][s1];
            float4 wA = *(const float4*)(w1t + k * 256 + tn * 8);
            float4 wB = *(const float4*)(w1t + k * 256 + tn * 8 + 4);
            fma16(acc0, acc1, a0, a1, wA, wB);
        }
        #pragma unroll
        for (int q = 0; q < 8; ++q) {
            int j = tn * 8 + q;
            float b = b1P[j];
            sH2T[j][s0] = tanhf(acc0[q] + b);
            sH2T[j][s1] = tanhf(acc1[q] + b);
        }
    }
    __syncthreads();

    const float* w2pt = ws + OFF_W2PT;
    const int* itab = (const int*)(ws + OFF_IT);
    const int* jtab = (const int*)(ws + OFF_JT);

    for (int ch = 0; ch < 8; ++ch) {
        int cb = ch * 256;
        int nlim = 2016 - cb; if (nlim > 256) nlim = 256;
        for (int idx = tid; idx < nlim; idx += 256) {
            sIT[idx] = itab[cb + idx];
            sJT[idx] = jtab[cb + idx];
        }
        __syncthreads();
        if (tn * 8 < nlim) {
            float acc0[8] = {0}, acc1[8] = {0};
            #pragma unroll 4
            for (int k = 0; k < 256; ++k) {
                float a0 = sH2T[k][s0], a1 = sH2T[k][s1];
                float4 wA = *(const float4*)(w2pt + k * 2016 + cb + tn * 8);
                float4 wB = *(const float4*)(w2pt + k * 2016 + cb + tn * 8 + 4);
                fma16(acc0, acc1, a0, a1, wA, wB);
            }
            // scatter: AdE_i += a*dE_j ; AdE_j -= a*dE_i (antisymmetric A)
            #pragma unroll
            for (int q = 0; q < 8; ++q) {
                int tt = tn * 8 + q;
                int i = sIT[tt], j = sJT[tt];
                float a0v = acc0[q], a1v = acc1[q];
                unsafeAtomicAdd(&sAdE[s0][i],  a0v * sdE[s0][j]);
                unsafeAtomicAdd(&sAdE[s0][j], -a0v * sdE[s0][i]);
                unsafeAtomicAdd(&sAdS[s0][i],  a0v * sdS[s0][j]);
                unsafeAtomicAdd(&sAdS[s0][j], -a0v * sdS[s0][i]);
                unsafeAtomicAdd(&sAdE[s1][i],  a1v * sdE[s1][j]);
                unsafeAtomicAdd(&sAdE[s1][j], -a1v * sdE[s1][i]);
                unsafeAtomicAdd(&sAdS[s1][i],  a1v * sdS[s1][j]);
                unsafeAtomicAdd(&sAdS[s1][j], -a1v * sdS[s1][i]);
            }
        }
        __syncthreads();
    }

    // scalars: [0]=dE.AdS  [1]=dE.dS  [2]=dS.dS
    for (int idx = tid; idx < SB * 64; idx += 256) {
        int s = idx >> 6, i = idx & 63;
        float de = sdE[s][i], dsv = sdS[s][i];
        unsafeAtomicAdd(&sScal[s][0], de * sAdS[s][i]);
        unsafeAtomicAdd(&sScal[s][1], de * dsv);
        unsafeAtomicAdd(&sScal[s][2], dsv * dsv);
    }
    __syncthreads();
    for (int idx = tid; idx < SB * 64; idx += 256) {
        int s = idx >> 6, i = idx & 63;
        float res = sAdE[s][i] + (sScal[s][0] * sdS[s][i] - sScal[s][1] * sAdS[s][i]) / sScal[s][2];
        dout[(sbase + s) * 64 + i] = res;
    }
}

// ---------------- K3: fC/fB heads + friction, accumulates into d_out ----------------
// 512 threads. Activations stored [sample][neuron] (broadcast reads, float4 writes).
// Bm kept in registers (bm[4][8][4]) between pass1 (B.dE, B.dS) and pass2 (B.v):
// eliminates the 256x4096 recompute GEMM. Reductions over i via 16-lane shfl_xor.
__global__ __launch_bounds__(512) void k3_friction(
    const float* __restrict__ y, const float* __restrict__ ws,
    const float* __restrict__ b0C, const float* __restrict__ b1C,
    const float* __restrict__ b0B, const float* __restrict__ b1B,
    float* __restrict__ dout)
{
    extern __shared__ float smem[];
    float* sYT  = smem;               // 16*64   [s][i]
    float* sA   = sYT + 1024;         // 16*256  [s][n]  (H1)
    float* sB   = sA + 4096;          // 16*256  [s][n]  (H2c then H2b)
    float* sC   = sB + 4096;          // 16*1089: C[s][k*17 + m], k<64, m<16 (pad 17 kills stride-16 conflicts)
    float* sdE  = sC + 17424;         // 16*64
    float* sdS  = sdE + 1024;
    float* sBdE = sdS + 1024;
    float* sBdS = sBdE + 1024;
    float* sv   = sBdS + 1024;
    float* sq   = sv + 1024;
    float* sScal = sq + 1024;         // 16*4: [0]=dE.dE [1]=dE.dS [2]=dE.v
    float* sr   = sScal + 64;         // 16*16
    // total = 33104 floats = 132416 B

    const int tid = threadIdx.x;
    const int sbase = blockIdx.x * SB;
    const float* gdE = ws + OFF_DE;
    const float* gdS = ws + OFF_DS;

    for (int idx = tid; idx < SB * 64; idx += 512) {
        sYT[idx] = y[sbase * 64 + idx];     // [s][i] contiguous
        sdE[idx] = gdE[sbase * 64 + idx];
        sdS[idx] = gdS[sbase * 64 + idx];
    }
    if (tid < 64) sScal[tid] = 0.f;
    __syncthreads();

    // dE.dE, dE.dS (consumed much later; barriers in between guarantee visibility)
    for (int idx = tid; idx < SB * 64; idx += 512) {
        int s = idx >> 6;
        float de = sdE[idx];
        unsafeAtomicAdd(&sScal[s * 4 + 0], de * de);
        unsafeAtomicAdd(&sScal[s * 4 + 1], de * sdS[idx]);
    }

    // ---- forward layers: 2-sample mapping (256 outputs) ----
    const int ts = tid >> 6, tn = tid & 63, n4 = tn * 4;
    const int fs0 = 2 * ts, fs1 = fs0 + 1;

    // ---- 4-sample mapping for wide GEMMs ----
    const int sgrp = tid >> 7;          // 0..3
    const int c    = tid & 127;         // 0..127
    const int sb4  = sgrp * 4;          // base sample
    const int i0   = 4 * (c & 15);      // dE/dS/v segment per lane
    const int khi  = c >> 4;            // 0..7 (includes wave-half bit)

    // ============ fC forward ============
    {
        const float* w0t = ws + OFF_W0T + 3 * 16384;
        float acc0[4] = {0}, acc1[4] = {0};
        #pragma unroll 4
        for (int k = 0; k < 64; ++k) {
            float a0 = sYT[fs0 * 64 + k], a1 = sYT[fs1 * 64 + k];
            float4 w = *(const float4*)(w0t + k * 256 + n4);
            fma8v(acc0, acc1, a0, a1, w);
        }
        float4 o0, o1;
        o0.x = tanhf(acc0[0] + b0C[n4]);     o1.x = tanhf(acc1[0] + b0C[n4]);
        o0.y = tanhf(acc0[1] + b0C[n4 + 1]); o1.y = tanhf(acc1[1] + b0C[n4 + 1]);
        o0.z = tanhf(acc0[2] + b0C[n4 + 2]); o1.z = tanhf(acc1[2] + b0C[n4 + 2]);
        o0.w = tanhf(acc0[3] + b0C[n4 + 3]); o1.w = tanhf(acc1[3] + b0C[n4 + 3]);
        *(float4*)(sA + fs0 * 256 + n4) = o0;
        *(float4*)(sA + fs1 * 256 + n4) = o1;
    }
    __syncthreads();
    {
        const float* w1t = ws + OFF_W1T + 3 * 65536;
        float acc0[4] = {0}, acc1[4] = {0};
        #pragma unroll 4
        for (int k = 0; k < 256; ++k) {
            float a0 = sA[fs0 * 256 + k], a1 = sA[fs1 * 256 + k];
            float4 w = *(const float4*)(w1t + k * 256 + n4);
            fma8v(acc0, acc1, a0, a1, w);
        }
        float4 o0, o1;
        o0.x = tanhf(acc0[0] + b1C[n4]);     o1.x = tanhf(acc1[0] + b1C[n4]);
        o0.y = tanhf(acc0[1] + b1C[n4 + 1]); o1.y = tanhf(acc1[1] + b1C[n4 + 1]);
        o0.z = tanhf(acc0[2] + b1C[n4 + 2]); o1.z = tanhf(acc1[2] + b1C[n4 + 2]);
        o0.w = tanhf(acc0[3] + b1C[n4 + 3]); o1.w = tanhf(acc1[3] + b1C[n4 + 3]);
        *(float4*)(sB + fs0 * 256 + n4) = o0;
        *(float4*)(sB + fs1 * 256 + n4) = o1;
    }
    __syncthreads();

    // ============ C head: 4 samples/thread, n = cc2*512 + 4c + q ============
    {
        const float* w2ct = ws + OFF_W2CT + 4 * c;
        #pragma unroll
        for (int cc2 = 0; cc2 < 2; ++cc2) {
            float a0[4] = {0}, a1[4] = {0}, a2[4] = {0}, a3[4] = {0};
            #pragma unroll 2
            for (int k = 0; k < 256; ++k) {
                float4 w = *(const float4*)(w2ct + k * 1024 + cc2 * 512);
                float h0 = sB[(sb4 + 0) * 256 + k];
                float h1 = sB[(sb4 + 1) * 256 + k];
                float h2 = sB[(sb4 + 2) * 256 + k];
                float h3 = sB[(sb4 + 3) * 256 + k];
                fma4acc(a0, h0, w); fma4acc(a1, h1, w);
                fma4acc(a2, h2, w); fma4acc(a3, h3, w);
            }
            int kC = cc2 * 32 + (c >> 2);
            int mC = 4 * (c & 3);
            float* p0 = sC + (sb4 + 0) * 1089 + kC * 17 + mC;
            float* p1 = sC + (sb4 + 1) * 1089 + kC * 17 + mC;
            float* p2 = sC + (sb4 + 2) * 1089 + kC * 17 + mC;
            float* p3 = sC + (sb4 + 3) * 1089 + kC * 17 + mC;
            #pragma unroll
            for (int q = 0; q < 4; ++q) {
                p0[q] = a0[q]; p1[q] = a1[q]; p2[q] = a2[q]; p3[q] = a3[q];
            }
        }
    }
    __syncthreads();

    // ============ fB forward (reuse sA, sB) ============
    {
        const float* w0t = ws + OFF_W0T + 4 * 16384;
        float acc0[4] = {0}, acc1[4] = {0};
        #pragma unroll 4
        for (int k = 0; k < 64; ++k) {
            float a0 = sYT[fs0 * 64 + k], a1 = sYT[fs1 * 64 + k];
            float4 w = *(const float4*)(w0t + k * 256 + n4);
            fma8v(acc0, acc1, a0, a1, w);
        }
        float4 o0, o1;
        o0.x = tanhf(acc0[0] + b0B[n4]);     o1.x = tanhf(acc1[0] + b0B[n4]);
        o0.y = tanhf(acc0[1] + b0B[n4 + 1]); o1.y = tanhf(acc1[1] + b0B[n4 + 1]);
        o0.z = tanhf(acc0[2] + b0B[n4 + 2]); o1.z = tanhf(acc1[2] + b0B[n4 + 2]);
        o0.w = tanhf(acc0[3] + b0B[n4 + 3]); o1.w = tanhf(acc1[3] + b0B[n4 + 3]);
        *(float4*)(sA + fs0 * 256 + n4) = o0;
        *(float4*)(sA + fs1 * 256 + n4) = o1;
    }
    __syncthreads();
    {
        const float* w1t = ws + OFF_W1T + 4 * 65536;
        float acc0[4] = {0}, acc1[4] = {0};
        #pragma unroll 4
        for (int k = 0; k < 256; ++k) {
            float a0 = sA[fs0 * 256 + k], a1 = sA[fs1 * 256 + k];
            float4 w = *(const float4*)(w1t + k * 256 + n4);
            fma8v(acc0, acc1, a0, a1, w);
        }
        float4 o0, o1;
        o0.x = tanhf(acc0[0] + b1B[n4]);     o1.x = tanhf(acc1[0] + b1B[n4]);
        o0.y = tanhf(acc0[1] + b1B[n4 + 1]); o1.y = tanhf(acc1[1] + b1B[n4 + 1]);
        o0.z = tanhf(acc0[2] + b1B[n4 + 2]); o1.z = tanhf(acc1[2] + b1B[n4 + 2]);
        o0.w = tanhf(acc0[3] + b1B[n4 + 3]); o1.w = tanhf(acc1[3] + b1B[n4 + 3]);
        *(float4*)(sB + fs0 * 256 + n4) = o0;
        *(float4*)(sB + fs1 * 256 + n4) = o1;
    }
    __syncthreads();

    // ============ pass1: Bm into registers + BdotdE/BdotdS ============
    // n = rb2*512 + 4c + q  ->  k' = rb2*8 + khi,  i = i0 + q
    float bm[4][8][4];
    #pragma unroll
    for (int s = 0; s < 4; ++s)
        #pragma unroll
        for (int r2 = 0; r2 < 8; ++r2)
            #pragma unroll
            for (int q = 0; q < 4; ++q) bm[s][r2][q] = 0.f;

    {
        const float* wb = ws + OFF_W2BT + 4 * c;
        for (int k = 0; k < 256; ++k) {
            float h0 = sB[(sb4 + 0) * 256 + k];
            float h1 = sB[(sb4 + 1) * 256 + k];
            float h2 = sB[(sb4 + 2) * 256 + k];
            float h3 = sB[(sb4 + 3) * 256 + k];
            const float* wk = wb + k * 4096;
            #pragma unroll
            for (int r2 = 0; r2 < 8; ++r2) {
                float4 w = *(const float4*)(wk + r2 * 512);
                fma4acc(bm[0][r2], h0, w);
                fma4acc(bm[1][r2], h1, w);
                fma4acc(bm[2][r2], h2, w);
                fma4acc(bm[3][r2], h3, w);
            }
        }
    }
    // dots with dE, dS; 16-lane shfl reduction over i
    #pragma unroll
    for (int r2 = 0; r2 < 8; ++r2) {
        #pragma unroll
        for (int s = 0; s < 4; ++s) {
            float pd = dot4(bm[s][r2], sdE + (sb4 + s) * 64 + i0);
            float ps = dot4(bm[s][r2], sdS + (sb4 + s) * 64 + i0);
            pd += __shfl_xor(pd, 1); ps += __shfl_xor(ps, 1);
            pd += __shfl_xor(pd, 2); ps += __shfl_xor(ps, 2);
            pd += __shfl_xor(pd, 4); ps += __shfl_xor(ps, 4);
            pd += __shfl_xor(pd, 8); ps += __shfl_xor(ps, 8);
            if ((c & 15) == 0) {
                int kk = r2 * 8 + khi;
                sBdE[(sb4 + s) * 64 + kk] = pd;
                sBdS[(sb4 + s) * 64 + kk] = ps;
            }
        }
    }
    __syncthreads();

    // v = BdS - beta*BdE
    for (int idx = tid; idx < SB * 64; idx += 512) {
        int s = idx >> 6;
        float beta = sScal[s * 4 + 1] / sScal[s * 4 + 0];
        sv[idx] = sBdS[idx] - beta * sBdE[idx];
    }
    __syncthreads();
    for (int idx = tid; idx < SB * 64; idx += 512) {
        int s = idx >> 6;
        unsafeAtomicAdd(&sScal[s * 4 + 2], sdE[idx] * sv[idx]);
    }
    __syncthreads();

    // ============ pass2: q = Bm @ v from registers ============
    #pragma unroll
    for (int r2 = 0; r2 < 8; ++r2) {
        #pragma unroll
        for (int s = 0; s < 4; ++s) {
            float pq = dot4(bm[s][r2], sv + (sb4 + s) * 64 + i0);
            pq += __shfl_xor(pq, 1);
            pq += __shfl_xor(pq, 2);
            pq += __shfl_xor(pq, 4);
            pq += __shfl_xor(pq, 8);
            if ((c & 15) == 0) sq[(sb4 + s) * 64 + r2 * 8 + khi] = pq;
        }
    }
    __syncthreads();

    // r[m] = sum_k C[k,m] * (q[k] - gamma*BdE[k])
    if (tid < 256) {
        int s = tid >> 4, m = tid & 15;
        float gamma = sScal[s * 4 + 2] / sScal[s * 4 + 0];
        float r = 0.f;
        #pragma unroll 4
        for (int k = 0; k < 64; ++k) {
            float wv = sq[s * 64 + k] - gamma * sBdE[s * 64 + k];
            r = fmaf(sC[s * 1089 + k * 17 + m], wv, r);
        }
        sr[s * 16 + m] = r;
    }
    __syncthreads();
    // out_k += sum_m C[k,m] * r[m]
    for (int idx = tid; idx < SB * 64; idx += 512) {
        int s = idx >> 6, k = idx & 63;
        float o = 0.f;
        #pragma unroll
        for (int m2 = 0; m2 < 16; ++m2)
            o = fmaf(sC[s * 1089 + k * 17 + m2], sr[s * 16 + m2], o);
        int gi = sbase * 64 + idx;
        dout[gi] = dout[gi] + o;
    }
}

extern "C" void kernel_launch(void* const* d_in, const int* in_sizes, int n_in,
                              void* d_out, int out_size, void* d_ws, size_t ws_size,
                              hipStream_t stream)
{
    (void)in_sizes; (void)n_in; (void)out_size;
    const float* y = (const float*)d_in[1];
    const float* W0[5]; const float* b0[5]; const float* W1[5]; const float* b1[5]; const float* W2[5];
    for (int m = 0; m < 5; ++m) {
        int base = 2 + m * 5;
        W0[m] = (const float*)d_in[base + 0];
        b0[m] = (const float*)d_in[base + 1];
        W1[m] = (const float*)d_in[base + 2];
        b1[m] = (const float*)d_in[base + 3];
        W2[m] = (const float*)d_in[base + 4];
    }
    float* ws = (float*)d_ws;
    float* dout = (float*)d_out;
    if (ws_size < (size_t)WS_FLOATS * sizeof(float)) return;

    for (int m = 0; m < 5; ++m) {
        hipLaunchKernelGGL(k_transpose, dim3((256 * 64 + 255) / 256), dim3(256), 0, stream,
                           W0[m], ws + OFF_W0T + m * 16384, 256, 64);
        hipLaunchKernelGGL(k_transpose, dim3((256 * 256 + 255) / 256), dim3(256), 0, stream,
                           W1[m], ws + OFF_W1T + m * 65536, 256, 256);
    }
    hipLaunchKernelGGL(k_transpose, dim3((2016 * 256 + 255) / 256), dim3(256), 0, stream,
                       W2[2], ws + OFF_W2PT, 2016, 256);
    hipLaunchKernelGGL(k_transpose, dim3((1024 * 256 + 255) / 256), dim3(256), 0, stream,
                       W2[3], ws + OFF_W2CT, 1024, 256);
    hipLaunchKernelGGL(k_transpose, dim3((4096 * 256 + 255) / 256), dim3(256), 0, stream,
                       W2[4], ws + OFF_W2BT, 4096, 256);
    hipLaunchKernelGGL(k_trilidx, dim3(8), dim3(256), 0, stream,
                       (int*)(ws + OFF_IT), (int*)(ws + OFF_JT));

    hipLaunchKernelGGL(k1_grads, dim3(1024), dim3(256), 0, stream,
                       y, ws,
                       W0[0], b0[0], W1[0], b1[0], W2[0],
                       W0[1], b0[1], W1[1], b1[1], W2[1],
                       ws + OFF_DE, ws + OFF_DS);
    hipLaunchKernelGGL(k2_poisson, dim3(1024), dim3(256), 0, stream, y, ws, b0[2], b1[2], dout);

    const int k3_smem = 132416;
    hipFuncSetAttribute((const void*)k3_friction, hipFuncAttributeMaxDynamicSharedMemorySize, k3_smem);
    hipLaunchKernelGGL(k3_friction, dim3(1024), dim3(512), k3_smem, stream,
                       y, ws, b0[3], b1[3], b0[4], b1[4], dout);
}

// Round 3
// 2120.761 us; speedup vs baseline: 2.2935x; 1.2908x over previous
//
#include <hip/hip_runtime.h>
#include <math.h>

// Problem constants: B=16384 samples, DIM=64, WIDTH=256, DD=64, C2=16
#define SB 16      // samples per workgroup
#define PAD 17     // LDS row pad for transposed [neuron][sample] tiles (k1)

// ws layout (float offsets)
#define OFF_W0T  0            // 5 x (64x256)
#define OFF_W1T  81920        // 5 x (256x256)
#define OFF_W2PT 409600       // 256x2016
#define OFF_W2CT 925696       // 256x1024
#define OFF_W2BT 1187840      // 256x4096
#define OFF_DE   2236416      // 16384x64
#define OFF_DS   3284992      // 16384x64
#define WS_FLOATS 4337600     // ~17.35 MB

__device__ __forceinline__ void fma16(float* acc0, float* acc1, float a0, float a1,
                                      float4 wA, float4 wB) {
    float w[8] = {wA.x, wA.y, wA.z, wA.w, wB.x, wB.y, wB.z, wB.w};
    #pragma unroll
    for (int q = 0; q < 8; ++q) {
        acc0[q] = fmaf(a0, w[q], acc0[q]);
        acc1[q] = fmaf(a1, w[q], acc1[q]);
    }
}

__device__ __forceinline__ void fma8v(float* acc0, float* acc1, float a0, float a1, float4 w) {
    acc0[0] = fmaf(a0, w.x, acc0[0]); acc0[1] = fmaf(a0, w.y, acc0[1]);
    acc0[2] = fmaf(a0, w.z, acc0[2]); acc0[3] = fmaf(a0, w.w, acc0[3]);
    acc1[0] = fmaf(a1, w.x, acc1[0]); acc1[1] = fmaf(a1, w.y, acc1[1]);
    acc1[2] = fmaf(a1, w.z, acc1[2]); acc1[3] = fmaf(a1, w.w, acc1[3]);
}

__device__ __forceinline__ void fma4acc(float* a, float h, float4 w) {
    a[0] = fmaf(h, w.x, a[0]); a[1] = fmaf(h, w.y, a[1]);
    a[2] = fmaf(h, w.z, a[2]); a[3] = fmaf(h, w.w, a[3]);
}

__device__ __forceinline__ float dot4(const float* a, const float* b) {
    return fmaf(a[3], b[3], fmaf(a[2], b[2], fmaf(a[1], b[1], a[0] * b[0])));
}

// out[c*R + r] = in[r*C + c]   (in: R rows x C cols, row-major)
__global__ void k_transpose(const float* __restrict__ in, float* __restrict__ out, int R, int C) {
    int tid = blockIdx.x * blockDim.x + threadIdx.x;
    if (tid >= R * C) return;
    int c = tid / R, r = tid - c * R;
    out[tid] = in[r * C + c];
}

// ---------------- K1: dE, dS (energy/entropy forward + analytic backward) ----------------
__global__ __launch_bounds__(256) void k1_grads(
    const float* __restrict__ y, const float* __restrict__ ws,
    const float* __restrict__ W0E, const float* __restrict__ b0E,
    const float* __restrict__ W1E, const float* __restrict__ b1E,
    const float* __restrict__ w2E,
    const float* __restrict__ W0S, const float* __restrict__ b0S,
    const float* __restrict__ W1S, const float* __restrict__ b1S,
    const float* __restrict__ w2S,
    float* __restrict__ odE, float* __restrict__ odS)
{
    __shared__ float sYT[64][PAD];
    __shared__ float sH1T[256][PAD];
    __shared__ float sH2T[256][PAD];
    __shared__ float sUT[256][PAD];

    const int tid = threadIdx.x;
    const int sbase = blockIdx.x * SB;
    for (int idx = tid; idx < SB * 64; idx += 256) {
        int s = idx >> 6, i = idx & 63;
        sYT[i][s] = y[(sbase + s) * 64 + i];
    }
    __syncthreads();

    const int ts = tid >> 5, tn = tid & 31;
    const int s0 = 2 * ts, s1 = s0 + 1;

    for (int m = 0; m < 2; ++m) {
        const float* w0t = ws + OFF_W0T + m * 16384;
        const float* w1t = ws + OFF_W1T + m * 65536;
        const float* W0 = m ? W0S : W0E;
        const float* W1 = m ? W1S : W1E;
        const float* b0 = m ? b0S : b0E;
        const float* b1 = m ? b1S : b1E;
        const float* w2 = m ? w2S : w2E;
        float* outg = m ? odS : odE;

        // H1 = tanh(Y @ W0^T + b0), K=64
        {
            float acc0[8] = {0}, acc1[8] = {0};
            #pragma unroll 4
            for (int k = 0; k < 64; ++k) {
                float a0 = sYT[k][s0], a1 = sYT[k][s1];
                float4 wA = *(const float4*)(w0t + k * 256 + tn * 8);
                float4 wB = *(const float4*)(w0t + k * 256 + tn * 8 + 4);
                fma16(acc0, acc1, a0, a1, wA, wB);
            }
            #pragma unroll
            for (int q = 0; q < 8; ++q) {
                int j = tn * 8 + q;
                float b = b0[j];
                sH1T[j][s0] = tanhf(acc0[q] + b);
                sH1T[j][s1] = tanhf(acc1[q] + b);
            }
        }
        __syncthreads();
        // H2 = tanh(H1 @ W1^T + b1), K=256
        {
            float acc0[8] = {0}, acc1[8] = {0};
            #pragma unroll 4
            for (int k = 0; k < 256; ++k) {
                float a0 = sH1T[k][s0], a1 = sH1T[k][s1];
                float4 wA = *(const float4*)(w1t + k * 256 + tn * 8);
                float4 wB = *(const float4*)(w1t + k * 256 + tn * 8 + 4);
                fma16(acc0, acc1, a0, a1, wA, wB);
            }
            #pragma unroll
            for (int q = 0; q < 8; ++q) {
                int j = tn * 8 + q;
                float b = b1[j];
                sH2T[j][s0] = tanhf(acc0[q] + b);
                sH2T[j][s1] = tanhf(acc1[q] + b);
            }
        }
        __syncthreads();
        // G2 = (1 - H2^2) * w2  (in place)
        for (int idx = tid; idx < 256 * SB; idx += 256) {
            int j = idx >> 4, s = idx & 15;
            float h = sH2T[j][s];
            sH2T[j][s] = (1.f - h * h) * w2[j];
        }
        __syncthreads();
        // U = G2 @ W1 (natural layout), fused G1 = (1-H1^2)*U
        {
            float acc0[8] = {0}, acc1[8] = {0};
            #pragma unroll 4
            for (int k = 0; k < 256; ++k) {
                float a0 = sH2T[k][s0], a1 = sH2T[k][s1];
                float4 wA = *(const float4*)(W1 + k * 256 + tn * 8);
                float4 wB = *(const float4*)(W1 + k * 256 + tn * 8 + 4);
                fma16(acc0, acc1, a0, a1, wA, wB);
            }
            #pragma unroll
            for (int q = 0; q < 8; ++q) {
                int ko = tn * 8 + q;
                float h0 = sH1T[ko][s0], h1v = sH1T[ko][s1];
                sUT[ko][s0] = (1.f - h0 * h0) * acc0[q];
                sUT[ko][s1] = (1.f - h1v * h1v) * acc1[q];
            }
        }
        __syncthreads();
        // dE = G1 @ W0 (natural layout)
        {
            float a00 = 0, a01 = 0, a10 = 0, a11 = 0;
            #pragma unroll 4
            for (int k = 0; k < 256; ++k) {
                float g0 = sUT[k][s0], g1 = sUT[k][s1];
                float2 w = *(const float2*)(W0 + k * 64 + tn * 2);
                a00 = fmaf(g0, w.x, a00); a01 = fmaf(g0, w.y, a01);
                a10 = fmaf(g1, w.x, a10); a11 = fmaf(g1, w.y, a11);
            }
            outg[(sbase + s0) * 64 + tn * 2]     = a00;
            outg[(sbase + s0) * 64 + tn * 2 + 1] = a01;
            outg[(sbase + s1) * 64 + tn * 2]     = a10;
            outg[(sbase + s1) * 64 + tn * 2 + 1] = a11;
        }
        __syncthreads();
    }
}

// ---------------- K2: pA head + poisson (atomic-free), writes d_out ----------------
// 512 threads, 16 samples/block, 1 block/CU (150 KB LDS).
// Phase F: forward H1,H2 (2 samples/thread).
// Phase G: a = H2 @ W2P^T, 4 samples/thread, plain float4 stores into sa[s][t].
// Phase R: gather AdE_i/AdS_i via branch-free triangular indexing; shfl scalars;
//          output written straight from registers. Zero atomics, 5 barriers.
__global__ __launch_bounds__(512) void k2_poisson(
    const float* __restrict__ y, const float* __restrict__ ws,
    const float* __restrict__ b0P, const float* __restrict__ b1P,
    float* __restrict__ dout)
{
    extern __shared__ float smem[];
    float* sa  = smem;            // 16 x 2024 (a-values, padded). Aliased: H1 @ [0,4096), y @ [4096,5120)
    float* sH2 = smem + 32384;    // 16 x 256
    float* sdE = sH2 + 4096;      // 16 x 64
    float* sdS = sdE + 1024;      // 16 x 64
    // total 38528 floats = 154112 B

    float* sH1 = sa;              // alias (dead before a-GEMM writes)
    float* sy  = sa + 4096;       // alias (dead after H1)

    const int tid = threadIdx.x;
    const int sbase = blockIdx.x * SB;
    const float* gdE = ws + OFF_DE;
    const float* gdS = ws + OFF_DS;

    // P0: load y, dE, dS ([s][i] contiguous)
    for (int idx = tid; idx < SB * 64; idx += 512) {
        sy[idx]  = y[sbase * 64 + idx];
        sdE[idx] = gdE[sbase * 64 + idx];
        sdS[idx] = gdS[sbase * 64 + idx];
    }
    __syncthreads();

    const int ts = tid >> 6, tn = tid & 63, n4 = tn * 4;
    const int fs0 = 2 * ts, fs1 = fs0 + 1;

    // P1: H1 = tanh(y @ W0^T + b0)
    {
        const float* w0t = ws + OFF_W0T + 2 * 16384;
        float acc0[4] = {0}, acc1[4] = {0};
        #pragma unroll 4
        for (int k = 0; k < 64; ++k) {
            float a0 = sy[fs0 * 64 + k], a1 = sy[fs1 * 64 + k];
            float4 w = *(const float4*)(w0t + k * 256 + n4);
            fma8v(acc0, acc1, a0, a1, w);
        }
        float4 o0, o1;
        o0.x = tanhf(acc0[0] + b0P[n4]);     o1.x = tanhf(acc1[0] + b0P[n4]);
        o0.y = tanhf(acc0[1] + b0P[n4 + 1]); o1.y = tanhf(acc1[1] + b0P[n4 + 1]);
        o0.z = tanhf(acc0[2] + b0P[n4 + 2]); o1.z = tanhf(acc1[2] + b0P[n4 + 2]);
        o0.w = tanhf(acc0[3] + b0P[n4 + 3]); o1.w = tanhf(acc1[3] + b0P[n4 + 3]);
        *(float4*)(sH1 + fs0 * 256 + n4) = o0;
        *(float4*)(sH1 + fs1 * 256 + n4) = o1;
    }
    __syncthreads();

    // P2: H2 = tanh(H1 @ W1^T + b1)
    {
        const float* w1t = ws + OFF_W1T + 2 * 65536;
        float acc0[4] = {0}, acc1[4] = {0};
        #pragma unroll 4
        for (int k = 0; k < 256; ++k) {
            float a0 = sH1[fs0 * 256 + k], a1 = sH1[fs1 * 256 + k];
            float4 w = *(const float4*)(w1t + k * 256 + n4);
            fma8v(acc0, acc1, a0, a1, w);
        }
        float4 o0, o1;
        o0.x = tanhf(acc0[0] + b1P[n4]);     o1.x = tanhf(acc1[0] + b1P[n4]);
        o0.y = tanhf(acc0[1] + b1P[n4 + 1]); o1.y = tanhf(acc1[1] + b1P[n4 + 1]);
        o0.z = tanhf(acc0[2] + b1P[n4 + 2]); o1.z = tanhf(acc1[2] + b1P[n4 + 2]);
        o0.w = tanhf(acc0[3] + b1P[n4 + 3]); o1.w = tanhf(acc1[3] + b1P[n4 + 3]);
        *(float4*)(sH2 + fs0 * 256 + n4) = o0;
        *(float4*)(sH2 + fs1 * 256 + n4) = o1;
    }
    __syncthreads();   // H1/y regions dead; sa fully writable

    // P3: a-GEMM. 4 samples/thread: tg = tid>>7 (4 sample groups), cn = tid&127.
    // Chunks of 1008 t's; cn<126 active, 8 t's each.
    {
        const int tg = tid >> 7, cn = tid & 127;
        const int sb4 = tg * 4;
        const float* w2pt = ws + OFF_W2PT;
        #pragma unroll 1
        for (int ch = 0; ch < 2; ++ch) {
            const int cb = ch * 1008;
            if (cn < 126) {
                float acc[4][8];
                #pragma unroll
                for (int s = 0; s < 4; ++s)
                    #pragma unroll
                    for (int q = 0; q < 8; ++q) acc[s][q] = 0.f;
                const float* wp = w2pt + cb + cn * 8;
                #pragma unroll 2
                for (int k = 0; k < 256; ++k) {
                    float4 wA = *(const float4*)(wp + k * 2016);
                    float4 wB = *(const float4*)(wp + k * 2016 + 4);
                    float h0 = sH2[(sb4 + 0) * 256 + k];
                    float h1 = sH2[(sb4 + 1) * 256 + k];
                    float h2 = sH2[(sb4 + 2) * 256 + k];
                    float h3 = sH2[(sb4 + 3) * 256 + k];
                    fma4acc(&acc[0][0], h0, wA); fma4acc(&acc[0][4], h0, wB);
                    fma4acc(&acc[1][0], h1, wA); fma4acc(&acc[1][4], h1, wB);
                    fma4acc(&acc[2][0], h2, wA); fma4acc(&acc[2][4], h2, wB);
                    fma4acc(&acc[3][0], h3, wA); fma4acc(&acc[3][4], h3, wB);
                }
                #pragma unroll
                for (int s = 0; s < 4; ++s) {
                    float* p = sa + (sb4 + s) * 2024 + cb + cn * 8;
                    *(float4*)(p)     = make_float4(acc[s][0], acc[s][1], acc[s][2], acc[s][3]);
                    *(float4*)(p + 4) = make_float4(acc[s][4], acc[s][5], acc[s][6], acc[s][7]);
                }
            }
        }
    }
    __syncthreads();

    // P4: gather.  thread -> sample s = tid>>5, rows i and i+32 (i = tid&31).
    {
        const int s = tid >> 5;
        const int i1 = tid & 31, i2 = i1 + 32;
        const int ib1 = i1 * (i1 - 1) / 2;
        const int ib2 = i2 * (i2 - 1) / 2;
        const float* ap = sa + s * 2024;
        const float* dep = sdE + s * 64;
        const float* dsp = sdS + s * 64;

        float adE1 = 0.f, adS1 = 0.f, adE2 = 0.f, adS2 = 0.f;
        int trij = 0;   // j*(j-1)/2
        #pragma unroll 4
        for (int j = 0; j < 64; ++j) {
            float dej = dep[j], dsj = dsp[j];
            // row i1:  A[i1][j] = (j<i1) ? a[t(i1,j)] : (j>i1) ? -a[t(j,i1)] : 0
            {
                int t = (j < i1) ? (ib1 + j) : (trij + i1);
                float sel = (j < i1) ? 1.f : ((j == i1) ? 0.f : -1.f);
                float c = sel * ap[t];
                adE1 = fmaf(c, dej, adE1);
                adS1 = fmaf(c, dsj, adS1);
            }
            // row i2
            {
                int t = (j < i2) ? (ib2 + j) : (trij + i2);
                float sel = (j < i2) ? 1.f : ((j == i2) ? 0.f : -1.f);
                float c = sel * ap[t];
                adE2 = fmaf(c, dej, adE2);
                adS2 = fmaf(c, dsj, adS2);
            }
            trij += j;
        }

        // scalars via 32-lane shfl reduction (sample = one half-wave)
        float de1 = dep[i1], de2 = dep[i2];
        float ds1 = dsp[i1], ds2 = dsp[i2];
        float p0 = de1 * adS1 + de2 * adS2;   // dE . AdS
        float p1 = de1 * ds1 + de2 * ds2;     // dE . dS
        float p2 = ds1 * ds1 + ds2 * ds2;     // dS . dS
        #pragma unroll
        for (int m = 1; m <= 16; m <<= 1) {
            p0 += __shfl_xor(p0, m);
            p1 += __shfl_xor(p1, m);
            p2 += __shfl_xor(p2, m);
        }
        float inv = 1.f / p2;
        dout[(sbase + s) * 64 + i1] = adE1 + (p0 * ds1 - p1 * adS1) * inv;
        dout[(sbase + s) * 64 + i2] = adE2 + (p0 * ds2 - p1 * adS2) * inv;
    }
}

// ---------------- K3: fC/fB heads + friction, accumulates into d_out ----------------
// 512 threads. Activations stored [sample][neuron] (broadcast reads, float4 writes).
// Bm kept in registers (bm[4][8][4]) between pass1 (B.dE, B.dS) and pass2 (B.v):
// eliminates the 256x4096 recompute GEMM. Reductions over i via 16-lane shfl_xor.
__global__ __launch_bounds__(512) void k3_friction(
    const float* __restrict__ y, const float* __restrict__ ws,
    const float* __restrict__ b0C, const float* __restrict__ b1C,
    const float* __restrict__ b0B, const float* __restrict__ b1B,
    float* __restrict__ dout)
{
    extern __shared__ float smem[];
    float* sYT  = smem;               // 16*64   [s][i]
    float* sA   = sYT + 1024;         // 16*256  [s][n]  (H1)
    float* sB   = sA + 4096;          // 16*256  [s][n]  (H2c then H2b)
    float* sC   = sB + 4096;          // 16*1089: C[s][k*17 + m]
    float* sdE  = sC + 17424;         // 16*64
    float* sdS  = sdE + 1024;
    float* sBdE = sdS + 1024;
    float* sBdS = sBdE + 1024;
    float* sv   = sBdS + 1024;
    float* sq   = sv + 1024;
    float* sScal = sq + 1024;         // 16*4: [0]=dE.dE [1]=dE.dS [2]=dE.v
    float* sr   = sScal + 64;         // 16*16
    // total = 33104 floats = 132416 B

    const int tid = threadIdx.x;
    const int sbase = blockIdx.x * SB;
    const float* gdE = ws + OFF_DE;
    const float* gdS = ws + OFF_DS;

    for (int idx = tid; idx < SB * 64; idx += 512) {
        sYT[idx] = y[sbase * 64 + idx];     // [s][i] contiguous
        sdE[idx] = gdE[sbase * 64 + idx];
        sdS[idx] = gdS[sbase * 64 + idx];
    }
    if (tid < 64) sScal[tid] = 0.f;
    __syncthreads();

    // dE.dE, dE.dS (consumed much later; barriers in between guarantee visibility)
    for (int idx = tid; idx < SB * 64; idx += 512) {
        int s = idx >> 6;
        float de = sdE[idx];
        unsafeAtomicAdd(&sScal[s * 4 + 0], de * de);
        unsafeAtomicAdd(&sScal[s * 4 + 1], de * sdS[idx]);
    }

    // ---- forward layers: 2-sample mapping (256 outputs) ----
    const int ts = tid >> 6, tn = tid & 63, n4 = tn * 4;
    const int fs0 = 2 * ts, fs1 = fs0 + 1;

    // ---- 4-sample mapping for wide GEMMs ----
    const int sgrp = tid >> 7;          // 0..3
    const int c    = tid & 127;         // 0..127
    const int sb4  = sgrp * 4;          // base sample
    const int i0   = 4 * (c & 15);      // dE/dS/v segment per lane
    const int khi  = c >> 4;            // 0..7 (includes wave-half bit)

    // ============ fC forward ============
    {
        const float* w0t = ws + OFF_W0T + 3 * 16384;
        float acc0[4] = {0}, acc1[4] = {0};
        #pragma unroll 4
        for (int k = 0; k < 64; ++k) {
            float a0 = sYT[fs0 * 64 + k], a1 = sYT[fs1 * 64 + k];
            float4 w = *(const float4*)(w0t + k * 256 + n4);
            fma8v(acc0, acc1, a0, a1, w);
        }
        float4 o0, o1;
        o0.x = tanhf(acc0[0] + b0C[n4]);     o1.x = tanhf(acc1[0] + b0C[n4]);
        o0.y = tanhf(acc0[1] + b0C[n4 + 1]); o1.y = tanhf(acc1[1] + b0C[n4 + 1]);
        o0.z = tanhf(acc0[2] + b0C[n4 + 2]); o1.z = tanhf(acc1[2] + b0C[n4 + 2]);
        o0.w = tanhf(acc0[3] + b0C[n4 + 3]); o1.w = tanhf(acc1[3] + b0C[n4 + 3]);
        *(float4*)(sA + fs0 * 256 + n4) = o0;
        *(float4*)(sA + fs1 * 256 + n4) = o1;
    }
    __syncthreads();
    {
        const float* w1t = ws + OFF_W1T + 3 * 65536;
        float acc0[4] = {0}, acc1[4] = {0};
        #pragma unroll 4
        for (int k = 0; k < 256; ++k) {
            float a0 = sA[fs0 * 256 + k], a1 = sA[fs1 * 256 + k];
            float4 w = *(const float4*)(w1t + k * 256 + n4);
            fma8v(acc0, acc1, a0, a1, w);
        }
        float4 o0, o1;
        o0.x = tanhf(acc0[0] + b1C[n4]);     o1.x = tanhf(acc1[0] + b1C[n4]);
        o0.y = tanhf(acc0[1] + b1C[n4 + 1]); o1.y = tanhf(acc1[1] + b1C[n4 + 1]);
        o0.z = tanhf(acc0[2] + b1C[n4 + 2]); o1.z = tanhf(acc1[2] + b1C[n4 + 2]);
        o0.w = tanhf(acc0[3] + b1C[n4 + 3]); o1.w = tanhf(acc1[3] + b1C[n4 + 3]);
        *(float4*)(sB + fs0 * 256 + n4) = o0;
        *(float4*)(sB + fs1 * 256 + n4) = o1;
    }
    __syncthreads();

    // ============ C head: 4 samples/thread, n = cc2*512 + 4c + q ============
    {
        const float* w2ct = ws + OFF_W2CT + 4 * c;
        #pragma unroll
        for (int cc2 = 0; cc2 < 2; ++cc2) {
            float a0[4] = {0}, a1[4] = {0}, a2[4] = {0}, a3[4] = {0};
            #pragma unroll 2
            for (int k = 0; k < 256; ++k) {
                float4 w = *(const float4*)(w2ct + k * 1024 + cc2 * 512);
                float h0 = sB[(sb4 + 0) * 256 + k];
                float h1 = sB[(sb4 + 1) * 256 + k];
                float h2 = sB[(sb4 + 2) * 256 + k];
                float h3 = sB[(sb4 + 3) * 256 + k];
                fma4acc(a0, h0, w); fma4acc(a1, h1, w);
                fma4acc(a2, h2, w); fma4acc(a3, h3, w);
            }
            int kC = cc2 * 32 + (c >> 2);
            int mC = 4 * (c & 3);
            float* p0 = sC + (sb4 + 0) * 1089 + kC * 17 + mC;
            float* p1 = sC + (sb4 + 1) * 1089 + kC * 17 + mC;
            float* p2 = sC + (sb4 + 2) * 1089 + kC * 17 + mC;
            float* p3 = sC + (sb4 + 3) * 1089 + kC * 17 + mC;
            #pragma unroll
            for (int q = 0; q < 4; ++q) {
                p0[q] = a0[q]; p1[q] = a1[q]; p2[q] = a2[q]; p3[q] = a3[q];
            }
        }
    }
    __syncthreads();

    // ============ fB forward (reuse sA, sB) ============
    {
        const float* w0t = ws + OFF_W0T + 4 * 16384;
        float acc0[4] = {0}, acc1[4] = {0};
        #pragma unroll 4
        for (int k = 0; k < 64; ++k) {
            float a0 = sYT[fs0 * 64 + k], a1 = sYT[fs1 * 64 + k];
            float4 w = *(const float4*)(w0t + k * 256 + n4);
            fma8v(acc0, acc1, a0, a1, w);
        }
        float4 o0, o1;
        o0.x = tanhf(acc0[0] + b0B[n4]);     o1.x = tanhf(acc1[0] + b0B[n4]);
        o0.y = tanhf(acc0[1] + b0B[n4 + 1]); o1.y = tanhf(acc1[1] + b0B[n4 + 1]);
        o0.z = tanhf(acc0[2] + b0B[n4 + 2]); o1.z = tanhf(acc1[2] + b0B[n4 + 2]);
        o0.w = tanhf(acc0[3] + b0B[n4 + 3]); o1.w = tanhf(acc1[3] + b0B[n4 + 3]);
        *(float4*)(sA + fs0 * 256 + n4) = o0;
        *(float4*)(sA + fs1 * 256 + n4) = o1;
    }
    __syncthreads();
    {
        const float* w1t = ws + OFF_W1T + 4 * 65536;
        float acc0[4] = {0}, acc1[4] = {0};
        #pragma unroll 4
        for (int k = 0; k < 256; ++k) {
            float a0 = sA[fs0 * 256 + k], a1 = sA[fs1 * 256 + k];
            float4 w = *(const float4*)(w1t + k * 256 + n4);
            fma8v(acc0, acc1, a0, a1, w);
        }
        float4 o0, o1;
        o0.x = tanhf(acc0[0] + b1B[n4]);     o1.x = tanhf(acc1[0] + b1B[n4]);
        o0.y = tanhf(acc0[1] + b1B[n4 + 1]); o1.y = tanhf(acc1[1] + b1B[n4 + 1]);
        o0.z = tanhf(acc0[2] + b1B[n4 + 2]); o1.z = tanhf(acc1[2] + b1B[n4 + 2]);
        o0.w = tanhf(acc0[3] + b1B[n4 + 3]); o1.w = tanhf(acc1[3] + b1B[n4 + 3]);
        *(float4*)(sB + fs0 * 256 + n4) = o0;
        *(float4*)(sB + fs1 * 256 + n4) = o1;
    }
    __syncthreads();

    // ============ pass1: Bm into registers + BdotdE/BdotdS ============
    // n = rb2*512 + 4c + q  ->  k' = rb2*8 + khi,  i = i0 + q
    float bm[4][8][4];
    #pragma unroll
    for (int s = 0; s < 4; ++s)
        #pragma unroll
        for (int r2 = 0; r2 < 8; ++r2)
            #pragma unroll
            for (int q = 0; q < 4; ++q) bm[s][r2][q] = 0.f;

    {
        const float* wb = ws + OFF_W2BT + 4 * c;
        for (int k = 0; k < 256; ++k) {
            float h0 = sB[(sb4 + 0) * 256 + k];
            float h1 = sB[(sb4 + 1) * 256 + k];
            float h2 = sB[(sb4 + 2) * 256 + k];
            float h3 = sB[(sb4 + 3) * 256 + k];
            const float* wk = wb + k * 4096;
            #pragma unroll
            for (int r2 = 0; r2 < 8; ++r2) {
                float4 w = *(const float4*)(wk + r2 * 512);
                fma4acc(bm[0][r2], h0, w);
                fma4acc(bm[1][r2], h1, w);
                fma4acc(bm[2][r2], h2, w);
                fma4acc(bm[3][r2], h3, w);
            }
        }
    }
    // dots with dE, dS; 16-lane shfl reduction over i
    #pragma unroll
    for (int r2 = 0; r2 < 8; ++r2) {
        #pragma unroll
        for (int s = 0; s < 4; ++s) {
            float pd = dot4(bm[s][r2], sdE + (sb4 + s) * 64 + i0);
            float ps = dot4(bm[s][r2], sdS + (sb4 + s) * 64 + i0);
            pd += __shfl_xor(pd, 1); ps += __shfl_xor(ps, 1);
            pd += __shfl_xor(pd, 2); ps += __shfl_xor(ps, 2);
            pd += __shfl_xor(pd, 4); ps += __shfl_xor(ps, 4);
            pd += __shfl_xor(pd, 8); ps += __shfl_xor(ps, 8);
            if ((c & 15) == 0) {
                int kk = r2 * 8 + khi;
                sBdE[(sb4 + s) * 64 + kk] = pd;
                sBdS[(sb4 + s) * 64 + kk] = ps;
            }
        }
    }
    __syncthreads();

    // v = BdS - beta*BdE
    for (int idx = tid; idx < SB * 64; idx += 512) {
        int s = idx >> 6;
        float beta = sScal[s * 4 + 1] / sScal[s * 4 + 0];
        sv[idx] = sBdS[idx] - beta * sBdE[idx];
    }
    __syncthreads();
    for (int idx = tid; idx < SB * 64; idx += 512) {
        int s = idx >> 6;
        unsafeAtomicAdd(&sScal[s * 4 + 2], sdE[idx] * sv[idx]);
    }
    __syncthreads();

    // ============ pass2: q = Bm @ v from registers ============
    #pragma unroll
    for (int r2 = 0; r2 < 8; ++r2) {
        #pragma unroll
        for (int s = 0; s < 4; ++s) {
            float pq = dot4(bm[s][r2], sv + (sb4 + s) * 64 + i0);
            pq += __shfl_xor(pq, 1);
            pq += __shfl_xor(pq, 2);
            pq += __shfl_xor(pq, 4);
            pq += __shfl_xor(pq, 8);
            if ((c & 15) == 0) sq[(sb4 + s) * 64 + r2 * 8 + khi] = pq;
        }
    }
    __syncthreads();

    // r[m] = sum_k C[k,m] * (q[k] - gamma*BdE[k])
    if (tid < 256) {
        int s = tid >> 4, m = tid & 15;
        float gamma = sScal[s * 4 + 2] / sScal[s * 4 + 0];
        float r = 0.f;
        #pragma unroll 4
        for (int k = 0; k < 64; ++k) {
            float wv = sq[s * 64 + k] - gamma * sBdE[s * 64 + k];
            r = fmaf(sC[s * 1089 + k * 17 + m], wv, r);
        }
        sr[s * 16 + m] = r;
    }
    __syncthreads();
    // out_k += sum_m C[k,m] * r[m]
    for (int idx = tid; idx < SB * 64; idx += 512) {
        int s = idx >> 6, k = idx & 63;
        float o = 0.f;
        #pragma unroll
        for (int m2 = 0; m2 < 16; ++m2)
            o = fmaf(sC[s * 1089 + k * 17 + m2], sr[s * 16 + m2], o);
        int gi = sbase * 64 + idx;
        dout[gi] = dout[gi] + o;
    }
}

extern "C" void kernel_launch(void* const* d_in, const int* in_sizes, int n_in,
                              void* d_out, int out_size, void* d_ws, size_t ws_size,
                              hipStream_t stream)
{
    (void)in_sizes; (void)n_in; (void)out_size;
    const float* y = (const float*)d_in[1];
    const float* W0[5]; const float* b0[5]; const float* W1[5]; const float* b1[5]; const float* W2[5];
    for (int m = 0; m < 5; ++m) {
        int base = 2 + m * 5;
        W0[m] = (const float*)d_in[base + 0];
        b0[m] = (const float*)d_in[base + 1];
        W1[m] = (const float*)d_in[base + 2];
        b1[m] = (const float*)d_in[base + 3];
        W2[m] = (const float*)d_in[base + 4];
    }
    float* ws = (float*)d_ws;
    float* dout = (float*)d_out;
    if (ws_size < (size_t)WS_FLOATS * sizeof(float)) return;

    for (int m = 0; m < 5; ++m) {
        hipLaunchKernelGGL(k_transpose, dim3((256 * 64 + 255) / 256), dim3(256), 0, stream,
                           W0[m], ws + OFF_W0T + m * 16384, 256, 64);
        hipLaunchKernelGGL(k_transpose, dim3((256 * 256 + 255) / 256), dim3(256), 0, stream,
                           W1[m], ws + OFF_W1T + m * 65536, 256, 256);
    }
    hipLaunchKernelGGL(k_transpose, dim3((2016 * 256 + 255) / 256), dim3(256), 0, stream,
                       W2[2], ws + OFF_W2PT, 2016, 256);
    hipLaunchKernelGGL(k_transpose, dim3((1024 * 256 + 255) / 256), dim3(256), 0, stream,
                       W2[3], ws + OFF_W2CT, 1024, 256);
    hipLaunchKernelGGL(k_transpose, dim3((4096 * 256 + 255) / 256), dim3(256), 0, stream,
                       W2[4], ws + OFF_W2BT, 4096, 256);

    hipLaunchKernelGGL(k1_grads, dim3(1024), dim3(256), 0, stream,
                       y, ws,
                       W0[0], b0[0], W1[0], b1[0], W2[0],
                       W0[1], b0[1], W1[1], b1[1], W2[1],
                       ws + OFF_DE, ws + OFF_DS);

    const int k2_smem = 154112;
    hipFuncSetAttribute((const void*)k2_poisson, hipFuncAttributeMaxDynamicSharedMemorySize, k2_smem);
    hipLaunchKernelGGL(k2_poisson, dim3(1024), dim3(512), k2_smem, stream,
                       y, ws, b0[2], b1[2], dout);

    const int k3_smem = 132416;
    hipFuncSetAttribute((const void*)k3_friction, hipFuncAttributeMaxDynamicSharedMemorySize, k3_smem);
    hipLaunchKernelGGL(k3_friction, dim3(1024), dim3(512), k3_smem, stream,
                       y, ws, b0[3], b1[3], b0[4], b1[4], dout);
}

// Round 4
// 2080.977 us; speedup vs baseline: 2.3374x; 1.0191x over previous
//
#include <hip/hip_runtime.h>
#include <math.h>

// Problem constants: B=16384 samples, DIM=64, WIDTH=256, DD=64, C2=16
#define SB 16      // samples per workgroup
#define PAD 17     // LDS row pad for transposed [neuron][sample] tiles (k1)

// ws layout (float offsets)
#define OFF_W0T  0            // 5 x (64x256)
#define OFF_W1T  81920        // 5 x (256x256)
#define OFF_W2PT 409600       // 256x2016
#define OFF_W2CT 925696       // 256x1024
#define OFF_W2BT 1187840      // 256x4096
#define OFF_DE   2236416      // 16384x64
#define OFF_DS   3284992      // 16384x64
#define WS_FLOATS 4337600     // ~17.35 MB

__device__ __forceinline__ void fma16(float* acc0, float* acc1, float a0, float a1,
                                      float4 wA, float4 wB) {
    float w[8] = {wA.x, wA.y, wA.z, wA.w, wB.x, wB.y, wB.z, wB.w};
    #pragma unroll
    for (int q = 0; q < 8; ++q) {
        acc0[q] = fmaf(a0, w[q], acc0[q]);
        acc1[q] = fmaf(a1, w[q], acc1[q]);
    }
}

__device__ __forceinline__ void fma8v(float* acc0, float* acc1, float a0, float a1, float4 w) {
    acc0[0] = fmaf(a0, w.x, acc0[0]); acc0[1] = fmaf(a0, w.y, acc0[1]);
    acc0[2] = fmaf(a0, w.z, acc0[2]); acc0[3] = fmaf(a0, w.w, acc0[3]);
    acc1[0] = fmaf(a1, w.x, acc1[0]); acc1[1] = fmaf(a1, w.y, acc1[1]);
    acc1[2] = fmaf(a1, w.z, acc1[2]); acc1[3] = fmaf(a1, w.w, acc1[3]);
}

__device__ __forceinline__ void fma4acc(float* a, float h, float4 w) {
    a[0] = fmaf(h, w.x, a[0]); a[1] = fmaf(h, w.y, a[1]);
    a[2] = fmaf(h, w.z, a[2]); a[3] = fmaf(h, w.w, a[3]);
}

__device__ __forceinline__ float dot4(const float* a, const float* b) {
    return fmaf(a[3], b[3], fmaf(a[2], b[2], fmaf(a[1], b[1], a[0] * b[0])));
}

// out[c*R + r] = in[r*C + c]   (in: R rows x C cols, row-major)
__global__ void k_transpose(const float* __restrict__ in, float* __restrict__ out, int R, int C) {
    int tid = blockIdx.x * blockDim.x + threadIdx.x;
    if (tid >= R * C) return;
    int c = tid / R, r = tid - c * R;
    out[tid] = in[r * C + c];
}

// ---------------- K1: dE, dS (energy/entropy forward + analytic backward) ----------------
__global__ __launch_bounds__(256) void k1_grads(
    const float* __restrict__ y, const float* __restrict__ ws,
    const float* __restrict__ W0E, const float* __restrict__ b0E,
    const float* __restrict__ W1E, const float* __restrict__ b1E,
    const float* __restrict__ w2E,
    const float* __restrict__ W0S, const float* __restrict__ b0S,
    const float* __restrict__ W1S, const float* __restrict__ b1S,
    const float* __restrict__ w2S,
    float* __restrict__ odE, float* __restrict__ odS)
{
    __shared__ float sYT[64][PAD];
    __shared__ float sH1T[256][PAD];
    __shared__ float sH2T[256][PAD];
    __shared__ float sUT[256][PAD];

    const int tid = threadIdx.x;
    const int sbase = blockIdx.x * SB;
    for (int idx = tid; idx < SB * 64; idx += 256) {
        int s = idx >> 6, i = idx & 63;
        sYT[i][s] = y[(sbase + s) * 64 + i];
    }
    __syncthreads();

    const int ts = tid >> 5, tn = tid & 31;
    const int s0 = 2 * ts, s1 = s0 + 1;

    for (int m = 0; m < 2; ++m) {
        const float* w0t = ws + OFF_W0T + m * 16384;
        const float* w1t = ws + OFF_W1T + m * 65536;
        const float* W0 = m ? W0S : W0E;
        const float* W1 = m ? W1S : W1E;
        const float* b0 = m ? b0S : b0E;
        const float* b1 = m ? b1S : b1E;
        const float* w2 = m ? w2S : w2E;
        float* outg = m ? odS : odE;

        // H1 = tanh(Y @ W0^T + b0), K=64
        {
            float acc0[8] = {0}, acc1[8] = {0};
            #pragma unroll 4
            for (int k = 0; k < 64; ++k) {
                float a0 = sYT[k][s0], a1 = sYT[k][s1];
                float4 wA = *(const float4*)(w0t + k * 256 + tn * 8);
                float4 wB = *(const float4*)(w0t + k * 256 + tn * 8 + 4);
                fma16(acc0, acc1, a0, a1, wA, wB);
            }
            #pragma unroll
            for (int q = 0; q < 8; ++q) {
                int j = tn * 8 + q;
                float b = b0[j];
                sH1T[j][s0] = tanhf(acc0[q] + b);
                sH1T[j][s1] = tanhf(acc1[q] + b);
            }
        }
        __syncthreads();
        // H2 = tanh(H1 @ W1^T + b1), K=256
        {
            float acc0[8] = {0}, acc1[8] = {0};
            #pragma unroll 4
            for (int k = 0; k < 256; ++k) {
                float a0 = sH1T[k][s0], a1 = sH1T[k][s1];
                float4 wA = *(const float4*)(w1t + k * 256 + tn * 8);
                float4 wB = *(const float4*)(w1t + k * 256 + tn * 8 + 4);
                fma16(acc0, acc1, a0, a1, wA, wB);
            }
            #pragma unroll
            for (int q = 0; q < 8; ++q) {
                int j = tn * 8 + q;
                float b = b1[j];
                sH2T[j][s0] = tanhf(acc0[q] + b);
                sH2T[j][s1] = tanhf(acc1[q] + b);
            }
        }
        __syncthreads();
        // G2 = (1 - H2^2) * w2  (in place)
        for (int idx = tid; idx < 256 * SB; idx += 256) {
            int j = idx >> 4, s = idx & 15;
            float h = sH2T[j][s];
            sH2T[j][s] = (1.f - h * h) * w2[j];
        }
        __syncthreads();
        // U = G2 @ W1 (natural layout), fused G1 = (1-H1^2)*U
        {
            float acc0[8] = {0}, acc1[8] = {0};
            #pragma unroll 4
            for (int k = 0; k < 256; ++k) {
                float a0 = sH2T[k][s0], a1 = sH2T[k][s1];
                float4 wA = *(const float4*)(W1 + k * 256 + tn * 8);
                float4 wB = *(const float4*)(W1 + k * 256 + tn * 8 + 4);
                fma16(acc0, acc1, a0, a1, wA, wB);
            }
            #pragma unroll
            for (int q = 0; q < 8; ++q) {
                int ko = tn * 8 + q;
                float h0 = sH1T[ko][s0], h1v = sH1T[ko][s1];
                sUT[ko][s0] = (1.f - h0 * h0) * acc0[q];
                sUT[ko][s1] = (1.f - h1v * h1v) * acc1[q];
            }
        }
        __syncthreads();
        // dE = G1 @ W0 (natural layout)
        {
            float a00 = 0, a01 = 0, a10 = 0, a11 = 0;
            #pragma unroll 4
            for (int k = 0; k < 256; ++k) {
                float g0 = sUT[k][s0], g1 = sUT[k][s1];
                float2 w = *(const float2*)(W0 + k * 64 + tn * 2);
                a00 = fmaf(g0, w.x, a00); a01 = fmaf(g0, w.y, a01);
                a10 = fmaf(g1, w.x, a10); a11 = fmaf(g1, w.y, a11);
            }
            outg[(sbase + s0) * 64 + tn * 2]     = a00;
            outg[(sbase + s0) * 64 + tn * 2 + 1] = a01;
            outg[(sbase + s1) * 64 + tn * 2]     = a10;
            outg[(sbase + s1) * 64 + tn * 2 + 1] = a11;
        }
        __syncthreads();
    }
}

// ---------------- K2: pA head + poisson (atomic-free), writes d_out ----------------
__global__ __launch_bounds__(512) void k2_poisson(
    const float* __restrict__ y, const float* __restrict__ ws,
    const float* __restrict__ b0P, const float* __restrict__ b1P,
    float* __restrict__ dout)
{
    extern __shared__ float smem[];
    float* sa  = smem;            // 16 x 2024 (a-values, padded). Aliased: H1 @ [0,4096), y @ [4096,5120)
    float* sH2 = smem + 32384;    // 16 x 256
    float* sdE = sH2 + 4096;      // 16 x 64
    float* sdS = sdE + 1024;      // 16 x 64
    // total 38528 floats = 154112 B

    float* sH1 = sa;              // alias (dead before a-GEMM writes)
    float* sy  = sa + 4096;       // alias (dead after H1)

    const int tid = threadIdx.x;
    const int sbase = blockIdx.x * SB;
    const float* gdE = ws + OFF_DE;
    const float* gdS = ws + OFF_DS;

    // P0: load y, dE, dS ([s][i] contiguous)
    for (int idx = tid; idx < SB * 64; idx += 512) {
        sy[idx]  = y[sbase * 64 + idx];
        sdE[idx] = gdE[sbase * 64 + idx];
        sdS[idx] = gdS[sbase * 64 + idx];
    }
    __syncthreads();

    const int ts = tid >> 6, tn = tid & 63, n4 = tn * 4;
    const int fs0 = 2 * ts, fs1 = fs0 + 1;

    // P1: H1 = tanh(y @ W0^T + b0)
    {
        const float* w0t = ws + OFF_W0T + 2 * 16384;
        float acc0[4] = {0}, acc1[4] = {0};
        #pragma unroll 4
        for (int k = 0; k < 64; ++k) {
            float a0 = sy[fs0 * 64 + k], a1 = sy[fs1 * 64 + k];
            float4 w = *(const float4*)(w0t + k * 256 + n4);
            fma8v(acc0, acc1, a0, a1, w);
        }
        float4 o0, o1;
        o0.x = tanhf(acc0[0] + b0P[n4]);     o1.x = tanhf(acc1[0] + b0P[n4]);
        o0.y = tanhf(acc0[1] + b0P[n4 + 1]); o1.y = tanhf(acc1[1] + b0P[n4 + 1]);
        o0.z = tanhf(acc0[2] + b0P[n4 + 2]); o1.z = tanhf(acc1[2] + b0P[n4 + 2]);
        o0.w = tanhf(acc0[3] + b0P[n4 + 3]); o1.w = tanhf(acc1[3] + b0P[n4 + 3]);
        *(float4*)(sH1 + fs0 * 256 + n4) = o0;
        *(float4*)(sH1 + fs1 * 256 + n4) = o1;
    }
    __syncthreads();

    // P2: H2 = tanh(H1 @ W1^T + b1)
    {
        const float* w1t = ws + OFF_W1T + 2 * 65536;
        float acc0[4] = {0}, acc1[4] = {0};
        #pragma unroll 4
        for (int k = 0; k < 256; ++k) {
            float a0 = sH1[fs0 * 256 + k], a1 = sH1[fs1 * 256 + k];
            float4 w = *(const float4*)(w1t + k * 256 + n4);
            fma8v(acc0, acc1, a0, a1, w);
        }
        float4 o0, o1;
        o0.x = tanhf(acc0[0] + b1P[n4]);     o1.x = tanhf(acc1[0] + b1P[n4]);
        o0.y = tanhf(acc0[1] + b1P[n4 + 1]); o1.y = tanhf(acc1[1] + b1P[n4 + 1]);
        o0.z = tanhf(acc0[2] + b1P[n4 + 2]); o1.z = tanhf(acc1[2] + b1P[n4 + 2]);
        o0.w = tanhf(acc0[3] + b1P[n4 + 3]); o1.w = tanhf(acc1[3] + b1P[n4 + 3]);
        *(float4*)(sH2 + fs0 * 256 + n4) = o0;
        *(float4*)(sH2 + fs1 * 256 + n4) = o1;
    }
    __syncthreads();   // H1/y regions dead; sa fully writable

    // P3: a-GEMM. 4 samples/thread
    {
        const int tg = tid >> 7, cn = tid & 127;
        const int sb4 = tg * 4;
        const float* w2pt = ws + OFF_W2PT;
        #pragma unroll 1
        for (int ch = 0; ch < 2; ++ch) {
            const int cb = ch * 1008;
            if (cn < 126) {
                float acc[4][8];
                #pragma unroll
                for (int s = 0; s < 4; ++s)
                    #pragma unroll
                    for (int q = 0; q < 8; ++q) acc[s][q] = 0.f;
                const float* wp = w2pt + cb + cn * 8;
                #pragma unroll 2
                for (int k = 0; k < 256; ++k) {
                    float4 wA = *(const float4*)(wp + k * 2016);
                    float4 wB = *(const float4*)(wp + k * 2016 + 4);
                    float h0 = sH2[(sb4 + 0) * 256 + k];
                    float h1 = sH2[(sb4 + 1) * 256 + k];
                    float h2 = sH2[(sb4 + 2) * 256 + k];
                    float h3 = sH2[(sb4 + 3) * 256 + k];
                    fma4acc(&acc[0][0], h0, wA); fma4acc(&acc[0][4], h0, wB);
                    fma4acc(&acc[1][0], h1, wA); fma4acc(&acc[1][4], h1, wB);
                    fma4acc(&acc[2][0], h2, wA); fma4acc(&acc[2][4], h2, wB);
                    fma4acc(&acc[3][0], h3, wA); fma4acc(&acc[3][4], h3, wB);
                }
                #pragma unroll
                for (int s = 0; s < 4; ++s) {
                    float* p = sa + (sb4 + s) * 2024 + cb + cn * 8;
                    *(float4*)(p)     = make_float4(acc[s][0], acc[s][1], acc[s][2], acc[s][3]);
                    *(float4*)(p + 4) = make_float4(acc[s][4], acc[s][5], acc[s][6], acc[s][7]);
                }
            }
        }
    }
    __syncthreads();

    // P4: gather.  thread -> sample s = tid>>5, rows i and i+32 (i = tid&31).
    {
        const int s = tid >> 5;
        const int i1 = tid & 31, i2 = i1 + 32;
        const int ib1 = i1 * (i1 - 1) / 2;
        const int ib2 = i2 * (i2 - 1) / 2;
        const float* ap = sa + s * 2024;
        const float* dep = sdE + s * 64;
        const float* dsp = sdS + s * 64;

        float adE1 = 0.f, adS1 = 0.f, adE2 = 0.f, adS2 = 0.f;
        int trij = 0;   // j*(j-1)/2
        #pragma unroll 4
        for (int j = 0; j < 64; ++j) {
            float dej = dep[j], dsj = dsp[j];
            {
                int t = (j < i1) ? (ib1 + j) : (trij + i1);
                float sel = (j < i1) ? 1.f : ((j == i1) ? 0.f : -1.f);
                float c = sel * ap[t];
                adE1 = fmaf(c, dej, adE1);
                adS1 = fmaf(c, dsj, adS1);
            }
            {
                int t = (j < i2) ? (ib2 + j) : (trij + i2);
                float sel = (j < i2) ? 1.f : ((j == i2) ? 0.f : -1.f);
                float c = sel * ap[t];
                adE2 = fmaf(c, dej, adE2);
                adS2 = fmaf(c, dsj, adS2);
            }
            trij += j;
        }

        float de1 = dep[i1], de2 = dep[i2];
        float ds1 = dsp[i1], ds2 = dsp[i2];
        float p0 = de1 * adS1 + de2 * adS2;   // dE . AdS
        float p1 = de1 * ds1 + de2 * ds2;     // dE . dS
        float p2 = ds1 * ds1 + ds2 * ds2;     // dS . dS
        #pragma unroll
        for (int m = 1; m <= 16; m <<= 1) {
            p0 += __shfl_xor(p0, m);
            p1 += __shfl_xor(p1, m);
            p2 += __shfl_xor(p2, m);
        }
        float inv = 1.f / p2;
        dout[(sbase + s) * 64 + i1] = adE1 + (p0 * ds1 - p1 * adS1) * inv;
        dout[(sbase + s) * 64 + i2] = adE2 + (p0 * ds2 - p1 * adS2) * inv;
    }
}

// ---------------- K3: fC/fB heads + friction, accumulates into d_out ----------------
// 1024 threads (16 waves = 4 waves/SIMD at 1 block/CU), SB=16.
// Bm register tile bm[4][4][4] (64 fp) held across pass1/pass2.
__global__ __launch_bounds__(1024, 4) void k3_friction(
    const float* __restrict__ y, const float* __restrict__ ws,
    const float* __restrict__ b0C, const float* __restrict__ b1C,
    const float* __restrict__ b0B, const float* __restrict__ b1B,
    float* __restrict__ dout)
{
    extern __shared__ float smem[];
    float* sYT  = smem;               // 16*64   [s][i]
    float* sA   = sYT + 1024;         // 16*256  [s][n]  (H1)
    float* sB   = sA + 4096;          // 16*256  [s][n]  (H2c then H2b)
    float* sC   = sB + 4096;          // 16*1089: C[s][k*17 + m]
    float* sdE  = sC + 17424;         // 16*64
    float* sdS  = sdE + 1024;
    float* sBdE = sdS + 1024;
    float* sBdS = sBdE + 1024;
    float* sv   = sBdS + 1024;
    float* sq   = sv + 1024;
    float* sScal = sq + 1024;         // 16*4: [0]=dE.dE [1]=dE.dS [2]=dE.v
    float* sr   = sScal + 64;         // 16*16
    // total = 33104 floats = 132416 B

    const int tid = threadIdx.x;
    const int sbase = blockIdx.x * SB;
    const float* gdE = ws + OFF_DE;
    const float* gdS = ws + OFF_DS;

    // one element per thread (SB*64 == 1024)
    sYT[tid] = y[sbase * 64 + tid];
    sdE[tid] = gdE[sbase * 64 + tid];
    sdS[tid] = gdS[sbase * 64 + tid];
    if (tid < 64) sScal[tid] = 0.f;
    __syncthreads();

    {
        int s = tid >> 6;
        float de = sdE[tid];
        unsafeAtomicAdd(&sScal[s * 4 + 0], de * de);
        unsafeAtomicAdd(&sScal[s * 4 + 1], de * sdS[tid]);
    }

    // ---- forward mapping: 1 sample x 4 neurons per thread ----
    const int fs = tid >> 6;            // sample 0..15
    const int tn = tid & 63, n4 = tn * 4;

    // ---- wide-GEMM mapping: 4 samples x (cn covers wide dim) ----
    const int sg4 = tid >> 8;           // 0..3
    const int cn  = tid & 255;          // 0..255
    const int sb4 = sg4 * 4;
    const int i0  = 4 * (cn & 15);      // Bm: DIM segment
    const int khl = cn >> 4;            // Bm: DD sub-index 0..15

    // ============ fC forward ============
    {
        const float* w0t = ws + OFF_W0T + 3 * 16384;
        float acc[4] = {0};
        #pragma unroll 4
        for (int k = 0; k < 64; ++k) {
            float a = sYT[fs * 64 + k];
            float4 w = *(const float4*)(w0t + k * 256 + n4);
            fma4acc(acc, a, w);
        }
        float4 o;
        o.x = tanhf(acc[0] + b0C[n4]);
        o.y = tanhf(acc[1] + b0C[n4 + 1]);
        o.z = tanhf(acc[2] + b0C[n4 + 2]);
        o.w = tanhf(acc[3] + b0C[n4 + 3]);
        *(float4*)(sA + fs * 256 + n4) = o;
    }
    __syncthreads();
    {
        const float* w1t = ws + OFF_W1T + 3 * 65536;
        float acc[4] = {0};
        #pragma unroll 4
        for (int k = 0; k < 256; ++k) {
            float a = sA[fs * 256 + k];
            float4 w = *(const float4*)(w1t + k * 256 + n4);
            fma4acc(acc, a, w);
        }
        float4 o;
        o.x = tanhf(acc[0] + b1C[n4]);
        o.y = tanhf(acc[1] + b1C[n4 + 1]);
        o.z = tanhf(acc[2] + b1C[n4 + 2]);
        o.w = tanhf(acc[3] + b1C[n4 + 3]);
        *(float4*)(sB + fs * 256 + n4) = o;
    }
    __syncthreads();

    // ============ C head: 4 samples/thread, n = 4*cn + q ============
    {
        const float* w2ct = ws + OFF_W2CT + 4 * cn;
        float a0[4] = {0}, a1[4] = {0}, a2[4] = {0}, a3[4] = {0};
        #pragma unroll 2
        for (int k = 0; k < 256; ++k) {
            float4 w = *(const float4*)(w2ct + k * 1024);
            float h0 = sB[(sb4 + 0) * 256 + k];
            float h1 = sB[(sb4 + 1) * 256 + k];
            float h2 = sB[(sb4 + 2) * 256 + k];
            float h3 = sB[(sb4 + 3) * 256 + k];
            fma4acc(a0, h0, w); fma4acc(a1, h1, w);
            fma4acc(a2, h2, w); fma4acc(a3, h3, w);
        }
        const int kC = cn >> 2;          // 0..63
        const int mC = 4 * (cn & 3);     // 0,4,8,12
        float* p0 = sC + (sb4 + 0) * 1089 + kC * 17 + mC;
        float* p1 = sC + (sb4 + 1) * 1089 + kC * 17 + mC;
        float* p2 = sC + (sb4 + 2) * 1089 + kC * 17 + mC;
        float* p3 = sC + (sb4 + 3) * 1089 + kC * 17 + mC;
        #pragma unroll
        for (int q = 0; q < 4; ++q) {
            p0[q] = a0[q]; p1[q] = a1[q]; p2[q] = a2[q]; p3[q] = a3[q];
        }
    }
    __syncthreads();

    // ============ fB forward (reuse sA, sB) ============
    {
        const float* w0t = ws + OFF_W0T + 4 * 16384;
        float acc[4] = {0};
        #pragma unroll 4
        for (int k = 0; k < 64; ++k) {
            float a = sYT[fs * 64 + k];
            float4 w = *(const float4*)(w0t + k * 256 + n4);
            fma4acc(acc, a, w);
        }
        float4 o;
        o.x = tanhf(acc[0] + b0B[n4]);
        o.y = tanhf(acc[1] + b0B[n4 + 1]);
        o.z = tanhf(acc[2] + b0B[n4 + 2]);
        o.w = tanhf(acc[3] + b0B[n4 + 3]);
        *(float4*)(sA + fs * 256 + n4) = o;
    }
    __syncthreads();
    {
        const float* w1t = ws + OFF_W1T + 4 * 65536;
        float acc[4] = {0};
        #pragma unroll 4
        for (int k = 0; k < 256; ++k) {
            float a = sA[fs * 256 + k];
            float4 w = *(const float4*)(w1t + k * 256 + n4);
            fma4acc(acc, a, w);
        }
        float4 o;
        o.x = tanhf(acc[0] + b1B[n4]);
        o.y = tanhf(acc[1] + b1B[n4 + 1]);
        o.z = tanhf(acc[2] + b1B[n4 + 2]);
        o.w = tanhf(acc[3] + b1B[n4 + 3]);
        *(float4*)(sB + fs * 256 + n4) = o;
    }
    __syncthreads();

    // ============ pass1: Bm into registers + BdotdE/BdotdS ============
    // n = r2*1024 + 4*cn + q  ->  k' = r2*16 + (cn>>4),  i = 4*(cn&15) + q
    float bm[4][4][4];
    #pragma unroll
    for (int s = 0; s < 4; ++s)
        #pragma unroll
        for (int r2 = 0; r2 < 4; ++r2)
            #pragma unroll
            for (int q = 0; q < 4; ++q) bm[s][r2][q] = 0.f;

    {
        const float* wb = ws + OFF_W2BT + 4 * cn;
        #pragma unroll 2
        for (int k = 0; k < 256; ++k) {
            float h0 = sB[(sb4 + 0) * 256 + k];
            float h1 = sB[(sb4 + 1) * 256 + k];
            float h2 = sB[(sb4 + 2) * 256 + k];
            float h3 = sB[(sb4 + 3) * 256 + k];
            const float* wk = wb + k * 4096;
            #pragma unroll
            for (int r2 = 0; r2 < 4; ++r2) {
                float4 w = *(const float4*)(wk + r2 * 1024);
                fma4acc(bm[0][r2], h0, w);
                fma4acc(bm[1][r2], h1, w);
                fma4acc(bm[2][r2], h2, w);
                fma4acc(bm[3][r2], h3, w);
            }
        }
    }
    // dots with dE, dS; 16-lane shfl reduction over i
    #pragma unroll
    for (int r2 = 0; r2 < 4; ++r2) {
        #pragma unroll
        for (int s = 0; s < 4; ++s) {
            float pd = dot4(bm[s][r2], sdE + (sb4 + s) * 64 + i0);
            float ps = dot4(bm[s][r2], sdS + (sb4 + s) * 64 + i0);
            pd += __shfl_xor(pd, 1); ps += __shfl_xor(ps, 1);
            pd += __shfl_xor(pd, 2); ps += __shfl_xor(ps, 2);
            pd += __shfl_xor(pd, 4); ps += __shfl_xor(ps, 4);
            pd += __shfl_xor(pd, 8); ps += __shfl_xor(ps, 8);
            if ((cn & 15) == 0) {
                int kk = r2 * 16 + khl;
                sBdE[(sb4 + s) * 64 + kk] = pd;
                sBdS[(sb4 + s) * 64 + kk] = ps;
            }
        }
    }
    __syncthreads();

    // v = BdS - beta*BdE  (one element per thread)
    {
        int s = tid >> 6;
        float beta = sScal[s * 4 + 1] / sScal[s * 4 + 0];
        sv[tid] = sBdS[tid] - beta * sBdE[tid];
    }
    __syncthreads();
    {
        int s = tid >> 6;
        unsafeAtomicAdd(&sScal[s * 4 + 2], sdE[tid] * sv[tid]);
    }
    __syncthreads();

    // ============ pass2: q = Bm @ v from registers ============
    #pragma unroll
    for (int r2 = 0; r2 < 4; ++r2) {
        #pragma unroll
        for (int s = 0; s < 4; ++s) {
            float pq = dot4(bm[s][r2], sv + (sb4 + s) * 64 + i0);
            pq += __shfl_xor(pq, 1);
            pq += __shfl_xor(pq, 2);
            pq += __shfl_xor(pq, 4);
            pq += __shfl_xor(pq, 8);
            if ((cn & 15) == 0) sq[(sb4 + s) * 64 + r2 * 16 + khl] = pq;
        }
    }
    __syncthreads();

    // r[m] = sum_k C[k,m] * (q[k] - gamma*BdE[k])
    if (tid < 256) {
        int s = tid >> 4, m = tid & 15;
        float gamma = sScal[s * 4 + 2] / sScal[s * 4 + 0];
        float r = 0.f;
        #pragma unroll 4
        for (int k = 0; k < 64; ++k) {
            float wv = sq[s * 64 + k] - gamma * sBdE[s * 64 + k];
            r = fmaf(sC[s * 1089 + k * 17 + m], wv, r);
        }
        sr[s * 16 + m] = r;
    }
    __syncthreads();
    // out_k += sum_m C[k,m] * r[m]  (one element per thread)
    {
        int s = tid >> 6, k = tid & 63;
        float o = 0.f;
        #pragma unroll
        for (int m2 = 0; m2 < 16; ++m2)
            o = fmaf(sC[s * 1089 + k * 17 + m2], sr[s * 16 + m2], o);
        int gi = sbase * 64 + tid;
        dout[gi] = dout[gi] + o;
    }
}

extern "C" void kernel_launch(void* const* d_in, const int* in_sizes, int n_in,
                              void* d_out, int out_size, void* d_ws, size_t ws_size,
                              hipStream_t stream)
{
    (void)in_sizes; (void)n_in; (void)out_size;
    const float* y = (const float*)d_in[1];
    const float* W0[5]; const float* b0[5]; const float* W1[5]; const float* b1[5]; const float* W2[5];
    for (int m = 0; m < 5; ++m) {
        int base = 2 + m * 5;
        W0[m] = (const float*)d_in[base + 0];
        b0[m] = (const float*)d_in[base + 1];
        W1[m] = (const float*)d_in[base + 2];
        b1[m] = (const float*)d_in[base + 3];
        W2[m] = (const float*)d_in[base + 4];
    }
    float* ws = (float*)d_ws;
    float* dout = (float*)d_out;
    if (ws_size < (size_t)WS_FLOATS * sizeof(float)) return;

    for (int m = 0; m < 5; ++m) {
        hipLaunchKernelGGL(k_transpose, dim3((256 * 64 + 255) / 256), dim3(256), 0, stream,
                           W0[m], ws + OFF_W0T + m * 16384, 256, 64);
        hipLaunchKernelGGL(k_transpose, dim3((256 * 256 + 255) / 256), dim3(256), 0, stream,
                           W1[m], ws + OFF_W1T + m * 65536, 256, 256);
    }
    hipLaunchKernelGGL(k_transpose, dim3((2016 * 256 + 255) / 256), dim3(256), 0, stream,
                       W2[2], ws + OFF_W2PT, 2016, 256);
    hipLaunchKernelGGL(k_transpose, dim3((1024 * 256 + 255) / 256), dim3(256), 0, stream,
                       W2[3], ws + OFF_W2CT, 1024, 256);
    hipLaunchKernelGGL(k_transpose, dim3((4096 * 256 + 255) / 256), dim3(256), 0, stream,
                       W2[4], ws + OFF_W2BT, 4096, 256);

    hipLaunchKernelGGL(k1_grads, dim3(1024), dim3(256), 0, stream,
                       y, ws,
                       W0[0], b0[0], W1[0], b1[0], W2[0],
                       W0[1], b0[1], W1[1], b1[1], W2[1],
                       ws + OFF_DE, ws + OFF_DS);

    const int k2_smem = 154112;
    hipFuncSetAttribute((const void*)k2_poisson, hipFuncAttributeMaxDynamicSharedMemorySize, k2_smem);
    hipLaunchKernelGGL(k2_poisson, dim3(1024), dim3(512), k2_smem, stream,
                       y, ws, b0[2], b1[2], dout);

    const int k3_smem = 132416;
    hipFuncSetAttribute((const void*)k3_friction, hipFuncAttributeMaxDynamicSharedMemorySize, k3_smem);
    hipLaunchKernelGGL(k3_friction, dim3(1024), dim3(1024), k3_smem, stream,
                       y, ws, b0[3], b1[3], b0[4], b1[4], dout);
}

// Round 5
// 1811.144 us; speedup vs baseline: 2.6856x; 1.1490x over previous
//
#include <hip/hip_runtime.h>
#include <math.h>

// Problem constants: B=16384 samples, DIM=64, WIDTH=256, DD=64, C2=16
#define SB 16      // samples per workgroup
#define PAD 17     // LDS row pad for transposed [neuron][sample] tiles (k1)

// ws layout (float offsets)
#define OFF_W0T  0            // 5 x (64x256)
#define OFF_W1T  81920        // 5 x (256x256)
#define OFF_W2PT 409600       // 256x2016
#define OFF_W2CT 925696       // 256x1024
#define OFF_W2BT 1187840      // 256x4096
#define OFF_DE   2236416      // 16384x64
#define OFF_DS   3284992      // 16384x64
#define WS_FLOATS 4337600     // ~17.35 MB

__device__ __forceinline__ void fma16(float* acc0, float* acc1, float a0, float a1,
                                      float4 wA, float4 wB) {
    float w[8] = {wA.x, wA.y, wA.z, wA.w, wB.x, wB.y, wB.z, wB.w};
    #pragma unroll
    for (int q = 0; q < 8; ++q) {
        acc0[q] = fmaf(a0, w[q], acc0[q]);
        acc1[q] = fmaf(a1, w[q], acc1[q]);
    }
}

__device__ __forceinline__ void fma8v(float* acc0, float* acc1, float a0, float a1, float4 w) {
    acc0[0] = fmaf(a0, w.x, acc0[0]); acc0[1] = fmaf(a0, w.y, acc0[1]);
    acc0[2] = fmaf(a0, w.z, acc0[2]); acc0[3] = fmaf(a0, w.w, acc0[3]);
    acc1[0] = fmaf(a1, w.x, acc1[0]); acc1[1] = fmaf(a1, w.y, acc1[1]);
    acc1[2] = fmaf(a1, w.z, acc1[2]); acc1[3] = fmaf(a1, w.w, acc1[3]);
}

__device__ __forceinline__ void fma4acc(float* a, float h, float4 w) {
    a[0] = fmaf(h, w.x, a[0]); a[1] = fmaf(h, w.y, a[1]);
    a[2] = fmaf(h, w.z, a[2]); a[3] = fmaf(h, w.w, a[3]);
}

__device__ __forceinline__ float4 f4fma(float a, float4 w, float4 c) {
    c.x = fmaf(a, w.x, c.x); c.y = fmaf(a, w.y, c.y);
    c.z = fmaf(a, w.z, c.z); c.w = fmaf(a, w.w, c.w);
    return c;
}

__device__ __forceinline__ float dot4f(float4 a, float4 b) {
    return fmaf(a.w, b.w, fmaf(a.z, b.z, fmaf(a.y, b.y, a.x * b.x)));
}

// out[c*R + r] = in[r*C + c]   (in: R rows x C cols, row-major)
__global__ void k_transpose(const float* __restrict__ in, float* __restrict__ out, int R, int C) {
    int tid = blockIdx.x * blockDim.x + threadIdx.x;
    if (tid >= R * C) return;
    int c = tid / R, r = tid - c * R;
    out[tid] = in[r * C + c];
}

// ---------------- K1: dE, dS (energy/entropy forward + analytic backward) ----------------
__global__ __launch_bounds__(256) void k1_grads(
    const float* __restrict__ y, const float* __restrict__ ws,
    const float* __restrict__ W0E, const float* __restrict__ b0E,
    const float* __restrict__ W1E, const float* __restrict__ b1E,
    const float* __restrict__ w2E,
    const float* __restrict__ W0S, const float* __restrict__ b0S,
    const float* __restrict__ W1S, const float* __restrict__ b1S,
    const float* __restrict__ w2S,
    float* __restrict__ odE, float* __restrict__ odS)
{
    __shared__ float sYT[64][PAD];
    __shared__ float sH1T[256][PAD];
    __shared__ float sH2T[256][PAD];
    __shared__ float sUT[256][PAD];

    const int tid = threadIdx.x;
    const int sbase = blockIdx.x * SB;
    for (int idx = tid; idx < SB * 64; idx += 256) {
        int s = idx >> 6, i = idx & 63;
        sYT[i][s] = y[(sbase + s) * 64 + i];
    }
    __syncthreads();

    const int ts = tid >> 5, tn = tid & 31;
    const int s0 = 2 * ts, s1 = s0 + 1;

    for (int m = 0; m < 2; ++m) {
        const float* w0t = ws + OFF_W0T + m * 16384;
        const float* w1t = ws + OFF_W1T + m * 65536;
        const float* W0 = m ? W0S : W0E;
        const float* W1 = m ? W1S : W1E;
        const float* b0 = m ? b0S : b0E;
        const float* b1 = m ? b1S : b1E;
        const float* w2 = m ? w2S : w2E;
        float* outg = m ? odS : odE;

        // H1 = tanh(Y @ W0^T + b0), K=64
        {
            float acc0[8] = {0}, acc1[8] = {0};
            #pragma unroll 4
            for (int k = 0; k < 64; ++k) {
                float a0 = sYT[k][s0], a1 = sYT[k][s1];
                float4 wA = *(const float4*)(w0t + k * 256 + tn * 8);
                float4 wB = *(const float4*)(w0t + k * 256 + tn * 8 + 4);
                fma16(acc0, acc1, a0, a1, wA, wB);
            }
            #pragma unroll
            for (int q = 0; q < 8; ++q) {
                int j = tn * 8 + q;
                float b = b0[j];
                sH1T[j][s0] = tanhf(acc0[q] + b);
                sH1T[j][s1] = tanhf(acc1[q] + b);
            }
        }
        __syncthreads();
        // H2 = tanh(H1 @ W1^T + b1), K=256
        {
            float acc0[8] = {0}, acc1[8] = {0};
            #pragma unroll 4
            for (int k = 0; k < 256; ++k) {
                float a0 = sH1T[k][s0], a1 = sH1T[k][s1];
                float4 wA = *(const float4*)(w1t + k * 256 + tn * 8);
                float4 wB = *(const float4*)(w1t + k * 256 + tn * 8 + 4);
                fma16(acc0, acc1, a0, a1, wA, wB);
            }
            #pragma unroll
            for (int q = 0; q < 8; ++q) {
                int j = tn * 8 + q;
                float b = b1[j];
                sH2T[j][s0] = tanhf(acc0[q] + b);
                sH2T[j][s1] = tanhf(acc1[q] + b);
            }
        }
        __syncthreads();
        // G2 = (1 - H2^2) * w2  (in place)
        for (int idx = tid; idx < 256 * SB; idx += 256) {
            int j = idx >> 4, s = idx & 15;
            float h = sH2T[j][s];
            sH2T[j][s] = (1.f - h * h) * w2[j];
        }
        __syncthreads();
        // U = G2 @ W1 (natural layout), fused G1 = (1-H1^2)*U
        {
            float acc0[8] = {0}, acc1[8] = {0};
            #pragma unroll 4
            for (int k = 0; k < 256; ++k) {
                float a0 = sH2T[k][s0], a1 = sH2T[k][s1];
                float4 wA = *(const float4*)(W1 + k * 256 + tn * 8);
                float4 wB = *(const float4*)(W1 + k * 256 + tn * 8 + 4);
                fma16(acc0, acc1, a0, a1, wA, wB);
            }
            #pragma unroll
            for (int q = 0; q < 8; ++q) {
                int ko = tn * 8 + q;
                float h0 = sH1T[ko][s0], h1v = sH1T[ko][s1];
                sUT[ko][s0] = (1.f - h0 * h0) * acc0[q];
                sUT[ko][s1] = (1.f - h1v * h1v) * acc1[q];
            }
        }
        __syncthreads();
        // dE = G1 @ W0 (natural layout)
        {
            float a00 = 0, a01 = 0, a10 = 0, a11 = 0;
            #pragma unroll 4
            for (int k = 0; k < 256; ++k) {
                float g0 = sUT[k][s0], g1 = sUT[k][s1];
                float2 w = *(const float2*)(W0 + k * 64 + tn * 2);
                a00 = fmaf(g0, w.x, a00); a01 = fmaf(g0, w.y, a01);
                a10 = fmaf(g1, w.x, a10); a11 = fmaf(g1, w.y, a11);
            }
            outg[(sbase + s0) * 64 + tn * 2]     = a00;
            outg[(sbase + s0) * 64 + tn * 2 + 1] = a01;
            outg[(sbase + s1) * 64 + tn * 2]     = a10;
            outg[(sbase + s1) * 64 + tn * 2 + 1] = a11;
        }
        __syncthreads();
    }
}

// ---------------- K2: pA head + poisson (atomic-free), writes d_out ----------------
__global__ __launch_bounds__(512) void k2_poisson(
    const float* __restrict__ y, const float* __restrict__ ws,
    const float* __restrict__ b0P, const float* __restrict__ b1P,
    float* __restrict__ dout)
{
    extern __shared__ float smem[];
    float* sa  = smem;            // 16 x 2024 (a-values, padded). Aliased: H1 @ [0,4096), y @ [4096,5120)
    float* sH2 = smem + 32384;    // 16 x 256
    float* sdE = sH2 + 4096;      // 16 x 64
    float* sdS = sdE + 1024;      // 16 x 64
    // total 38528 floats = 154112 B

    float* sH1 = sa;              // alias (dead before a-GEMM writes)
    float* sy  = sa + 4096;       // alias (dead after H1)

    const int tid = threadIdx.x;
    const int sbase = blockIdx.x * SB;
    const float* gdE = ws + OFF_DE;
    const float* gdS = ws + OFF_DS;

    // P0: load y, dE, dS ([s][i] contiguous)
    for (int idx = tid; idx < SB * 64; idx += 512) {
        sy[idx]  = y[sbase * 64 + idx];
        sdE[idx] = gdE[sbase * 64 + idx];
        sdS[idx] = gdS[sbase * 64 + idx];
    }
    __syncthreads();

    const int ts = tid >> 6, tn = tid & 63, n4 = tn * 4;
    const int fs0 = 2 * ts, fs1 = fs0 + 1;

    // P1: H1 = tanh(y @ W0^T + b0)
    {
        const float* w0t = ws + OFF_W0T + 2 * 16384;
        float acc0[4] = {0}, acc1[4] = {0};
        #pragma unroll 4
        for (int k = 0; k < 64; ++k) {
            float a0 = sy[fs0 * 64 + k], a1 = sy[fs1 * 64 + k];
            float4 w = *(const float4*)(w0t + k * 256 + n4);
            fma8v(acc0, acc1, a0, a1, w);
        }
        float4 o0, o1;
        o0.x = tanhf(acc0[0] + b0P[n4]);     o1.x = tanhf(acc1[0] + b0P[n4]);
        o0.y = tanhf(acc0[1] + b0P[n4 + 1]); o1.y = tanhf(acc1[1] + b0P[n4 + 1]);
        o0.z = tanhf(acc0[2] + b0P[n4 + 2]); o1.z = tanhf(acc1[2] + b0P[n4 + 2]);
        o0.w = tanhf(acc0[3] + b0P[n4 + 3]); o1.w = tanhf(acc1[3] + b0P[n4 + 3]);
        *(float4*)(sH1 + fs0 * 256 + n4) = o0;
        *(float4*)(sH1 + fs1 * 256 + n4) = o1;
    }
    __syncthreads();

    // P2: H2 = tanh(H1 @ W1^T + b1)
    {
        const float* w1t = ws + OFF_W1T + 2 * 65536;
        float acc0[4] = {0}, acc1[4] = {0};
        #pragma unroll 4
        for (int k = 0; k < 256; ++k) {
            float a0 = sH1[fs0 * 256 + k], a1 = sH1[fs1 * 256 + k];
            float4 w = *(const float4*)(w1t + k * 256 + n4);
            fma8v(acc0, acc1, a0, a1, w);
        }
        float4 o0, o1;
        o0.x = tanhf(acc0[0] + b1P[n4]);     o1.x = tanhf(acc1[0] + b1P[n4]);
        o0.y = tanhf(acc0[1] + b1P[n4 + 1]); o1.y = tanhf(acc1[1] + b1P[n4 + 1]);
        o0.z = tanhf(acc0[2] + b1P[n4 + 2]); o1.z = tanhf(acc1[2] + b1P[n4 + 2]);
        o0.w = tanhf(acc0[3] + b1P[n4 + 3]); o1.w = tanhf(acc1[3] + b1P[n4 + 3]);
        *(float4*)(sH2 + fs0 * 256 + n4) = o0;
        *(float4*)(sH2 + fs1 * 256 + n4) = o1;
    }
    __syncthreads();   // H1/y regions dead; sa fully writable

    // P3: a-GEMM. 4 samples/thread
    {
        const int tg = tid >> 7, cn = tid & 127;
        const int sb4 = tg * 4;
        const float* w2pt = ws + OFF_W2PT;
        #pragma unroll 1
        for (int ch = 0; ch < 2; ++ch) {
            const int cb = ch * 1008;
            if (cn < 126) {
                float acc[4][8];
                #pragma unroll
                for (int s = 0; s < 4; ++s)
                    #pragma unroll
                    for (int q = 0; q < 8; ++q) acc[s][q] = 0.f;
                const float* wp = w2pt + cb + cn * 8;
                #pragma unroll 2
                for (int k = 0; k < 256; ++k) {
                    float4 wA = *(const float4*)(wp + k * 2016);
                    float4 wB = *(const float4*)(wp + k * 2016 + 4);
                    float h0 = sH2[(sb4 + 0) * 256 + k];
                    float h1 = sH2[(sb4 + 1) * 256 + k];
                    float h2 = sH2[(sb4 + 2) * 256 + k];
                    float h3 = sH2[(sb4 + 3) * 256 + k];
                    fma4acc(&acc[0][0], h0, wA); fma4acc(&acc[0][4], h0, wB);
                    fma4acc(&acc[1][0], h1, wA); fma4acc(&acc[1][4], h1, wB);
                    fma4acc(&acc[2][0], h2, wA); fma4acc(&acc[2][4], h2, wB);
                    fma4acc(&acc[3][0], h3, wA); fma4acc(&acc[3][4], h3, wB);
                }
                #pragma unroll
                for (int s = 0; s < 4; ++s) {
                    float* p = sa + (sb4 + s) * 2024 + cb + cn * 8;
                    *(float4*)(p)     = make_float4(acc[s][0], acc[s][1], acc[s][2], acc[s][3]);
                    *(float4*)(p + 4) = make_float4(acc[s][4], acc[s][5], acc[s][6], acc[s][7]);
                }
            }
        }
    }
    __syncthreads();

    // P4: gather.  thread -> sample s = tid>>5, rows i and i+32 (i = tid&31).
    {
        const int s = tid >> 5;
        const int i1 = tid & 31, i2 = i1 + 32;
        const int ib1 = i1 * (i1 - 1) / 2;
        const int ib2 = i2 * (i2 - 1) / 2;
        const float* ap = sa + s * 2024;
        const float* dep = sdE + s * 64;
        const float* dsp = sdS + s * 64;

        float adE1 = 0.f, adS1 = 0.f, adE2 = 0.f, adS2 = 0.f;
        int trij = 0;   // j*(j-1)/2
        #pragma unroll 4
        for (int j = 0; j < 64; ++j) {
            float dej = dep[j], dsj = dsp[j];
            {
                int t = (j < i1) ? (ib1 + j) : (trij + i1);
                float sel = (j < i1) ? 1.f : ((j == i1) ? 0.f : -1.f);
                float c = sel * ap[t];
                adE1 = fmaf(c, dej, adE1);
                adS1 = fmaf(c, dsj, adS1);
            }
            {
                int t = (j < i2) ? (ib2 + j) : (trij + i2);
                float sel = (j < i2) ? 1.f : ((j == i2) ? 0.f : -1.f);
                float c = sel * ap[t];
                adE2 = fmaf(c, dej, adE2);
                adS2 = fmaf(c, dsj, adS2);
            }
            trij += j;
        }

        float de1 = dep[i1], de2 = dep[i2];
        float ds1 = dsp[i1], ds2 = dsp[i2];
        float p0 = de1 * adS1 + de2 * adS2;   // dE . AdS
        float p1 = de1 * ds1 + de2 * ds2;     // dE . dS
        float p2 = ds1 * ds1 + ds2 * ds2;     // dS . dS
        #pragma unroll
        for (int m = 1; m <= 16; m <<= 1) {
            p0 += __shfl_xor(p0, m);
            p1 += __shfl_xor(p1, m);
            p2 += __shfl_xor(p2, m);
        }
        float inv = 1.f / p2;
        dout[(sbase + s) * 64 + i1] = adE1 + (p0 * ds1 - p1 * adS1) * inv;
        dout[(sbase + s) * 64 + i2] = adE2 + (p0 * ds2 - p1 * adS2) * inv;
    }
}

// ---------------- K3: fC/fB heads + friction, accumulates into d_out ----------------
// 1024 threads, SB=16. Weight-dedup design: every W2BT/W2CT element read ONCE
// per block; W0T/W1T read 4x (one per sample-quad). Activations kept in
// TRANSPOSED LDS tiles ([neuron][sample], stride 16 -> b128-aligned rows) so
// wide GEMMs get all 16 samples' h via 4 broadcast ds_read_b128.
__global__ __launch_bounds__(1024, 4) void k3_friction(
    const float* __restrict__ y, const float* __restrict__ ws,
    const float* __restrict__ b0C, const float* __restrict__ b1C,
    const float* __restrict__ b0B, const float* __restrict__ b1B,
    float* __restrict__ dout)
{
    extern __shared__ float smem[];
    float* sYT  = smem;               // [64][16]  y transposed
    float* sAT  = sYT + 1024;         // [256][16] H1 transposed
    float* sBT  = sAT + 4096;         // [256][16] H2 transposed (fC then fB)
    float* sC   = sBT + 4096;         // 16*1089: C[s][k*17+m]
    float* sdE  = sC + 17424;         // [s][i]
    float* sdS  = sdE + 1024;
    float* sBdE = sdS + 1024;
    float* sBdS = sBdE + 1024;
    float* sv   = sBdS + 1024;
    float* sq   = sv + 1024;
    float* sScal = sq + 1024;         // 16*4: [0]=dE.dE [1]=dE.dS [2]=dE.v
    float* sr   = sScal + 64;         // 16*16
    // total = 33104 floats = 132416 B

    const int tid = threadIdx.x;
    const int sbase = blockIdx.x * SB;
    const float* gdE = ws + OFF_DE;
    const float* gdS = ws + OFF_DS;

    // one element per thread (SB*64 == 1024); y stored transposed
    {
        int s = tid >> 6, i = tid & 63;
        sYT[i * 16 + s] = y[sbase * 64 + tid];
        sdE[tid] = gdE[sbase * 64 + tid];
        sdS[tid] = gdS[sbase * 64 + tid];
    }
    if (tid < 64) sScal[tid] = 0.f;
    __syncthreads();

    {
        int s = tid >> 6;
        float de = sdE[tid];
        unsafeAtomicAdd(&sScal[s * 4 + 0], de * de);
        unsafeAtomicAdd(&sScal[s * 4 + 1], de * sdS[tid]);
    }

    // forward mapping: column c (0..255) x sample-quad sg (0..3)
    const int c  = tid & 255;
    const int sg = tid >> 8;
    const int s4 = sg * 4;
    // wide-GEMM mapping: thread = one column-quad of the flattened output
    const int kp = tid >> 4;          // Bm row 0..63
    const int i0 = 4 * (tid & 15);    // Bm col segment

    // ============ fC forward ============
    {
        const float* w0t = ws + OFF_W0T + 3 * 16384;
        float acc[4] = {0, 0, 0, 0};
        #pragma unroll 4
        for (int k = 0; k < 64; ++k) {
            float w = w0t[k * 256 + c];
            float4 yv = *(const float4*)(sYT + k * 16 + s4);
            acc[0] = fmaf(yv.x, w, acc[0]);
            acc[1] = fmaf(yv.y, w, acc[1]);
            acc[2] = fmaf(yv.z, w, acc[2]);
            acc[3] = fmaf(yv.w, w, acc[3]);
        }
        float b = b0C[c];
        *(float4*)(sAT + c * 16 + s4) =
            make_float4(tanhf(acc[0] + b), tanhf(acc[1] + b), tanhf(acc[2] + b), tanhf(acc[3] + b));
    }
    __syncthreads();
    {
        const float* w1t = ws + OFF_W1T + 3 * 65536;
        float acc[4] = {0, 0, 0, 0};
        #pragma unroll 4
        for (int k = 0; k < 256; ++k) {
            float w = w1t[k * 256 + c];
            float4 hv = *(const float4*)(sAT + k * 16 + s4);
            acc[0] = fmaf(hv.x, w, acc[0]);
            acc[1] = fmaf(hv.y, w, acc[1]);
            acc[2] = fmaf(hv.z, w, acc[2]);
            acc[3] = fmaf(hv.w, w, acc[3]);
        }
        float b = b1C[c];
        *(float4*)(sBT + c * 16 + s4) =
            make_float4(tanhf(acc[0] + b), tanhf(acc[1] + b), tanhf(acc[2] + b), tanhf(acc[3] + b));
    }
    __syncthreads();

    // ============ C head: full dedup, thread = one column n=tid, 16 samples ============
    {
        const float* w2ct = ws + OFF_W2CT;
        float acc[16];
        #pragma unroll
        for (int s = 0; s < 16; ++s) acc[s] = 0.f;
        #pragma unroll 2
        for (int k = 0; k < 256; ++k) {
            float w = w2ct[k * 1024 + tid];
            float4 h0 = *(const float4*)(sBT + k * 16);
            float4 h1 = *(const float4*)(sBT + k * 16 + 4);
            float4 h2 = *(const float4*)(sBT + k * 16 + 8);
            float4 h3 = *(const float4*)(sBT + k * 16 + 12);
            float hs[16] = {h0.x, h0.y, h0.z, h0.w, h1.x, h1.y, h1.z, h1.w,
                            h2.x, h2.y, h2.z, h2.w, h3.x, h3.y, h3.z, h3.w};
            #pragma unroll
            for (int s = 0; s < 16; ++s) acc[s] = fmaf(hs[s], w, acc[s]);
        }
        const int kC = tid >> 4, mC = tid & 15;
        #pragma unroll
        for (int s = 0; s < 16; ++s) sC[s * 1089 + kC * 17 + mC] = acc[s];
    }
    __syncthreads();

    // ============ fB forward (reuse sAT, sBT) ============
    {
        const float* w0t = ws + OFF_W0T + 4 * 16384;
        float acc[4] = {0, 0, 0, 0};
        #pragma unroll 4
        for (int k = 0; k < 64; ++k) {
            float w = w0t[k * 256 + c];
            float4 yv = *(const float4*)(sYT + k * 16 + s4);
            acc[0] = fmaf(yv.x, w, acc[0]);
            acc[1] = fmaf(yv.y, w, acc[1]);
            acc[2] = fmaf(yv.z, w, acc[2]);
            acc[3] = fmaf(yv.w, w, acc[3]);
        }
        float b = b0B[c];
        *(float4*)(sAT + c * 16 + s4) =
            make_float4(tanhf(acc[0] + b), tanhf(acc[1] + b), tanhf(acc[2] + b), tanhf(acc[3] + b));
    }
    __syncthreads();
    {
        const float* w1t = ws + OFF_W1T + 4 * 65536;
        float acc[4] = {0, 0, 0, 0};
        #pragma unroll 4
        for (int k = 0; k < 256; ++k) {
            float w = w1t[k * 256 + c];
            float4 hv = *(const float4*)(sAT + k * 16 + s4);
            acc[0] = fmaf(hv.x, w, acc[0]);
            acc[1] = fmaf(hv.y, w, acc[1]);
            acc[2] = fmaf(hv.z, w, acc[2]);
            acc[3] = fmaf(hv.w, w, acc[3]);
        }
        float b = b1B[c];
        *(float4*)(sBT + c * 16 + s4) =
            make_float4(tanhf(acc[0] + b), tanhf(acc[1] + b), tanhf(acc[2] + b), tanhf(acc[3] + b));
    }
    __syncthreads();

    // ============ Bm pass1: full dedup; bm[16] float4 held for pass2 ============
    // thread covers Bm flat n = 4*tid..4*tid+3  ->  k' = tid>>4, i = i0..i0+3
    float4 bm[16];
    #pragma unroll
    for (int s = 0; s < 16; ++s) bm[s] = make_float4(0.f, 0.f, 0.f, 0.f);
    {
        const float* wb = ws + OFF_W2BT + 4 * tid;
        #pragma unroll 2
        for (int k = 0; k < 256; ++k) {
            float4 w = *(const float4*)(wb + k * 4096);
            float4 h0 = *(const float4*)(sBT + k * 16);
            float4 h1 = *(const float4*)(sBT + k * 16 + 4);
            float4 h2 = *(const float4*)(sBT + k * 16 + 8);
            float4 h3 = *(const float4*)(sBT + k * 16 + 12);
            float hs[16] = {h0.x, h0.y, h0.z, h0.w, h1.x, h1.y, h1.z, h1.w,
                            h2.x, h2.y, h2.z, h2.w, h3.x, h3.y, h3.z, h3.w};
            #pragma unroll
            for (int s = 0; s < 16; ++s) bm[s] = f4fma(hs[s], w, bm[s]);
        }
    }
    // BdotdE/BdotdS: reduce over i via 16-lane shfl
    #pragma unroll
    for (int s = 0; s < 16; ++s) {
        float4 de = *(const float4*)(sdE + s * 64 + i0);
        float4 dsv = *(const float4*)(sdS + s * 64 + i0);
        float pd = dot4f(bm[s], de);
        float ps = dot4f(bm[s], dsv);
        pd += __shfl_xor(pd, 1); ps += __shfl_xor(ps, 1);
        pd += __shfl_xor(pd, 2); ps += __shfl_xor(ps, 2);
        pd += __shfl_xor(pd, 4); ps += __shfl_xor(ps, 4);
        pd += __shfl_xor(pd, 8); ps += __shfl_xor(ps, 8);
        if ((tid & 15) == 0) {
            sBdE[s * 64 + kp] = pd;
            sBdS[s * 64 + kp] = ps;
        }
    }
    __syncthreads();

    // v = BdS - beta*BdE  (one element per thread)
    {
        int s = tid >> 6;
        float beta = sScal[s * 4 + 1] / sScal[s * 4 + 0];
        sv[tid] = sBdS[tid] - beta * sBdE[tid];
    }
    __syncthreads();
    {
        int s = tid >> 6;
        unsafeAtomicAdd(&sScal[s * 4 + 2], sdE[tid] * sv[tid]);
    }
    __syncthreads();

    // ============ pass2: q = Bm @ v from registers ============
    #pragma unroll
    for (int s = 0; s < 16; ++s) {
        float4 vv = *(const float4*)(sv + s * 64 + i0);
        float pq = dot4f(bm[s], vv);
        pq += __shfl_xor(pq, 1);
        pq += __shfl_xor(pq, 2);
        pq += __shfl_xor(pq, 4);
        pq += __shfl_xor(pq, 8);
        if ((tid & 15) == 0) sq[s * 64 + kp] = pq;
    }
    __syncthreads();

    // r[m] = sum_k C[k,m] * (q[k] - gamma*BdE[k])
    if (tid < 256) {
        int s = tid >> 4, m = tid & 15;
        float gamma = sScal[s * 4 + 2] / sScal[s * 4 + 0];
        float r = 0.f;
        #pragma unroll 4
        for (int k = 0; k < 64; ++k) {
            float wv = sq[s * 64 + k] - gamma * sBdE[s * 64 + k];
            r = fmaf(sC[s * 1089 + k * 17 + m], wv, r);
        }
        sr[s * 16 + m] = r;
    }
    __syncthreads();
    // out_k += sum_m C[k,m] * r[m]  (one element per thread)
    {
        int s = tid >> 6, k = tid & 63;
        float o = 0.f;
        #pragma unroll
        for (int m2 = 0; m2 < 16; ++m2)
            o = fmaf(sC[s * 1089 + k * 17 + m2], sr[s * 16 + m2], o);
        int gi = sbase * 64 + tid;
        dout[gi] = dout[gi] + o;
    }
}

extern "C" void kernel_launch(void* const* d_in, const int* in_sizes, int n_in,
                              void* d_out, int out_size, void* d_ws, size_t ws_size,
                              hipStream_t stream)
{
    (void)in_sizes; (void)n_in; (void)out_size;
    const float* y = (const float*)d_in[1];
    const float* W0[5]; const float* b0[5]; const float* W1[5]; const float* b1[5]; const float* W2[5];
    for (int m = 0; m < 5; ++m) {
        int base = 2 + m * 5;
        W0[m] = (const float*)d_in[base + 0];
        b0[m] = (const float*)d_in[base + 1];
        W1[m] = (const float*)d_in[base + 2];
        b1[m] = (const float*)d_in[base + 3];
        W2[m] = (const float*)d_in[base + 4];
    }
    float* ws = (float*)d_ws;
    float* dout = (float*)d_out;
    if (ws_size < (size_t)WS_FLOATS * sizeof(float)) return;

    for (int m = 0; m < 5; ++m) {
        hipLaunchKernelGGL(k_transpose, dim3((256 * 64 + 255) / 256), dim3(256), 0, stream,
                           W0[m], ws + OFF_W0T + m * 16384, 256, 64);
        hipLaunchKernelGGL(k_transpose, dim3((256 * 256 + 255) / 256), dim3(256), 0, stream,
                           W1[m], ws + OFF_W1T + m * 65536, 256, 256);
    }
    hipLaunchKernelGGL(k_transpose, dim3((2016 * 256 + 255) / 256), dim3(256), 0, stream,
                       W2[2], ws + OFF_W2PT, 2016, 256);
    hipLaunchKernelGGL(k_transpose, dim3((1024 * 256 + 255) / 256), dim3(256), 0, stream,
                       W2[3], ws + OFF_W2CT, 1024, 256);
    hipLaunchKernelGGL(k_transpose, dim3((4096 * 256 + 255) / 256), dim3(256), 0, stream,
                       W2[4], ws + OFF_W2BT, 4096, 256);

    hipLaunchKernelGGL(k1_grads, dim3(1024), dim3(256), 0, stream,
                       y, ws,
                       W0[0], b0[0], W1[0], b1[0], W2[0],
                       W0[1], b0[1], W1[1], b1[1], W2[1],
                       ws + OFF_DE, ws + OFF_DS);

    const int k2_smem = 154112;
    hipFuncSetAttribute((const void*)k2_poisson, hipFuncAttributeMaxDynamicSharedMemorySize, k2_smem);
    hipLaunchKernelGGL(k2_poisson, dim3(1024), dim3(512), k2_smem, stream,
                       y, ws, b0[2], b1[2], dout);

    const int k3_smem = 132416;
    hipFuncSetAttribute((const void*)k3_friction, hipFuncAttributeMaxDynamicSharedMemorySize, k3_smem);
    hipLaunchKernelGGL(k3_friction, dim3(1024), dim3(1024), k3_smem, stream,
                       y, ws, b0[3], b1[3], b0[4], b1[4], dout);
}

// Round 6
// 1526.258 us; speedup vs baseline: 3.1869x; 1.1867x over previous
//
#include <hip/hip_runtime.h>
#include <math.h>

// Problem constants: B=16384 samples, DIM=64, WIDTH=256, DD=64, C2=16
#define SB 16      // samples per workgroup
#define PAD 17     // LDS row pad for transposed [neuron][sample] tiles (k1)

// ws layout (float offsets)
#define OFF_W0T  0            // 5 x (64x256)
#define OFF_W1T  81920        // 5 x (256x256)
#define OFF_W2PT 409600       // 256x2016
#define OFF_W2CT 925696       // 256x1024
#define OFF_W2BT 1187840      // 256x4096
#define OFF_DE   2236416      // 16384x64
#define OFF_DS   3284992      // 16384x64
#define WS_FLOATS 4337600     // ~17.35 MB

__device__ __forceinline__ void fma16(float* acc0, float* acc1, float a0, float a1,
                                      float4 wA, float4 wB) {
    float w[8] = {wA.x, wA.y, wA.z, wA.w, wB.x, wB.y, wB.z, wB.w};
    #pragma unroll
    for (int q = 0; q < 8; ++q) {
        acc0[q] = fmaf(a0, w[q], acc0[q]);
        acc1[q] = fmaf(a1, w[q], acc1[q]);
    }
}

__device__ __forceinline__ void fma8v(float* acc0, float* acc1, float a0, float a1, float4 w) {
    acc0[0] = fmaf(a0, w.x, acc0[0]); acc0[1] = fmaf(a0, w.y, acc0[1]);
    acc0[2] = fmaf(a0, w.z, acc0[2]); acc0[3] = fmaf(a0, w.w, acc0[3]);
    acc1[0] = fmaf(a1, w.x, acc1[0]); acc1[1] = fmaf(a1, w.y, acc1[1]);
    acc1[2] = fmaf(a1, w.z, acc1[2]); acc1[3] = fmaf(a1, w.w, acc1[3]);
}

__device__ __forceinline__ void fma4acc(float* a, float h, float4 w) {
    a[0] = fmaf(h, w.x, a[0]); a[1] = fmaf(h, w.y, a[1]);
    a[2] = fmaf(h, w.z, a[2]); a[3] = fmaf(h, w.w, a[3]);
}

__device__ __forceinline__ float4 f4fma(float a, float4 w, float4 c) {
    c.x = fmaf(a, w.x, c.x); c.y = fmaf(a, w.y, c.y);
    c.z = fmaf(a, w.z, c.z); c.w = fmaf(a, w.w, c.w);
    return c;
}

__device__ __forceinline__ float dot4f(float4 a, float4 b) {
    return fmaf(a.w, b.w, fmaf(a.z, b.z, fmaf(a.y, b.y, a.x * b.x)));
}

// out[c*R + r] = in[r*C + c]   (in: R rows x C cols, row-major)
__global__ void k_transpose(const float* __restrict__ in, float* __restrict__ out, int R, int C) {
    int tid = blockIdx.x * blockDim.x + threadIdx.x;
    if (tid >= R * C) return;
    int c = tid / R, r = tid - c * R;
    out[tid] = in[r * C + c];
}

// ---------------- K1: dE, dS (energy/entropy forward + analytic backward) ----------------
__global__ __launch_bounds__(256) void k1_grads(
    const float* __restrict__ y, const float* __restrict__ ws,
    const float* __restrict__ W0E, const float* __restrict__ b0E,
    const float* __restrict__ W1E, const float* __restrict__ b1E,
    const float* __restrict__ w2E,
    const float* __restrict__ W0S, const float* __restrict__ b0S,
    const float* __restrict__ W1S, const float* __restrict__ b1S,
    const float* __restrict__ w2S,
    float* __restrict__ odE, float* __restrict__ odS)
{
    __shared__ float sYT[64][PAD];
    __shared__ float sH1T[256][PAD];
    __shared__ float sH2T[256][PAD];
    __shared__ float sUT[256][PAD];

    const int tid = threadIdx.x;
    const int sbase = blockIdx.x * SB;
    for (int idx = tid; idx < SB * 64; idx += 256) {
        int s = idx >> 6, i = idx & 63;
        sYT[i][s] = y[(sbase + s) * 64 + i];
    }
    __syncthreads();

    const int ts = tid >> 5, tn = tid & 31;
    const int s0 = 2 * ts, s1 = s0 + 1;

    for (int m = 0; m < 2; ++m) {
        const float* w0t = ws + OFF_W0T + m * 16384;
        const float* w1t = ws + OFF_W1T + m * 65536;
        const float* W0 = m ? W0S : W0E;
        const float* W1 = m ? W1S : W1E;
        const float* b0 = m ? b0S : b0E;
        const float* b1 = m ? b1S : b1E;
        const float* w2 = m ? w2S : w2E;
        float* outg = m ? odS : odE;

        // H1 = tanh(Y @ W0^T + b0), K=64
        {
            float acc0[8] = {0}, acc1[8] = {0};
            #pragma unroll 4
            for (int k = 0; k < 64; ++k) {
                float a0 = sYT[k][s0], a1 = sYT[k][s1];
                float4 wA = *(const float4*)(w0t + k * 256 + tn * 8);
                float4 wB = *(const float4*)(w0t + k * 256 + tn * 8 + 4);
                fma16(acc0, acc1, a0, a1, wA, wB);
            }
            #pragma unroll
            for (int q = 0; q < 8; ++q) {
                int j = tn * 8 + q;
                float b = b0[j];
                sH1T[j][s0] = tanhf(acc0[q] + b);
                sH1T[j][s1] = tanhf(acc1[q] + b);
            }
        }
        __syncthreads();
        // H2 = tanh(H1 @ W1^T + b1), K=256
        {
            float acc0[8] = {0}, acc1[8] = {0};
            #pragma unroll 4
            for (int k = 0; k < 256; ++k) {
                float a0 = sH1T[k][s0], a1 = sH1T[k][s1];
                float4 wA = *(const float4*)(w1t + k * 256 + tn * 8);
                float4 wB = *(const float4*)(w1t + k * 256 + tn * 8 + 4);
                fma16(acc0, acc1, a0, a1, wA, wB);
            }
            #pragma unroll
            for (int q = 0; q < 8; ++q) {
                int j = tn * 8 + q;
                float b = b1[j];
                sH2T[j][s0] = tanhf(acc0[q] + b);
                sH2T[j][s1] = tanhf(acc1[q] + b);
            }
        }
        __syncthreads();
        // G2 = (1 - H2^2) * w2  (in place)
        for (int idx = tid; idx < 256 * SB; idx += 256) {
            int j = idx >> 4, s = idx & 15;
            float h = sH2T[j][s];
            sH2T[j][s] = (1.f - h * h) * w2[j];
        }
        __syncthreads();
        // U = G2 @ W1 (natural layout), fused G1 = (1-H1^2)*U
        {
            float acc0[8] = {0}, acc1[8] = {0};
            #pragma unroll 4
            for (int k = 0; k < 256; ++k) {
                float a0 = sH2T[k][s0], a1 = sH2T[k][s1];
                float4 wA = *(const float4*)(W1 + k * 256 + tn * 8);
                float4 wB = *(const float4*)(W1 + k * 256 + tn * 8 + 4);
                fma16(acc0, acc1, a0, a1, wA, wB);
            }
            #pragma unroll
            for (int q = 0; q < 8; ++q) {
                int ko = tn * 8 + q;
                float h0 = sH1T[ko][s0], h1v = sH1T[ko][s1];
                sUT[ko][s0] = (1.f - h0 * h0) * acc0[q];
                sUT[ko][s1] = (1.f - h1v * h1v) * acc1[q];
            }
        }
        __syncthreads();
        // dE = G1 @ W0 (natural layout)
        {
            float a00 = 0, a01 = 0, a10 = 0, a11 = 0;
            #pragma unroll 4
            for (int k = 0; k < 256; ++k) {
                float g0 = sUT[k][s0], g1 = sUT[k][s1];
                float2 w = *(const float2*)(W0 + k * 64 + tn * 2);
                a00 = fmaf(g0, w.x, a00); a01 = fmaf(g0, w.y, a01);
                a10 = fmaf(g1, w.x, a10); a11 = fmaf(g1, w.y, a11);
            }
            outg[(sbase + s0) * 64 + tn * 2]     = a00;
            outg[(sbase + s0) * 64 + tn * 2 + 1] = a01;
            outg[(sbase + s1) * 64 + tn * 2]     = a10;
            outg[(sbase + s1) * 64 + tn * 2 + 1] = a11;
        }
        __syncthreads();
    }
}

// ---------------- K2: pA head + poisson (atomic-free, weight-dedup), writes d_out ----------------
// 1024 threads, SB=16, 1 block/CU (154 KB LDS), 4 waves/SIMD.
// Forwards: column c x sample-quad sg with transposed activation tiles.
// a-GEMM: thread = one t-column (t=tid, t=tid+1024), acc[16] samples in regs,
// weights read ONCE per block (2 MB), h via broadcast ds_read_b128.
// Gather: 1 row/thread, branch-free triangular indexing, full-wave shfl scalars.
__global__ __launch_bounds__(1024, 4) void k2_poisson(
    const float* __restrict__ y, const float* __restrict__ ws,
    const float* __restrict__ b0P, const float* __restrict__ b1P,
    float* __restrict__ dout)
{
    extern __shared__ float smem[];
    float* sa   = smem;            // 16 x 2024 (a-values). Aliased: H1T @ [0,4096), yT @ [4096,5120)
    float* sH2T = smem + 32384;    // [256][16]
    float* sdE  = sH2T + 4096;     // [s][i]
    float* sdS  = sdE + 1024;
    // total 38528 floats = 154112 B

    float* sH1T = sa;              // alias [256][16] (dead before a-GEMM writes)
    float* syT  = sa + 4096;       // alias [64][16]  (dead after H1)

    const int tid = threadIdx.x;
    const int sbase = blockIdx.x * SB;
    const float* gdE = ws + OFF_DE;
    const float* gdS = ws + OFF_DS;

    // P0: one element per thread; y stored transposed
    {
        int s = tid >> 6, i = tid & 63;
        syT[i * 16 + s] = y[sbase * 64 + tid];
        sdE[tid] = gdE[sbase * 64 + tid];
        sdS[tid] = gdS[sbase * 64 + tid];
    }
    __syncthreads();

    const int c  = tid & 255;
    const int sg = tid >> 8;
    const int s4 = sg * 4;

    // P1: H1 = tanh(y @ W0^T + b0)
    {
        const float* w0t = ws + OFF_W0T + 2 * 16384;
        float acc[4] = {0, 0, 0, 0};
        #pragma unroll 4
        for (int k = 0; k < 64; ++k) {
            float w = w0t[k * 256 + c];
            float4 yv = *(const float4*)(syT + k * 16 + s4);
            acc[0] = fmaf(yv.x, w, acc[0]);
            acc[1] = fmaf(yv.y, w, acc[1]);
            acc[2] = fmaf(yv.z, w, acc[2]);
            acc[3] = fmaf(yv.w, w, acc[3]);
        }
        float b = b0P[c];
        *(float4*)(sH1T + c * 16 + s4) =
            make_float4(tanhf(acc[0] + b), tanhf(acc[1] + b), tanhf(acc[2] + b), tanhf(acc[3] + b));
    }
    __syncthreads();

    // P2: H2 = tanh(H1 @ W1^T + b1)
    {
        const float* w1t = ws + OFF_W1T + 2 * 65536;
        float acc[4] = {0, 0, 0, 0};
        #pragma unroll 4
        for (int k = 0; k < 256; ++k) {
            float w = w1t[k * 256 + c];
            float4 hv = *(const float4*)(sH1T + k * 16 + s4);
            acc[0] = fmaf(hv.x, w, acc[0]);
            acc[1] = fmaf(hv.y, w, acc[1]);
            acc[2] = fmaf(hv.z, w, acc[2]);
            acc[3] = fmaf(hv.w, w, acc[3]);
        }
        float b = b1P[c];
        *(float4*)(sH2T + c * 16 + s4) =
            make_float4(tanhf(acc[0] + b), tanhf(acc[1] + b), tanhf(acc[2] + b), tanhf(acc[3] + b));
    }
    __syncthreads();   // H1T/yT regions dead; sa fully writable

    // P3: a-GEMM, full dedup. Columns t0=tid (all), t1=tid+1024 (tid<992).
    {
        const float* w2pt = ws + OFF_W2PT;
        const bool has2 = tid < 992;
        const int t0 = tid, t1 = tid + 1024;
        float acc0[16], acc1[16];
        #pragma unroll
        for (int s = 0; s < 16; ++s) { acc0[s] = 0.f; acc1[s] = 0.f; }
        #pragma unroll 2
        for (int k = 0; k < 256; ++k) {
            float4 h0 = *(const float4*)(sH2T + k * 16);
            float4 h1 = *(const float4*)(sH2T + k * 16 + 4);
            float4 h2 = *(const float4*)(sH2T + k * 16 + 8);
            float4 h3 = *(const float4*)(sH2T + k * 16 + 12);
            float w0v = w2pt[k * 2016 + t0];
            float w1v = has2 ? w2pt[k * 2016 + t1] : 0.f;
            float hs[16] = {h0.x, h0.y, h0.z, h0.w, h1.x, h1.y, h1.z, h1.w,
                            h2.x, h2.y, h2.z, h2.w, h3.x, h3.y, h3.z, h3.w};
            #pragma unroll
            for (int s = 0; s < 16; ++s) {
                acc0[s] = fmaf(hs[s], w0v, acc0[s]);
                acc1[s] = fmaf(hs[s], w1v, acc1[s]);
            }
        }
        #pragma unroll
        for (int s = 0; s < 16; ++s) sa[s * 2024 + t0] = acc0[s];
        if (has2) {
            #pragma unroll
            for (int s = 0; s < 16; ++s) sa[s * 2024 + t1] = acc1[s];
        }
    }
    __syncthreads();

    // P4: gather. thread -> sample s = tid>>6, row i = tid&63 (one wave per sample).
    {
        const int s = tid >> 6;
        const int i = tid & 63;
        const int ib = i * (i - 1) / 2;
        const float* ap = sa + s * 2024;
        const float* dep = sdE + s * 64;
        const float* dsp = sdS + s * 64;

        float adE = 0.f, adS = 0.f;
        int trij = 0;   // j*(j-1)/2
        #pragma unroll 4
        for (int j = 0; j < 64; ++j) {
            int t = (j < i) ? (ib + j) : (trij + i);
            float sel = (j < i) ? 1.f : ((j == i) ? 0.f : -1.f);
            float cc = sel * ap[t];
            adE = fmaf(cc, dep[j], adE);
            adS = fmaf(cc, dsp[j], adS);
            trij += j;
        }

        float de = dep[i], dsv = dsp[i];
        float p0 = de * adS;     // dE . AdS
        float p1 = de * dsv;     // dE . dS
        float p2 = dsv * dsv;    // dS . dS
        #pragma unroll
        for (int m = 1; m <= 32; m <<= 1) {
            p0 += __shfl_xor(p0, m);
            p1 += __shfl_xor(p1, m);
            p2 += __shfl_xor(p2, m);
        }
        float inv = 1.f / p2;
        dout[sbase * 64 + tid] = adE + (p0 * dsv - p1 * adS) * inv;
    }
}

// ---------------- K3: fC/fB heads + friction, accumulates into d_out ----------------
// 1024 threads, SB=16. Weight-dedup design: every W2BT/W2CT element read ONCE
// per block; W0T/W1T read 4x (one per sample-quad). Activations kept in
// TRANSPOSED LDS tiles ([neuron][sample], stride 16 -> b128-aligned rows) so
// wide GEMMs get all 16 samples' h via 4 broadcast ds_read_b128.
__global__ __launch_bounds__(1024, 4) void k3_friction(
    const float* __restrict__ y, const float* __restrict__ ws,
    const float* __restrict__ b0C, const float* __restrict__ b1C,
    const float* __restrict__ b0B, const float* __restrict__ b1B,
    float* __restrict__ dout)
{
    extern __shared__ float smem[];
    float* sYT  = smem;               // [64][16]  y transposed
    float* sAT  = sYT + 1024;         // [256][16] H1 transposed
    float* sBT  = sAT + 4096;         // [256][16] H2 transposed (fC then fB)
    float* sC   = sBT + 4096;         // 16*1089: C[s][k*17+m]
    float* sdE  = sC + 17424;         // [s][i]
    float* sdS  = sdE + 1024;
    float* sBdE = sdS + 1024;
    float* sBdS = sBdE + 1024;
    float* sv   = sBdS + 1024;
    float* sq   = sv + 1024;
    float* sScal = sq + 1024;         // 16*4: [0]=dE.dE [1]=dE.dS [2]=dE.v
    float* sr   = sScal + 64;         // 16*16
    // total = 33104 floats = 132416 B

    const int tid = threadIdx.x;
    const int sbase = blockIdx.x * SB;
    const float* gdE = ws + OFF_DE;
    const float* gdS = ws + OFF_DS;

    // one element per thread (SB*64 == 1024); y stored transposed
    {
        int s = tid >> 6, i = tid & 63;
        sYT[i * 16 + s] = y[sbase * 64 + tid];
        sdE[tid] = gdE[sbase * 64 + tid];
        sdS[tid] = gdS[sbase * 64 + tid];
    }
    if (tid < 64) sScal[tid] = 0.f;
    __syncthreads();

    {
        int s = tid >> 6;
        float de = sdE[tid];
        unsafeAtomicAdd(&sScal[s * 4 + 0], de * de);
        unsafeAtomicAdd(&sScal[s * 4 + 1], de * sdS[tid]);
    }

    // forward mapping: column c (0..255) x sample-quad sg (0..3)
    const int c  = tid & 255;
    const int sg = tid >> 8;
    const int s4 = sg * 4;
    // wide-GEMM mapping: thread = one column-quad of the flattened output
    const int kp = tid >> 4;          // Bm row 0..63
    const int i0 = 4 * (tid & 15);    // Bm col segment

    // ============ fC forward ============
    {
        const float* w0t = ws + OFF_W0T + 3 * 16384;
        float acc[4] = {0, 0, 0, 0};
        #pragma unroll 4
        for (int k = 0; k < 64; ++k) {
            float w = w0t[k * 256 + c];
            float4 yv = *(const float4*)(sYT + k * 16 + s4);
            acc[0] = fmaf(yv.x, w, acc[0]);
            acc[1] = fmaf(yv.y, w, acc[1]);
            acc[2] = fmaf(yv.z, w, acc[2]);
            acc[3] = fmaf(yv.w, w, acc[3]);
        }
        float b = b0C[c];
        *(float4*)(sAT + c * 16 + s4) =
            make_float4(tanhf(acc[0] + b), tanhf(acc[1] + b), tanhf(acc[2] + b), tanhf(acc[3] + b));
    }
    __syncthreads();
    {
        const float* w1t = ws + OFF_W1T + 3 * 65536;
        float acc[4] = {0, 0, 0, 0};
        #pragma unroll 4
        for (int k = 0; k < 256; ++k) {
            float w = w1t[k * 256 + c];
            float4 hv = *(const float4*)(sAT + k * 16 + s4);
            acc[0] = fmaf(hv.x, w, acc[0]);
            acc[1] = fmaf(hv.y, w, acc[1]);
            acc[2] = fmaf(hv.z, w, acc[2]);
            acc[3] = fmaf(hv.w, w, acc[3]);
        }
        float b = b1C[c];
        *(float4*)(sBT + c * 16 + s4) =
            make_float4(tanhf(acc[0] + b), tanhf(acc[1] + b), tanhf(acc[2] + b), tanhf(acc[3] + b));
    }
    __syncthreads();

    // ============ C head: full dedup, thread = one column n=tid, 16 samples ============
    {
        const float* w2ct = ws + OFF_W2CT;
        float acc[16];
        #pragma unroll
        for (int s = 0; s < 16; ++s) acc[s] = 0.f;
        #pragma unroll 2
        for (int k = 0; k < 256; ++k) {
            float w = w2ct[k * 1024 + tid];
            float4 h0 = *(const float4*)(sBT + k * 16);
            float4 h1 = *(const float4*)(sBT + k * 16 + 4);
            float4 h2 = *(const float4*)(sBT + k * 16 + 8);
            float4 h3 = *(const float4*)(sBT + k * 16 + 12);
            float hs[16] = {h0.x, h0.y, h0.z, h0.w, h1.x, h1.y, h1.z, h1.w,
                            h2.x, h2.y, h2.z, h2.w, h3.x, h3.y, h3.z, h3.w};
            #pragma unroll
            for (int s = 0; s < 16; ++s) acc[s] = fmaf(hs[s], w, acc[s]);
        }
        const int kC = tid >> 4, mC = tid & 15;
        #pragma unroll
        for (int s = 0; s < 16; ++s) sC[s * 1089 + kC * 17 + mC] = acc[s];
    }
    __syncthreads();

    // ============ fB forward (reuse sAT, sBT) ============
    {
        const float* w0t = ws + OFF_W0T + 4 * 16384;
        float acc[4] = {0, 0, 0, 0};
        #pragma unroll 4
        for (int k = 0; k < 64; ++k) {
            float w = w0t[k * 256 + c];
            float4 yv = *(const float4*)(sYT + k * 16 + s4);
            acc[0] = fmaf(yv.x, w, acc[0]);
            acc[1] = fmaf(yv.y, w, acc[1]);
            acc[2] = fmaf(yv.z, w, acc[2]);
            acc[3] = fmaf(yv.w, w, acc[3]);
        }
        float b = b0B[c];
        *(float4*)(sAT + c * 16 + s4) =
            make_float4(tanhf(acc[0] + b), tanhf(acc[1] + b), tanhf(acc[2] + b), tanhf(acc[3] + b));
    }
    __syncthreads();
    {
        const float* w1t = ws + OFF_W1T + 4 * 65536;
        float acc[4] = {0, 0, 0, 0};
        #pragma unroll 4
        for (int k = 0; k < 256; ++k) {
            float w = w1t[k * 256 + c];
            float4 hv = *(const float4*)(sAT + k * 16 + s4);
            acc[0] = fmaf(hv.x, w, acc[0]);
            acc[1] = fmaf(hv.y, w, acc[1]);
            acc[2] = fmaf(hv.z, w, acc[2]);
            acc[3] = fmaf(hv.w, w, acc[3]);
        }
        float b = b1B[c];
        *(float4*)(sBT + c * 16 + s4) =
            make_float4(tanhf(acc[0] + b), tanhf(acc[1] + b), tanhf(acc[2] + b), tanhf(acc[3] + b));
    }
    __syncthreads();

    // ============ Bm pass1: full dedup; bm[16] float4 held for pass2 ============
    // thread covers Bm flat n = 4*tid..4*tid+3  ->  k' = tid>>4, i = i0..i0+3
    float4 bm[16];
    #pragma unroll
    for (int s = 0; s < 16; ++s) bm[s] = make_float4(0.f, 0.f, 0.f, 0.f);
    {
        const float* wb = ws + OFF_W2BT + 4 * tid;
        #pragma unroll 2
        for (int k = 0; k < 256; ++k) {
            float4 w = *(const float4*)(wb + k * 4096);
            float4 h0 = *(const float4*)(sBT + k * 16);
            float4 h1 = *(const float4*)(sBT + k * 16 + 4);
            float4 h2 = *(const float4*)(sBT + k * 16 + 8);
            float4 h3 = *(const float4*)(sBT + k * 16 + 12);
            float hs[16] = {h0.x, h0.y, h0.z, h0.w, h1.x, h1.y, h1.z, h1.w,
                            h2.x, h2.y, h2.z, h2.w, h3.x, h3.y, h3.z, h3.w};
            #pragma unroll
            for (int s = 0; s < 16; ++s) bm[s] = f4fma(hs[s], w, bm[s]);
        }
    }
    // BdotdE/BdotdS: reduce over i via 16-lane shfl
    #pragma unroll
    for (int s = 0; s < 16; ++s) {
        float4 de = *(const float4*)(sdE + s * 64 + i0);
        float4 dsv = *(const float4*)(sdS + s * 64 + i0);
        float pd = dot4f(bm[s], de);
        float ps = dot4f(bm[s], dsv);
        pd += __shfl_xor(pd, 1); ps += __shfl_xor(ps, 1);
        pd += __shfl_xor(pd, 2); ps += __shfl_xor(ps, 2);
        pd += __shfl_xor(pd, 4); ps += __shfl_xor(ps, 4);
        pd += __shfl_xor(pd, 8); ps += __shfl_xor(ps, 8);
        if ((tid & 15) == 0) {
            sBdE[s * 64 + kp] = pd;
            sBdS[s * 64 + kp] = ps;
        }
    }
    __syncthreads();

    // v = BdS - beta*BdE  (one element per thread)
    {
        int s = tid >> 6;
        float beta = sScal[s * 4 + 1] / sScal[s * 4 + 0];
        sv[tid] = sBdS[tid] - beta * sBdE[tid];
    }
    __syncthreads();
    {
        int s = tid >> 6;
        unsafeAtomicAdd(&sScal[s * 4 + 2], sdE[tid] * sv[tid]);
    }
    __syncthreads();

    // ============ pass2: q = Bm @ v from registers ============
    #pragma unroll
    for (int s = 0; s < 16; ++s) {
        float4 vv = *(const float4*)(sv + s * 64 + i0);
        float pq = dot4f(bm[s], vv);
        pq += __shfl_xor(pq, 1);
        pq += __shfl_xor(pq, 2);
        pq += __shfl_xor(pq, 4);
        pq += __shfl_xor(pq, 8);
        if ((tid & 15) == 0) sq[s * 64 + kp] = pq;
    }
    __syncthreads();

    // r[m] = sum_k C[k,m] * (q[k] - gamma*BdE[k])
    if (tid < 256) {
        int s = tid >> 4, m = tid & 15;
        float gamma = sScal[s * 4 + 2] / sScal[s * 4 + 0];
        float r = 0.f;
        #pragma unroll 4
        for (int k = 0; k < 64; ++k) {
            float wv = sq[s * 64 + k] - gamma * sBdE[s * 64 + k];
            r = fmaf(sC[s * 1089 + k * 17 + m], wv, r);
        }
        sr[s * 16 + m] = r;
    }
    __syncthreads();
    // out_k += sum_m C[k,m] * r[m]  (one element per thread)
    {
        int s = tid >> 6, k = tid & 63;
        float o = 0.f;
        #pragma unroll
        for (int m2 = 0; m2 < 16; ++m2)
            o = fmaf(sC[s * 1089 + k * 17 + m2], sr[s * 16 + m2], o);
        int gi = sbase * 64 + tid;
        dout[gi] = dout[gi] + o;
    }
}

extern "C" void kernel_launch(void* const* d_in, const int* in_sizes, int n_in,
                              void* d_out, int out_size, void* d_ws, size_t ws_size,
                              hipStream_t stream)
{
    (void)in_sizes; (void)n_in; (void)out_size;
    const float* y = (const float*)d_in[1];
    const float* W0[5]; const float* b0[5]; const float* W1[5]; const float* b1[5]; const float* W2[5];
    for (int m = 0; m < 5; ++m) {
        int base = 2 + m * 5;
        W0[m] = (const float*)d_in[base + 0];
        b0[m] = (const float*)d_in[base + 1];
        W1[m] = (const float*)d_in[base + 2];
        b1[m] = (const float*)d_in[base + 3];
        W2[m] = (const float*)d_in[base + 4];
    }
    float* ws = (float*)d_ws;
    float* dout = (float*)d_out;
    if (ws_size < (size_t)WS_FLOATS * sizeof(float)) return;

    for (int m = 0; m < 5; ++m) {
        hipLaunchKernelGGL(k_transpose, dim3((256 * 64 + 255) / 256), dim3(256), 0, stream,
                           W0[m], ws + OFF_W0T + m * 16384, 256, 64);
        hipLaunchKernelGGL(k_transpose, dim3((256 * 256 + 255) / 256), dim3(256), 0, stream,
                           W1[m], ws + OFF_W1T + m * 65536, 256, 256);
    }
    hipLaunchKernelGGL(k_transpose, dim3((2016 * 256 + 255) / 256), dim3(256), 0, stream,
                       W2[2], ws + OFF_W2PT, 2016, 256);
    hipLaunchKernelGGL(k_transpose, dim3((1024 * 256 + 255) / 256), dim3(256), 0, stream,
                       W2[3], ws + OFF_W2CT, 1024, 256);
    hipLaunchKernelGGL(k_transpose, dim3((4096 * 256 + 255) / 256), dim3(256), 0, stream,
                       W2[4], ws + OFF_W2BT, 4096, 256);

    hipLaunchKernelGGL(k1_grads, dim3(1024), dim3(256), 0, stream,
                       y, ws,
                       W0[0], b0[0], W1[0], b1[0], W2[0],
                       W0[1], b0[1], W1[1], b1[1], W2[1],
                       ws + OFF_DE, ws + OFF_DS);

    const int k2_smem = 154112;
    hipFuncSetAttribute((const void*)k2_poisson, hipFuncAttributeMaxDynamicSharedMemorySize, k2_smem);
    hipLaunchKernelGGL(k2_poisson, dim3(1024), dim3(1024), k2_smem, stream,
                       y, ws, b0[2], b1[2], dout);

    const int k3_smem = 132416;
    hipFuncSetAttribute((const void*)k3_friction, hipFuncAttributeMaxDynamicSharedMemorySize, k3_smem);
    hipLaunchKernelGGL(k3_friction, dim3(1024), dim3(1024), k3_smem, stream,
                       y, ws, b0[3], b1[3], b0[4], b1[4], dout);
}

// Round 7
// 1470.942 us; speedup vs baseline: 3.3067x; 1.0376x over previous
//
#include <hip/hip_runtime.h>
#include <math.h>

// Problem constants: B=16384 samples, DIM=64, WIDTH=256, DD=64, C2=16
#define SB 16      // samples per workgroup
#define PAD 17     // LDS row pad for transposed [neuron][sample] tiles (k1)

// ws layout (float offsets)
#define OFF_W0T  0            // 5 x (64x256)
#define OFF_W1T  81920        // 5 x (256x256)
#define OFF_W2PT 409600       // 256x2016
#define OFF_W2CT 925696       // 256x1024
#define OFF_W2BT 1187840      // 256x4096
#define OFF_DE   2236416      // 16384x64
#define OFF_DS   3284992      // 16384x64
#define WS_FLOATS 4337600     // ~17.35 MB

__device__ __forceinline__ void fma16(float* acc0, float* acc1, float a0, float a1,
                                      float4 wA, float4 wB) {
    float w[8] = {wA.x, wA.y, wA.z, wA.w, wB.x, wB.y, wB.z, wB.w};
    #pragma unroll
    for (int q = 0; q < 8; ++q) {
        acc0[q] = fmaf(a0, w[q], acc0[q]);
        acc1[q] = fmaf(a1, w[q], acc1[q]);
    }
}

__device__ __forceinline__ void fma8v(float* acc0, float* acc1, float a0, float a1, float4 w) {
    acc0[0] = fmaf(a0, w.x, acc0[0]); acc0[1] = fmaf(a0, w.y, acc0[1]);
    acc0[2] = fmaf(a0, w.z, acc0[2]); acc0[3] = fmaf(a0, w.w, acc0[3]);
    acc1[0] = fmaf(a1, w.x, acc1[0]); acc1[1] = fmaf(a1, w.y, acc1[1]);
    acc1[2] = fmaf(a1, w.z, acc1[2]); acc1[3] = fmaf(a1, w.w, acc1[3]);
}

__device__ __forceinline__ float4 f4fma(float a, float4 w, float4 c) {
    c.x = fmaf(a, w.x, c.x); c.y = fmaf(a, w.y, c.y);
    c.z = fmaf(a, w.z, c.z); c.w = fmaf(a, w.w, c.w);
    return c;
}

__device__ __forceinline__ float dot4f(float4 a, float4 b) {
    return fmaf(a.w, b.w, fmaf(a.z, b.z, fmaf(a.y, b.y, a.x * b.x)));
}

__device__ __forceinline__ float4 tanh4b(float4 a, float b) {
    return make_float4(tanhf(a.x + b), tanhf(a.y + b), tanhf(a.z + b), tanhf(a.w + b));
}

// out[c*R + r] = in[r*C + c]   (in: R rows x C cols, row-major)
__global__ void k_transpose(const float* __restrict__ in, float* __restrict__ out, int R, int C) {
    int tid = blockIdx.x * blockDim.x + threadIdx.x;
    if (tid >= R * C) return;
    int c = tid / R, r = tid - c * R;
    out[tid] = in[r * C + c];
}

// ---------------- K1: dE, dS (energy/entropy forward + analytic backward) ----------------
__global__ __launch_bounds__(256) void k1_grads(
    const float* __restrict__ y, const float* __restrict__ ws,
    const float* __restrict__ W0E, const float* __restrict__ b0E,
    const float* __restrict__ W1E, const float* __restrict__ b1E,
    const float* __restrict__ w2E,
    const float* __restrict__ W0S, const float* __restrict__ b0S,
    const float* __restrict__ W1S, const float* __restrict__ b1S,
    const float* __restrict__ w2S,
    float* __restrict__ odE, float* __restrict__ odS)
{
    __shared__ float sYT[64][PAD];
    __shared__ float sH1T[256][PAD];
    __shared__ float sH2T[256][PAD];
    __shared__ float sUT[256][PAD];

    const int tid = threadIdx.x;
    const int sbase = blockIdx.x * SB;
    for (int idx = tid; idx < SB * 64; idx += 256) {
        int s = idx >> 6, i = idx & 63;
        sYT[i][s] = y[(sbase + s) * 64 + i];
    }
    __syncthreads();

    const int ts = tid >> 5, tn = tid & 31;
    const int s0 = 2 * ts, s1 = s0 + 1;

    for (int m = 0; m < 2; ++m) {
        const float* w0t = ws + OFF_W0T + m * 16384;
        const float* w1t = ws + OFF_W1T + m * 65536;
        const float* W0 = m ? W0S : W0E;
        const float* W1 = m ? W1S : W1E;
        const float* b0 = m ? b0S : b0E;
        const float* b1 = m ? b1S : b1E;
        const float* w2 = m ? w2S : w2E;
        float* outg = m ? odS : odE;

        // H1 = tanh(Y @ W0^T + b0), K=64
        {
            float acc0[8] = {0}, acc1[8] = {0};
            #pragma unroll 4
            for (int k = 0; k < 64; ++k) {
                float a0 = sYT[k][s0], a1 = sYT[k][s1];
                float4 wA = *(const float4*)(w0t + k * 256 + tn * 8);
                float4 wB = *(const float4*)(w0t + k * 256 + tn * 8 + 4);
                fma16(acc0, acc1, a0, a1, wA, wB);
            }
            #pragma unroll
            for (int q = 0; q < 8; ++q) {
                int j = tn * 8 + q;
                float b = b0[j];
                sH1T[j][s0] = tanhf(acc0[q] + b);
                sH1T[j][s1] = tanhf(acc1[q] + b);
            }
        }
        __syncthreads();
        // H2 = tanh(H1 @ W1^T + b1), K=256
        {
            float acc0[8] = {0}, acc1[8] = {0};
            #pragma unroll 4
            for (int k = 0; k < 256; ++k) {
                float a0 = sH1T[k][s0], a1 = sH1T[k][s1];
                float4 wA = *(const float4*)(w1t + k * 256 + tn * 8);
                float4 wB = *(const float4*)(w1t + k * 256 + tn * 8 + 4);
                fma16(acc0, acc1, a0, a1, wA, wB);
            }
            #pragma unroll
            for (int q = 0; q < 8; ++q) {
                int j = tn * 8 + q;
                float b = b1[j];
                sH2T[j][s0] = tanhf(acc0[q] + b);
                sH2T[j][s1] = tanhf(acc1[q] + b);
            }
        }
        __syncthreads();
        // G2 = (1 - H2^2) * w2  (in place)
        for (int idx = tid; idx < 256 * SB; idx += 256) {
            int j = idx >> 4, s = idx & 15;
            float h = sH2T[j][s];
            sH2T[j][s] = (1.f - h * h) * w2[j];
        }
        __syncthreads();
        // U = G2 @ W1 (natural layout), fused G1 = (1-H1^2)*U
        {
            float acc0[8] = {0}, acc1[8] = {0};
            #pragma unroll 4
            for (int k = 0; k < 256; ++k) {
                float a0 = sH2T[k][s0], a1 = sH2T[k][s1];
                float4 wA = *(const float4*)(W1 + k * 256 + tn * 8);
                float4 wB = *(const float4*)(W1 + k * 256 + tn * 8 + 4);
                fma16(acc0, acc1, a0, a1, wA, wB);
            }
            #pragma unroll
            for (int q = 0; q < 8; ++q) {
                int ko = tn * 8 + q;
                float h0 = sH1T[ko][s0], h1v = sH1T[ko][s1];
                sUT[ko][s0] = (1.f - h0 * h0) * acc0[q];
                sUT[ko][s1] = (1.f - h1v * h1v) * acc1[q];
            }
        }
        __syncthreads();
        // dE = G1 @ W0 (natural layout)
        {
            float a00 = 0, a01 = 0, a10 = 0, a11 = 0;
            #pragma unroll 4
            for (int k = 0; k < 256; ++k) {
                float g0 = sUT[k][s0], g1 = sUT[k][s1];
                float2 w = *(const float2*)(W0 + k * 64 + tn * 2);
                a00 = fmaf(g0, w.x, a00); a01 = fmaf(g0, w.y, a01);
                a10 = fmaf(g1, w.x, a10); a11 = fmaf(g1, w.y, a11);
            }
            outg[(sbase + s0) * 64 + tn * 2]     = a00;
            outg[(sbase + s0) * 64 + tn * 2 + 1] = a01;
            outg[(sbase + s1) * 64 + tn * 2]     = a10;
            outg[(sbase + s1) * 64 + tn * 2 + 1] = a11;
        }
        __syncthreads();
    }
}

// ---------------- K2: pA head + poisson (atomic-free, weight-dedup), writes d_out ----------------
// 1024 threads, SB=16, 1 block/CU (154 KB LDS).
// a-GEMM tiled 4 cols x 8 samples: per k, 2 broadcast b128 h-reads + 1 weight
// float4 + 32 FMA (LDS 384 cyc/CU/k vs VALU 128 — was 768).
__global__ __launch_bounds__(1024, 4) void k2_poisson(
    const float* __restrict__ y, const float* __restrict__ ws,
    const float* __restrict__ b0P, const float* __restrict__ b1P,
    float* __restrict__ dout)
{
    extern __shared__ float smem[];
    float* sa   = smem;            // 16 x 2024 (a-values). Aliased: H1T @ [0,4096), yT @ [4096,5120)
    float* sH2T = smem + 32384;    // [256][16]
    float* sdE  = sH2T + 4096;     // [s][i]
    float* sdS  = sdE + 1024;
    // total 38528 floats = 154112 B

    float* sH1T = sa;              // alias [256][16] (dead before a-GEMM writes)
    float* syT  = sa + 4096;       // alias [64][16]  (dead after H1)

    const int tid = threadIdx.x;
    const int sbase = blockIdx.x * SB;
    const float* gdE = ws + OFF_DE;
    const float* gdS = ws + OFF_DS;

    // P0: one element per thread; y stored transposed
    {
        int s = tid >> 6, i = tid & 63;
        syT[i * 16 + s] = y[sbase * 64 + tid];
        sdE[tid] = gdE[sbase * 64 + tid];
        sdS[tid] = gdS[sbase * 64 + tid];
    }
    __syncthreads();

    const int c  = tid & 255;
    const int sg = tid >> 8;
    const int s4 = sg * 4;

    // P1: H1 = tanh(y @ W0^T + b0)
    {
        const float* w0t = ws + OFF_W0T + 2 * 16384;
        float4 acc = {0, 0, 0, 0};
        #pragma unroll 4
        for (int k = 0; k < 64; ++k) {
            float w = w0t[k * 256 + c];
            float4 yv = *(const float4*)(syT + k * 16 + s4);
            acc = f4fma(w, yv, acc);
        }
        *(float4*)(sH1T + c * 16 + s4) = tanh4b(acc, b0P[c]);
    }
    __syncthreads();

    // P2: H2 = tanh(H1 @ W1^T + b1)
    {
        const float* w1t = ws + OFF_W1T + 2 * 65536;
        float4 acc = {0, 0, 0, 0};
        #pragma unroll 4
        for (int k = 0; k < 256; ++k) {
            float w = w1t[k * 256 + c];
            float4 hv = *(const float4*)(sH1T + k * 16 + s4);
            acc = f4fma(w, hv, acc);
        }
        *(float4*)(sH2T + c * 16 + s4) = tanh4b(acc, b1P[c]);
    }
    __syncthreads();   // H1T/yT regions dead; sa fully writable

    // P3: a-GEMM, tiled 4 cols x 8 samples. cq<504 covers all 2016 cols.
    {
        const int sg2 = tid >> 9;           // 0..1 (sample octet)
        const int s8  = sg2 * 8;
        const int cq  = tid & 511;          // col quad
        if (cq < 504) {
            const float* wp = ws + OFF_W2PT + 4 * cq;
            float4 acc[8];
            #pragma unroll
            for (int s = 0; s < 8; ++s) acc[s] = make_float4(0.f, 0.f, 0.f, 0.f);
            #pragma unroll 2
            for (int k = 0; k < 256; ++k) {
                float4 hA = *(const float4*)(sH2T + k * 16 + s8);
                float4 hB = *(const float4*)(sH2T + k * 16 + s8 + 4);
                float4 w = *(const float4*)(wp + k * 2016);
                acc[0] = f4fma(hA.x, w, acc[0]);
                acc[1] = f4fma(hA.y, w, acc[1]);
                acc[2] = f4fma(hA.z, w, acc[2]);
                acc[3] = f4fma(hA.w, w, acc[3]);
                acc[4] = f4fma(hB.x, w, acc[4]);
                acc[5] = f4fma(hB.y, w, acc[5]);
                acc[6] = f4fma(hB.z, w, acc[6]);
                acc[7] = f4fma(hB.w, w, acc[7]);
            }
            #pragma unroll
            for (int s = 0; s < 8; ++s)
                *(float4*)(sa + (s8 + s) * 2024 + 4 * cq) = acc[s];
        }
    }
    __syncthreads();

    // P4: gather. thread -> sample s = tid>>6, row i = tid&63 (one wave per sample).
    {
        const int s = tid >> 6;
        const int i = tid & 63;
        const int ib = i * (i - 1) / 2;
        const float* ap = sa + s * 2024;
        const float* dep = sdE + s * 64;
        const float* dsp = sdS + s * 64;

        float adE = 0.f, adS = 0.f;
        int trij = 0;   // j*(j-1)/2
        #pragma unroll 4
        for (int j = 0; j < 64; ++j) {
            int t = (j < i) ? (ib + j) : (trij + i);
            float sel = (j < i) ? 1.f : ((j == i) ? 0.f : -1.f);
            float cc = sel * ap[t];
            adE = fmaf(cc, dep[j], adE);
            adS = fmaf(cc, dsp[j], adS);
            trij += j;
        }

        float de = dep[i], dsv = dsp[i];
        float p0 = de * adS;     // dE . AdS
        float p1 = de * dsv;     // dE . dS
        float p2 = dsv * dsv;    // dS . dS
        #pragma unroll
        for (int m = 1; m <= 32; m <<= 1) {
            p0 += __shfl_xor(p0, m);
            p1 += __shfl_xor(p1, m);
            p2 += __shfl_xor(p2, m);
        }
        float inv = 1.f / p2;
        dout[sbase * 64 + tid] = adE + (p0 * dsv - p1 * adS) * inv;
    }
}

// ---------------- K3: fC/fB heads + friction, accumulates into d_out ----------------
// 1024 threads, SB=16. LDS-instruction-balanced design:
//  - forwards: fC and fB run MERGED (net = tid>>9), thread = 2 cols x 4 samples
//  - C head:   thread = 4 cols x 4 samples
//  - Bm:       thread = 4 cols x 16 samples (weights read once; bm held for pass2)
// sC aliases the dead H1 tiles. Activation tiles [neuron][16] for broadcast b128.
__global__ __launch_bounds__(1024, 4) void k3_friction(
    const float* __restrict__ y, const float* __restrict__ ws,
    const float* __restrict__ b0C, const float* __restrict__ b1C,
    const float* __restrict__ b0B, const float* __restrict__ b1B,
    float* __restrict__ dout)
{
    extern __shared__ float smem[];
    float* sYT  = smem;               // [64][16]  y transposed
    float* sBTc = smem + 1024;        // [256][16] fC H2
    float* sBTb = smem + 5120;        // [256][16] fB H2
    float* sATc = smem + 9216;        // [256][16] fC H1 (dead after L1)
    float* sATb = smem + 13312;       // [256][16] fB H1 (dead after L1)
    float* sC   = smem + 9216;        // [16][1089] OVERLAPS sATc/sATb (written in C-head)
    float* sdE  = smem + 26640;       // [s][i]
    float* sdS  = sdE + 1024;
    float* sBdE = sdS + 1024;
    float* sBdS = sBdE + 1024;
    float* sv   = sBdS + 1024;
    float* sq   = sv + 1024;
    float* sScal = sq + 1024;         // 16*4
    float* sr   = sScal + 64;         // 16*16
    // total = 33104 floats = 132416 B

    const int tid = threadIdx.x;
    const int sbase = blockIdx.x * SB;
    const float* gdE = ws + OFF_DE;
    const float* gdS = ws + OFF_DS;

    {
        int s = tid >> 6, i = tid & 63;
        sYT[i * 16 + s] = y[sbase * 64 + tid];
        sdE[tid] = gdE[sbase * 64 + tid];
        sdS[tid] = gdS[sbase * 64 + tid];
    }
    if (tid < 64) sScal[tid] = 0.f;
    __syncthreads();

    {
        int s = tid >> 6;
        float de = sdE[tid];
        unsafeAtomicAdd(&sScal[s * 4 + 0], de * de);
        unsafeAtomicAdd(&sScal[s * 4 + 1], de * sdS[tid]);
    }

    // ---- merged forward mapping: net (0=fC,1=fB) x sample-quad x col-pair ----
    const int net = tid >> 9;
    const int t9  = tid & 511;
    const int sgf = t9 >> 7;          // 0..3
    const int s4f = sgf * 4;
    const int cp  = t9 & 127;         // col pair
    const int c0 = 2 * cp, c1 = c0 + 1;
    const float* w0t = ws + OFF_W0T + (3 + net) * 16384;
    const float* w1t = ws + OFF_W1T + (3 + net) * 65536;
    const float* b0v = net ? b0B : b0C;
    const float* b1v = net ? b1B : b1C;
    float* sH1 = net ? sATb : sATc;
    float* sH2 = net ? sBTb : sBTc;

    // ============ L0 (both nets): H1 = tanh(y @ W0^T + b0) ============
    {
        float4 a0 = {0, 0, 0, 0}, a1 = {0, 0, 0, 0};
        #pragma unroll 4
        for (int k = 0; k < 64; ++k) {
            float4 h = *(const float4*)(sYT + k * 16 + s4f);
            float2 w = *(const float2*)(w0t + k * 256 + c0);
            a0 = f4fma(w.x, h, a0);
            a1 = f4fma(w.y, h, a1);
        }
        *(float4*)(sH1 + c0 * 16 + s4f) = tanh4b(a0, b0v[c0]);
        *(float4*)(sH1 + c1 * 16 + s4f) = tanh4b(a1, b0v[c1]);
    }
    __syncthreads();

    // ============ L1 (both nets): H2 = tanh(H1 @ W1^T + b1) ============
    {
        float4 a0 = {0, 0, 0, 0}, a1 = {0, 0, 0, 0};
        #pragma unroll 4
        for (int k = 0; k < 256; ++k) {
            float4 h = *(const float4*)(sH1 + k * 16 + s4f);
            float2 w = *(const float2*)(w1t + k * 256 + c0);
            a0 = f4fma(w.x, h, a0);
            a1 = f4fma(w.y, h, a1);
        }
        *(float4*)(sH2 + c0 * 16 + s4f) = tanh4b(a0, b1v[c0]);
        *(float4*)(sH2 + c1 * 16 + s4f) = tanh4b(a1, b1v[c1]);
    }
    __syncthreads();   // H1 tiles dead from here; sC region writable

    // ============ C head: thread = 4 cols x 4 samples ============
    {
        const int sgc = tid >> 8;         // 0..3
        const int s4c = sgc * 4;
        const int cq  = tid & 255;        // col quad: cols 4cq..4cq+3
        const float* w2ct = ws + OFF_W2CT + 4 * cq;
        float4 a0 = {0,0,0,0}, a1 = {0,0,0,0}, a2 = {0,0,0,0}, a3 = {0,0,0,0};
        #pragma unroll 2
        for (int k = 0; k < 256; ++k) {
            float4 h = *(const float4*)(sBTc + k * 16 + s4c);
            float4 w = *(const float4*)(w2ct + k * 1024);
            a0 = f4fma(h.x, w, a0);
            a1 = f4fma(h.y, w, a1);
            a2 = f4fma(h.z, w, a2);
            a3 = f4fma(h.w, w, a3);
        }
        const int kC = cq >> 2;            // C row (DD index of this col group)
        const int mB = 4 * (cq & 3);       // C col base
        float* p0 = sC + (s4c + 0) * 1089 + kC * 17 + mB;
        float* p1 = sC + (s4c + 1) * 1089 + kC * 17 + mB;
        float* p2 = sC + (s4c + 2) * 1089 + kC * 17 + mB;
        float* p3 = sC + (s4c + 3) * 1089 + kC * 17 + mB;
        p0[0] = a0.x; p0[1] = a0.y; p0[2] = a0.z; p0[3] = a0.w;
        p1[0] = a1.x; p1[1] = a1.y; p1[2] = a1.z; p1[3] = a1.w;
        p2[0] = a2.x; p2[1] = a2.y; p2[2] = a2.z; p2[3] = a2.w;
        p3[0] = a3.x; p3[1] = a3.y; p3[2] = a3.z; p3[3] = a3.w;
    }
    __syncthreads();

    // ============ Bm pass1: full dedup; bm[16] float4 held for pass2 ============
    const int kp = tid >> 4;          // Bm row 0..63
    const int i0 = 4 * (tid & 15);    // Bm col segment
    float4 bm[16];
    #pragma unroll
    for (int s = 0; s < 16; ++s) bm[s] = make_float4(0.f, 0.f, 0.f, 0.f);
    {
        const float* wb = ws + OFF_W2BT + 4 * tid;
        #pragma unroll 2
        for (int k = 0; k < 256; ++k) {
            float4 w = *(const float4*)(wb + k * 4096);
            float4 h0 = *(const float4*)(sBTb + k * 16);
            float4 h1 = *(const float4*)(sBTb + k * 16 + 4);
            float4 h2 = *(const float4*)(sBTb + k * 16 + 8);
            float4 h3 = *(const float4*)(sBTb + k * 16 + 12);
            float hs[16] = {h0.x, h0.y, h0.z, h0.w, h1.x, h1.y, h1.z, h1.w,
                            h2.x, h2.y, h2.z, h2.w, h3.x, h3.y, h3.z, h3.w};
            #pragma unroll
            for (int s = 0; s < 16; ++s) bm[s] = f4fma(hs[s], w, bm[s]);
        }
    }
    // BdotdE/BdotdS: reduce over i via 16-lane shfl
    #pragma unroll
    for (int s = 0; s < 16; ++s) {
        float4 de = *(const float4*)(sdE + s * 64 + i0);
        float4 dsv = *(const float4*)(sdS + s * 64 + i0);
        float pd = dot4f(bm[s], de);
        float ps = dot4f(bm[s], dsv);
        pd += __shfl_xor(pd, 1); ps += __shfl_xor(ps, 1);
        pd += __shfl_xor(pd, 2); ps += __shfl_xor(ps, 2);
        pd += __shfl_xor(pd, 4); ps += __shfl_xor(ps, 4);
        pd += __shfl_xor(pd, 8); ps += __shfl_xor(ps, 8);
        if ((tid & 15) == 0) {
            sBdE[s * 64 + kp] = pd;
            sBdS[s * 64 + kp] = ps;
        }
    }
    __syncthreads();

    // v = BdS - beta*BdE  (one element per thread)
    {
        int s = tid >> 6;
        float beta = sScal[s * 4 + 1] / sScal[s * 4 + 0];
        sv[tid] = sBdS[tid] - beta * sBdE[tid];
    }
    __syncthreads();
    {
        int s = tid >> 6;
        unsafeAtomicAdd(&sScal[s * 4 + 2], sdE[tid] * sv[tid]);
    }
    __syncthreads();

    // ============ pass2: q = Bm @ v from registers ============
    #pragma unroll
    for (int s = 0; s < 16; ++s) {
        float4 vv = *(const float4*)(sv + s * 64 + i0);
        float pq = dot4f(bm[s], vv);
        pq += __shfl_xor(pq, 1);
        pq += __shfl_xor(pq, 2);
        pq += __shfl_xor(pq, 4);
        pq += __shfl_xor(pq, 8);
        if ((tid & 15) == 0) sq[s * 64 + kp] = pq;
    }
    __syncthreads();

    // r[m] = sum_k C[k,m] * (q[k] - gamma*BdE[k])
    if (tid < 256) {
        int s = tid >> 4, m = tid & 15;
        float gamma = sScal[s * 4 + 2] / sScal[s * 4 + 0];
        float r = 0.f;
        #pragma unroll 4
        for (int k = 0; k < 64; ++k) {
            float wv = sq[s * 64 + k] - gamma * sBdE[s * 64 + k];
            r = fmaf(sC[s * 1089 + k * 17 + m], wv, r);
        }
        sr[s * 16 + m] = r;
    }
    __syncthreads();
    // out_k += sum_m C[k,m] * r[m]  (one element per thread)
    {
        int s = tid >> 6, k = tid & 63;
        float o = 0.f;
        #pragma unroll
        for (int m2 = 0; m2 < 16; ++m2)
            o = fmaf(sC[s * 1089 + k * 17 + m2], sr[s * 16 + m2], o);
        int gi = sbase * 64 + tid;
        dout[gi] = dout[gi] + o;
    }
}

extern "C" void kernel_launch(void* const* d_in, const int* in_sizes, int n_in,
                              void* d_out, int out_size, void* d_ws, size_t ws_size,
                              hipStream_t stream)
{
    (void)in_sizes; (void)n_in; (void)out_size;
    const float* y = (const float*)d_in[1];
    const float* W0[5]; const float* b0[5]; const float* W1[5]; const float* b1[5]; const float* W2[5];
    for (int m = 0; m < 5; ++m) {
        int base = 2 + m * 5;
        W0[m] = (const float*)d_in[base + 0];
        b0[m] = (const float*)d_in[base + 1];
        W1[m] = (const float*)d_in[base + 2];
        b1[m] = (const float*)d_in[base + 3];
        W2[m] = (const float*)d_in[base + 4];
    }
    float* ws = (float*)d_ws;
    float* dout = (float*)d_out;
    if (ws_size < (size_t)WS_FLOATS * sizeof(float)) return;

    for (int m = 0; m < 5; ++m) {
        hipLaunchKernelGGL(k_transpose, dim3((256 * 64 + 255) / 256), dim3(256), 0, stream,
                           W0[m], ws + OFF_W0T + m * 16384, 256, 64);
        hipLaunchKernelGGL(k_transpose, dim3((256 * 256 + 255) / 256), dim3(256), 0, stream,
                           W1[m], ws + OFF_W1T + m * 65536, 256, 256);
    }
    hipLaunchKernelGGL(k_transpose, dim3((2016 * 256 + 255) / 256), dim3(256), 0, stream,
                       W2[2], ws + OFF_W2PT, 2016, 256);
    hipLaunchKernelGGL(k_transpose, dim3((1024 * 256 + 255) / 256), dim3(256), 0, stream,
                       W2[3], ws + OFF_W2CT, 1024, 256);
    hipLaunchKernelGGL(k_transpose, dim3((4096 * 256 + 255) / 256), dim3(256), 0, stream,
                       W2[4], ws + OFF_W2BT, 4096, 256);

    hipLaunchKernelGGL(k1_grads, dim3(1024), dim3(256), 0, stream,
                       y, ws,
                       W0[0], b0[0], W1[0], b1[0], W2[0],
                       W0[1], b0[1], W1[1], b1[1], W2[1],
                       ws + OFF_DE, ws + OFF_DS);

    const int k2_smem = 154112;
    hipFuncSetAttribute((const void*)k2_poisson, hipFuncAttributeMaxDynamicSharedMemorySize, k2_smem);
    hipLaunchKernelGGL(k2_poisson, dim3(1024), dim3(1024), k2_smem, stream,
                       y, ws, b0[2], b1[2], dout);

    const int k3_smem = 132416;
    hipFuncSetAttribute((const void*)k3_friction, hipFuncAttributeMaxDynamicSharedMemorySize, k3_smem);
    hipLaunchKernelGGL(k3_friction, dim3(1024), dim3(1024), k3_smem, stream,
                       y, ws, b0[3], b1[3], b0[4], b1[4], dout);
}